// Round 3
// baseline (1924.798 us; speedup 1.0000x reference)
//
#include <hip/hip_runtime.h>
#include <stdint.h>
#include <math.h>

// ---------------- problem constants ----------------
#define S_LEN 4096
#define BATCH 4
#define DIM   1024
#define AP    256
#define NBLK  32            // S_LEN/128 row-blocks per batch
#define BANDC 640           // 5*128 band columns
#define SCALE 0.03125f      // 1/sqrt(1024)

typedef __attribute__((ext_vector_type(4))) float f32x4;
typedef __attribute__((ext_vector_type(8))) short bf16x8;

// ---------------- helpers ----------------
__device__ __forceinline__ ushort f2bf(float f) {
  union { float f; uint32_t u; } v; v.f = f;
  uint32_t r = v.u + 0x7FFFu + ((v.u >> 16) & 1u);
  return (ushort)(r >> 16);
}

__device__ __forceinline__ void gload16(const void* g, void* l) {
  __builtin_amdgcn_global_load_lds((const __attribute__((address_space(1))) void*)g,
                                   (__attribute__((address_space(3))) void*)l,
                                   16, 0, 0);
}

__device__ __forceinline__ float block_sum(float v, float* red) {
  #pragma unroll
  for (int o = 32; o > 0; o >>= 1) v += __shfl_xor(v, o, 64);
  const int w = threadIdx.x >> 6;
  if ((threadIdx.x & 63) == 0) red[w] = v;
  __syncthreads();
  v = red[0] + red[1] + red[2] + red[3];
  __syncthreads();
  return v;
}

__device__ __forceinline__ float block_max(float v, float* red) {
  #pragma unroll
  for (int o = 32; o > 0; o >>= 1) v = fmaxf(v, __shfl_xor(v, o, 64));
  const int w = threadIdx.x >> 6;
  if ((threadIdx.x & 63) == 0) red[w] = v;
  __syncthreads();
  v = fmaxf(fmaxf(red[0], red[1]), fmaxf(red[2], red[3]));
  __syncthreads();
  return v;
}

// =====================================================================
// 256x256 GEMM core: 512 thr = 8 waves (2M x 4N), per-wave C = 128x64.
// BK=32, 2 LDS buffers (32KB each: A 16KB + B 16KB) = 64 KiB -> 2 blocks/CU.
// Depth-1 prefetch, counted vmcnt(4) steady state, ONE s_barrier/K-step.
// Swizzle (quarter-wave conflict-free): LDS slot (row,s) holds global
// seg s^((row>>1)&3); staging source pre-swizzled, read side swizzled,
// LDS dest linear (global_load_lds requirement).
// A: row-major [256 x K] (lda); B: row-major [256 n-rows x K] (ldb) = B^T.
// =====================================================================
__device__ __forceinline__ void gemm256_core(
    const ushort* __restrict__ Ablk, int lda,
    const ushort* __restrict__ Bblk, int ldb,
    int K, ushort* __restrict__ lds,
    f32x4 acc[8][4])
{
  const int tid  = threadIdx.x;
  const int lane = tid & 63;
  const int wave = tid >> 6;
  const int wr = wave >> 2;       // 0..1
  const int wn = wave & 3;        // 0..3

  // staging: thread covers (srow = tid>>2, slot = tid&3); source seg pre-swizzled
  const int srow = tid >> 2;                       // 0..127
  const int gseg = (tid & 3) ^ ((tid >> 3) & 3);   // slot ^ ((srow>>1)&3)
  const ushort* gA0 = Ablk + (size_t)srow * lda + gseg * 8;
  const ushort* gA1 = Ablk + (size_t)(srow + 128) * lda + gseg * 8;
  const ushort* gB0 = Bblk + (size_t)srow * ldb + gseg * 8;
  const ushort* gB1 = Bblk + (size_t)(srow + 128) * ldb + gseg * 8;
  const int stA = wave * 512;                      // wave-uniform LDS base (ushorts)

  // swizzled ds_read addresses
  const int l15 = lane & 15;
  const int seg = (lane >> 4) ^ ((lane >> 1) & 3); // kseg ^ ((row>>1)&3), row=..+l15
  const int roffA = (wr * 128 + l15) * 32 + seg * 8;   // + m*512 (16 rows per m)
  const int roffB = (wn * 64  + l15) * 32 + seg * 8;   // + n*512

  const int NT = K >> 5;

  // prologue: stage tile 0 into buf 0
  gload16(gA0, lds + stA);
  gload16(gA1, lds + 4096  + stA);
  gload16(gB0, lds + 8192  + stA);
  gload16(gB1, lds + 12288 + stA);

  for (int t = 0; t < NT; ++t) {
    if (t + 1 < NT) {
      ushort* buf = lds + ((t + 1) & 1) * 16384;
      const int k0 = (t + 1) * 32;
      gload16(gA0 + k0, buf + stA);
      gload16(gA1 + k0, buf + 4096  + stA);
      gload16(gB0 + k0, buf + 8192  + stA);
      gload16(gB1 + k0, buf + 12288 + stA);
      asm volatile("s_waitcnt vmcnt(4)" ::: "memory");   // tile t landed
    } else {
      asm volatile("s_waitcnt vmcnt(0)" ::: "memory");
    }
    __builtin_amdgcn_s_barrier();

    const ushort* buf = lds + (t & 1) * 16384;
    bf16x8 af[4], af2[4], bfv[4];
    #pragma unroll
    for (int n = 0; n < 4; ++n) bfv[n] = *(const bf16x8*)(buf + 8192 + roffB + n * 512);
    #pragma unroll
    for (int m = 0; m < 4; ++m) af[m] = *(const bf16x8*)(buf + roffA + m * 512);
    #pragma unroll
    for (int m = 0; m < 4; ++m) af2[m] = *(const bf16x8*)(buf + roffA + (m + 4) * 512);

    __builtin_amdgcn_s_setprio(1);
    #pragma unroll
    for (int m = 0; m < 4; ++m)
      #pragma unroll
      for (int n = 0; n < 4; ++n)
        acc[m][n] = __builtin_amdgcn_mfma_f32_16x16x32_bf16(af[m], bfv[n], acc[m][n], 0, 0, 0);
    #pragma unroll
    for (int m = 0; m < 4; ++m)
      #pragma unroll
      for (int n = 0; n < 4; ++n)
        acc[m + 4][n] = __builtin_amdgcn_mfma_f32_16x16x32_bf16(af2[m], bfv[n], acc[m + 4][n], 0, 0, 0);
    __builtin_amdgcn_s_setprio(0);
    // all this buffer's ds_reads retired before next barrier (race protection)
    asm volatile("s_waitcnt lgkmcnt(0)" ::: "memory");
  }
}

#define ACC256_ZERO(acc) \
  _Pragma("unroll") for (int m_ = 0; m_ < 8; m_++) \
  _Pragma("unroll") for (int n_ = 0; n_ < 4; n_++) \
  _Pragma("unroll") for (int r_ = 0; r_ < 4; r_++) acc[m_][n_][r_] = 0.0f;

#define EPI256_BEGIN(acc) { \
  const int lane_ = threadIdx.x & 63; \
  const int wave_ = threadIdx.x >> 6; \
  const int wrb_ = (wave_ >> 2) * 128; \
  const int wnb_ = (wave_ & 3) * 64; \
  const int rb_ = (lane_ >> 4) << 2; \
  const int cb_ = lane_ & 15; \
  _Pragma("unroll") for (int m_ = 0; m_ < 8; m_++) \
  _Pragma("unroll") for (int n_ = 0; n_ < 4; n_++) \
  _Pragma("unroll") for (int r_ = 0; r_ < 4; r_++) { \
    const int rloc = wrb_ + m_ * 16 + rb_ + r_; \
    const int cloc = wnb_ + n_ * 16 + cb_; \
    const float aval = acc[m_][n_][r_];
#define EPI256_END() } }

// =====================================================================
// 128x128 GEMM core (scores/av): 256 thr = 4 waves (2x2), dbuf 2x16KB=32KB,
// depth-1 prefetch, counted vmcnt(4), one barrier/step, same swizzle.
// Layout per buf (ushorts): A [128][32] at 0, B [128][32] at 4096.
// =====================================================================
__device__ __forceinline__ void gemm_core(
    const ushort* __restrict__ Ablk, int lda,
    const ushort* __restrict__ Bblk, int ldb,
    int k_begin, int k_end,
    ushort* __restrict__ lds,
    f32x4 acc[4][4])
{
  const int tid  = threadIdx.x;
  const int lane = tid & 63;
  const int wr = ((tid >> 7) & 1) * 64;
  const int wc = ((tid >> 6) & 1) * 64;
  const int lr = lane & 15;
  const int seg = (lane >> 4) ^ ((lane >> 1) & 3);

  const int srow = tid >> 2;                       // 0..63
  const int gseg = (tid & 3) ^ ((tid >> 3) & 3);
  const ushort* gA0 = Ablk + (size_t)srow * lda + gseg * 8;
  const ushort* gA1 = Ablk + (size_t)(srow + 64) * lda + gseg * 8;
  const ushort* gB0 = Bblk + (size_t)srow * ldb + gseg * 8;
  const ushort* gB1 = Bblk + (size_t)(srow + 64) * ldb + gseg * 8;
  const int stA = (tid >> 6) * 512;                // wave-uniform base (ushorts)

  const int NT = (k_end - k_begin) >> 5;

  gload16(gA0 + k_begin, lds + stA);
  gload16(gA1 + k_begin, lds + 2048 + stA);
  gload16(gB0 + k_begin, lds + 4096 + stA);
  gload16(gB1 + k_begin, lds + 6144 + stA);

  for (int t = 0; t < NT; ++t) {
    if (t + 1 < NT) {
      ushort* buf = lds + ((t + 1) & 1) * 8192;
      const int k0 = k_begin + (t + 1) * 32;
      gload16(gA0 + k0, buf + stA);
      gload16(gA1 + k0, buf + 2048 + stA);
      gload16(gB0 + k0, buf + 4096 + stA);
      gload16(gB1 + k0, buf + 6144 + stA);
      asm volatile("s_waitcnt vmcnt(4)" ::: "memory");
    } else {
      asm volatile("s_waitcnt vmcnt(0)" ::: "memory");
    }
    __builtin_amdgcn_s_barrier();

    const ushort* buf = lds + (t & 1) * 8192;
    bf16x8 af[4], bfv[4];
    #pragma unroll
    for (int m = 0; m < 4; m++)
      af[m] = *(const bf16x8*)(buf + (wr + m * 16 + lr) * 32 + seg * 8);
    #pragma unroll
    for (int n = 0; n < 4; n++)
      bfv[n] = *(const bf16x8*)(buf + 4096 + (wc + n * 16 + lr) * 32 + seg * 8);

    __builtin_amdgcn_s_setprio(1);
    #pragma unroll
    for (int m = 0; m < 4; m++)
      #pragma unroll
      for (int n = 0; n < 4; n++)
        acc[m][n] = __builtin_amdgcn_mfma_f32_16x16x32_bf16(af[m], bfv[n], acc[m][n], 0, 0, 0);
    __builtin_amdgcn_s_setprio(0);
    asm volatile("s_waitcnt lgkmcnt(0)" ::: "memory");
  }
}

#define ACC_ZERO(acc) \
  _Pragma("unroll") for (int m_ = 0; m_ < 4; m_++) \
  _Pragma("unroll") for (int n_ = 0; n_ < 4; n_++) \
  _Pragma("unroll") for (int r_ = 0; r_ < 4; r_++) acc[m_][n_][r_] = 0.0f;

#define EPI_BEGIN(acc) { \
  const int lane_ = threadIdx.x & 63; \
  const int wr_ = ((threadIdx.x >> 7) & 1) * 64; \
  const int wc_ = ((threadIdx.x >> 6) & 1) * 64; \
  const int rb_ = (lane_ >> 4) << 2; \
  const int cb_ = lane_ & 15; \
  _Pragma("unroll") for (int m_ = 0; m_ < 4; m_++) \
  _Pragma("unroll") for (int n_ = 0; n_ < 4; n_++) \
  _Pragma("unroll") for (int r_ = 0; r_ < 4; r_++) { \
    const int rloc = wr_ + m_ * 16 + rb_ + r_; \
    const int cloc = wc_ + n_ * 16 + cb_; \
    const float aval = acc[m_][n_][r_];
#define EPI_END() } }

// ---------------- elementwise prep kernels ----------------
__global__ __launch_bounds__(256) void prep_x(const float* __restrict__ x, ushort* __restrict__ xb) {
  size_t idx = ((size_t)blockIdx.x * 256 + threadIdx.x) * 4;   // dest flat index (b,s,d)
  int d = (int)(idx & 1023);
  int s = (int)((idx >> 10) & 4095);
  int b = (int)(idx >> 22);
  float4 v = *(const float4*)(x + ((size_t)s * BATCH + b) * DIM + d);
  ushort4 o;
  o.x = f2bf(v.x); o.y = f2bf(v.y); o.z = f2bf(v.z); o.w = f2bf(v.w);
  *(ushort4*)(xb + idx) = o;
}

__global__ __launch_bounds__(256) void f2bf_vec(const float* __restrict__ src, ushort* __restrict__ dst, int n) {
  int idx = (blockIdx.x * 256 + threadIdx.x) * 4;
  if (idx >= n) return;
  float4 v = *(const float4*)(src + idx);
  ushort4 o;
  o.x = f2bf(v.x); o.y = f2bf(v.y); o.z = f2bf(v.z); o.w = f2bf(v.w);
  *(ushort4*)(dst + idx) = o;
}

// ---------------- big GEMMs on the 256 core ----------------
__global__ __launch_bounds__(512, 4) void qkv_gemm256(
    const ushort* __restrict__ xb, const ushort* __restrict__ wqkv,
    ushort* __restrict__ Kp, ushort* __restrict__ Qp, ushort* __restrict__ Vp)
{
  __shared__ ushort lds[32768];
  // XCD-chunked swizzle: 768 blocks, 96 contiguous tiles per XCD
  const int nid = (blockIdx.x & 7) * 96 + (blockIdx.x >> 3);
  const int by = nid / 12;     // 0..63
  const int bx = nid % 12;     // 0..11
  f32x4 acc[8][4];
  ACC256_ZERO(acc)
  gemm256_core(xb + (size_t)by * 256 * DIM, DIM,
               wqkv + (size_t)bx * 256 * DIM, DIM, DIM, lds, acc);
  ushort* dst = (bx < 4) ? Kp : (bx < 8) ? Qp : Vp;
  const int colb = (bx & 3) * 256;
  EPI256_BEGIN(acc)
    int row = by * 256 + rloc;
    int col = colb + cloc;
    dst[(size_t)row * DIM + col] = f2bf(aval);
  EPI256_END()
}

__global__ __launch_bounds__(512, 4) void wp_gemm256(
    const ushort* __restrict__ cbuf, const ushort* __restrict__ wpb,
    const float* __restrict__ x, float* __restrict__ y0)
{
  __shared__ ushort lds[32768];
  const int nid = (blockIdx.x & 7) * 32 + (blockIdx.x >> 3);   // 256 blocks
  const int by = nid >> 2;     // 0..63
  const int bx = nid & 3;      // 0..3
  f32x4 acc[8][4];
  ACC256_ZERO(acc)
  gemm256_core(cbuf + (size_t)by * 256 * DIM, DIM,
               wpb + (size_t)bx * 256 * DIM, DIM, DIM, lds, acc);
  EPI256_BEGIN(acc)
    int row = by * 256 + rloc;           // b*4096+s
    int col = bx * 256 + cloc;
    int b = row >> 12, s = row & 4095;
    y0[(size_t)row * DIM + col] = aval + x[((size_t)s * BATCH + b) * DIM + col];
  EPI256_END()
}

__global__ __launch_bounds__(512, 4) void ffn1_gemm256(
    const ushort* __restrict__ y1, const ushort* __restrict__ w1b,
    const float* __restrict__ b1, float* __restrict__ h0)
{
  __shared__ ushort lds[32768];
  const int nid = (blockIdx.x & 7) * 32 + (blockIdx.x >> 3);
  const int by = nid >> 2;
  const int bx = nid & 3;
  f32x4 acc[8][4];
  ACC256_ZERO(acc)
  gemm256_core(y1 + (size_t)by * 256 * DIM, DIM,
               w1b + (size_t)bx * 256 * DIM, DIM, DIM, lds, acc);
  EPI256_BEGIN(acc)
    int row = by * 256 + rloc;
    int col = bx * 256 + cloc;
    h0[(size_t)row * DIM + col] = fmaxf(aval + b1[col], 0.0f);
  EPI256_END()
}

// ---------------- attention path (128 core) ----------------
__global__ __launch_bounds__(256) void transpose_v(const ushort* __restrict__ V, ushort* __restrict__ VT) {
  __shared__ ushort tile[64][66];
  const int s0 = blockIdx.x * 64, d0 = blockIdx.y * 64, b = blockIdx.z;
  const ushort* Vb = V + (size_t)b * S_LEN * DIM;
  ushort* VTb = VT + (size_t)b * DIM * S_LEN;
  #pragma unroll
  for (int it = 0; it < 16; it++) {
    int flat = it * 256 + threadIdx.x;
    int r = flat >> 6, c = flat & 63;
    tile[r][c] = Vb[(size_t)(s0 + r) * DIM + d0 + c];
  }
  __syncthreads();
  #pragma unroll
  for (int it = 0; it < 16; it++) {
    int flat = it * 256 + threadIdx.x;
    int r = flat >> 6, c = flat & 63;      // r = d-local, c = s-local
    VTb[(size_t)(d0 + r) * S_LEN + s0 + c] = tile[c][r];
  }
}

__global__ __launch_bounds__(256) void scores_gemm(
    const ushort* __restrict__ Qp, const ushort* __restrict__ Kp,
    float* __restrict__ eband)
{
  const int nid = (blockIdx.x & 7) * 80 + (blockIdx.x >> 3);   // 640 blocks
  const int b   = nid / 160;
  const int rem = nid % 160;
  const int i   = rem / 5;
  const int jj  = rem % 5;
  const int j   = i - 2 + jj;
  if (j < 0 || j >= NBLK) return;
  __shared__ ushort lds[16384];
  f32x4 acc[4][4];
  ACC_ZERO(acc)
  gemm_core(Qp + ((size_t)b * S_LEN + i * 128) * DIM, DIM,
            Kp + ((size_t)b * S_LEN + j * 128) * DIM, DIM, 0, DIM, lds, acc);
  EPI_BEGIN(acc)
    int q = i * 128 + rloc;
    int k = j * 128 + cloc;
    float v = aval * SCALE;
    int dqk = q - k;
    if (dqk == 0 || dqk > AP || dqk < -AP) v = -INFINITY;
    eband[((size_t)b * S_LEN + q) * BANDC + jj * 128 + cloc] = v;
  EPI_END()
}

__global__ __launch_bounds__(256) void softmax_band(const float* __restrict__ eband,
                                                    ushort* __restrict__ aband)
{
  __shared__ float red[4];
  const int qg = blockIdx.x;          // 0..16383
  const int s  = qg & 4095;
  const int i  = s >> 7;
  const float* row = eband + (size_t)qg * BANDC;
  ushort* arow = aband + (size_t)qg * BANDC;

  float vals[3];
  bool  valid[3];
  float mx = -INFINITY;
  #pragma unroll
  for (int t = 0; t < 3; t++) {
    int idx = threadIdx.x + t * 256;
    int jj = idx >> 7;
    int j = i - 2 + jj;
    bool ok = (idx < BANDC) && (j >= 0) && (j < NBLK);
    valid[t] = ok;
    float v = ok ? row[idx] : -INFINITY;
    vals[t] = v;
    mx = fmaxf(mx, v);
  }
  float bmax = block_max(mx, red);
  float ss = 0.0f;
  #pragma unroll
  for (int t = 0; t < 3; t++) {
    float e = valid[t] ? __expf(vals[t] - bmax) : 0.0f;
    vals[t] = e;
    ss += e;
  }
  float inv = 1.0f / block_sum(ss, red);
  #pragma unroll
  for (int t = 0; t < 3; t++) {
    int idx = threadIdx.x + t * 256;
    if (idx < BANDC) arow[idx] = f2bf(vals[t] * inv);
  }
}

__global__ __launch_bounds__(256) void av_gemm(
    const ushort* __restrict__ aband, const ushort* __restrict__ VT,
    ushort* __restrict__ cbuf)
{
  const int nid = (blockIdx.x & 7) * 128 + (blockIdx.x >> 3); // 1024 blocks
  const int by = nid >> 3;            // 0..127: (b,i)
  const int b = by >> 5, i = by & 31;
  const int bx = nid & 7;             // d-block
  const int jj_lo = (i < 2) ? (2 - i) : 0;
  const int jj_hi = (i > 29) ? (34 - i) : 5;
  __shared__ ushort lds[16384];
  f32x4 acc[4][4];
  ACC_ZERO(acc)
  const ushort* Ablk = aband + ((size_t)b * S_LEN + i * 128) * BANDC;
  const ushort* Bblk = VT + (size_t)b * DIM * S_LEN + (size_t)bx * 128 * S_LEN + (i - 2) * 128;
  gemm_core(Ablk, BANDC, Bblk, S_LEN, jj_lo * 128, jj_hi * 128, lds, acc);
  EPI_BEGIN(acc)
    int row = b * S_LEN + i * 128 + rloc;
    int col = bx * 128 + cloc;
    cbuf[(size_t)row * DIM + col] = f2bf(aval);
  EPI_END()
}

// ---------------- norm / head ----------------
__global__ __launch_bounds__(256) void ln_kernel(const float* __restrict__ y0, ushort* __restrict__ y1,
                                                 const float* __restrict__ gamma, const float* __restrict__ beta)
{
  __shared__ float red[4];
  const size_t q = blockIdx.x;
  const float* row = y0 + q * DIM;
  float v[4];
  #pragma unroll
  for (int t = 0; t < 4; t++) v[t] = row[threadIdx.x + t * 256];
  float mean = block_sum(v[0] + v[1] + v[2] + v[3], red) * (1.0f / DIM);
  float q2 = 0.0f;
  #pragma unroll
  for (int t = 0; t < 4; t++) { float d = v[t] - mean; q2 += d * d; }
  float var = block_sum(q2, red) * (1.0f / DIM);
  float rstd = rsqrtf(var + 1e-6f);
  #pragma unroll
  for (int t = 0; t < 4; t++) {
    int d = threadIdx.x + t * 256;
    y1[q * DIM + d] = f2bf((v[t] - mean) * rstd * gamma[d] + beta[d]);
  }
}

__global__ __launch_bounds__(256) void head_kernel(const float* __restrict__ h0,
    const float* __restrict__ gamma, const float* __restrict__ beta,
    const float* __restrict__ W2, const float* __restrict__ b2,
    float* __restrict__ out)
{
  __shared__ float red[4];
  const int qg = blockIdx.x;
  const int b = qg >> 12, s = qg & 4095;
  const float* row = h0 + (size_t)qg * DIM;
  float v[4];
  #pragma unroll
  for (int t = 0; t < 4; t++) v[t] = row[threadIdx.x + t * 256];
  float mean = block_sum(v[0] + v[1] + v[2] + v[3], red) * (1.0f / DIM);
  float q2 = 0.0f;
  #pragma unroll
  for (int t = 0; t < 4; t++) { float d = v[t] - mean; q2 += d * d; }
  float var = block_sum(q2, red) * (1.0f / DIM);
  float rstd = rsqrtf(var + 1e-6f);
  float part = 0.0f;
  #pragma unroll
  for (int t = 0; t < 4; t++) {
    int d = threadIdx.x + t * 256;
    part += ((v[t] - mean) * rstd * gamma[d] + beta[d]) * W2[d];
  }
  float logit = block_sum(part, red) + b2[0];
  if (threadIdx.x == 0) out[(size_t)s * BATCH + b] = 1.0f / (1.0f + expf(-logit));
}

// ---------------- launch ----------------
extern "C" void kernel_launch(void* const* d_in, const int* in_sizes, int n_in,
                              void* d_out, int out_size, void* d_ws, size_t ws_size,
                              hipStream_t stream) {
  const float* x     = (const float*)d_in[0];
  const float* Wk    = (const float*)d_in[1];
  const float* Wq    = (const float*)d_in[2];
  const float* Wv    = (const float*)d_in[3];
  const float* Wp    = (const float*)d_in[4];
  const float* W1    = (const float*)d_in[5];
  const float* b1    = (const float*)d_in[6];
  const float* W2    = (const float*)d_in[7];
  const float* b2    = (const float*)d_in[8];
  const float* gamma = (const float*)d_in[9];
  const float* beta  = (const float*)d_in[10];
  float* out = (float*)d_out;

  char* w = (char*)d_ws;
  ushort* xb   = (ushort*)(w + 0);            // 33,554,432 B
  ushort* wqkv = (ushort*)(w + 33554432);     //  6,291,456 B
  ushort* wpb  = (ushort*)(w + 39845888);     //  2,097,152 B
  ushort* w1b  = (ushort*)(w + 41943040);     //  2,097,152 B
  ushort* Qp   = (ushort*)(w + 44040192);     // 33,554,432 B
  ushort* Kp   = (ushort*)(w + 77594624);     // 33,554,432 B
  ushort* Vp   = (ushort*)(w + 111149056);    // 33,554,432 B
  ushort* VT   = (ushort*)(w + 144703488);    // 33,554,432 B
  float*  big  = (float*)(w + 178257920);     // 67,108,864 B (eband -> y0 -> h0)
  // reuse (sequentially dead regions):
  ushort* aband = Qp;     // Q dead after scores
  ushort* cbuf  = Kp;     // K dead after scores
  ushort* y1    = Vp;     // V dead after transpose
  float* eband = big;
  float* y0    = big;
  float* h0    = big;

  prep_x<<<16384, 256, 0, stream>>>(x, xb);
  f2bf_vec<<<1024, 256, 0, stream>>>(Wk, wqkv,            1048576);
  f2bf_vec<<<1024, 256, 0, stream>>>(Wq, wqkv + 1048576,  1048576);
  f2bf_vec<<<1024, 256, 0, stream>>>(Wv, wqkv + 2097152,  1048576);
  f2bf_vec<<<1024, 256, 0, stream>>>(Wp, wpb, 1048576);
  f2bf_vec<<<1024, 256, 0, stream>>>(W1, w1b, 1048576);

  qkv_gemm256<<<768, 512, 0, stream>>>(xb, wqkv, Kp, Qp, Vp);
  transpose_v<<<dim3(64, 16, 4), 256, 0, stream>>>(Vp, VT);
  scores_gemm<<<640, 256, 0, stream>>>(Qp, Kp, eband);
  softmax_band<<<16384, 256, 0, stream>>>(eband, aband);
  av_gemm<<<1024, 256, 0, stream>>>(aband, VT, cbuf);
  wp_gemm256<<<256, 512, 0, stream>>>(cbuf, wpb, x, y0);
  ln_kernel<<<16384, 256, 0, stream>>>(y0, y1, gamma, beta);
  ffn1_gemm256<<<256, 512, 0, stream>>>(y1, w1b, b1, h0);
  head_kernel<<<16384, 256, 0, stream>>>(h0, gamma, beta, W2, b2, out);
}

// Round 4
// 385.170 us; speedup vs baseline: 4.9973x; 4.9973x over previous
//
#include <hip/hip_runtime.h>
#include <stdint.h>
#include <math.h>

// ---------------- problem constants ----------------
#define S_LEN 4096
#define BATCH 4
#define DIM   1024
#define AP    256
#define NBLK  32            // S_LEN/128 row-blocks per batch
#define BANDC 640           // 5*128 band columns
#define SCALE 0.03125f      // 1/sqrt(1024)

typedef __attribute__((ext_vector_type(4))) float f32x4;
typedef __attribute__((ext_vector_type(8))) short bf16x8;

// ---------------- helpers ----------------
__device__ __forceinline__ ushort f2bf(float f) {
  union { float f; uint32_t u; } v; v.f = f;
  uint32_t r = v.u + 0x7FFFu + ((v.u >> 16) & 1u);
  return (ushort)(r >> 16);
}

__device__ __forceinline__ void gload16(const void* g, void* l) {
  __builtin_amdgcn_global_load_lds((const __attribute__((address_space(1))) void*)g,
                                   (__attribute__((address_space(3))) void*)l,
                                   16, 0, 0);
}

__device__ __forceinline__ float block_sum(float v, float* red) {
  #pragma unroll
  for (int o = 32; o > 0; o >>= 1) v += __shfl_xor(v, o, 64);
  const int w = threadIdx.x >> 6;
  if ((threadIdx.x & 63) == 0) red[w] = v;
  __syncthreads();
  v = red[0] + red[1] + red[2] + red[3];
  __syncthreads();
  return v;
}

__device__ __forceinline__ float block_max(float v, float* red) {
  #pragma unroll
  for (int o = 32; o > 0; o >>= 1) v = fmaxf(v, __shfl_xor(v, o, 64));
  const int w = threadIdx.x >> 6;
  if ((threadIdx.x & 63) == 0) red[w] = v;
  __syncthreads();
  v = fmaxf(fmaxf(red[0], red[1]), fmaxf(red[2], red[3]));
  __syncthreads();
  return v;
}

// =====================================================================
// 256x256 GEMM core: 512 thr = 8 waves (2M x 4N), per-wave C = 128x64.
// BK=32, FOUR LDS K-tile buffers (32KB each) = 128 KiB -> 1 block/CU
// (register-bound anyway: 128 acc regs/thread needs 2 waves/EU cap 256).
// Depth-3 prefetch, counted vmcnt(8/4/0), ONE s_barrier/K-step.
// Quarter-wave conflict-free swizzle: LDS slot (row,s) holds global seg
// s^((row>>1)&3); staging source pre-swizzled, read side swizzled,
// LDS dest linear (global_load_lds requirement).  [verified: conflicts=0]
// A: row-major [256 x K] (lda); B: row-major [256 n-rows x K] (ldb) = B^T.
// =====================================================================
__device__ __forceinline__ void gemm256_core(
    const ushort* __restrict__ Ablk, int lda,
    const ushort* __restrict__ Bblk, int ldb,
    int K, ushort* __restrict__ lds,
    f32x4 acc[8][4])
{
  const int tid  = threadIdx.x;
  const int lane = tid & 63;
  const int wave = tid >> 6;
  const int wr = wave >> 2;       // 0..1
  const int wn = wave & 3;        // 0..3

  // staging: thread covers (srow = tid>>2, slot = tid&3); source seg pre-swizzled
  const int srow = tid >> 2;                       // 0..127
  const int gseg = (tid & 3) ^ ((tid >> 3) & 3);   // slot ^ ((srow>>1)&3)
  const ushort* gA0 = Ablk + (size_t)srow * lda + gseg * 8;
  const ushort* gA1 = Ablk + (size_t)(srow + 128) * lda + gseg * 8;
  const ushort* gB0 = Bblk + (size_t)srow * ldb + gseg * 8;
  const ushort* gB1 = Bblk + (size_t)(srow + 128) * ldb + gseg * 8;
  const int stA = wave * 512;                      // wave-uniform LDS base (ushorts)

  // swizzled ds_read addresses
  const int l15 = lane & 15;
  const int seg = (lane >> 4) ^ ((lane >> 1) & 3); // kseg ^ ((row>>1)&3), row=..+l15
  const int roffA = (wr * 128 + l15) * 32 + seg * 8;   // + m*512 (16 rows per m)
  const int roffB = (wn * 64  + l15) * 32 + seg * 8;   // + n*512

  const int NT = K >> 5;

  // prologue: stage tiles 0..2 into bufs 0..2
  #pragma unroll
  for (int p = 0; p < 3; ++p) {
    ushort* buf = lds + p * 16384;
    const int k0 = p * 32;
    gload16(gA0 + k0, buf + stA);
    gload16(gA1 + k0, buf + 4096  + stA);
    gload16(gB0 + k0, buf + 8192  + stA);
    gload16(gB1 + k0, buf + 12288 + stA);
  }

  for (int t = 0; t < NT; ++t) {
    const int rem = NT - 1 - t;
    if (rem >= 2)      asm volatile("s_waitcnt vmcnt(8)" ::: "memory");  // tile t landed
    else if (rem == 1) asm volatile("s_waitcnt vmcnt(4)" ::: "memory");
    else               asm volatile("s_waitcnt vmcnt(0)" ::: "memory");
    __builtin_amdgcn_s_barrier();

    if (t + 3 < NT) {
      ushort* buf = lds + ((t + 3) & 3) * 16384;
      const int k0 = (t + 3) * 32;
      gload16(gA0 + k0, buf + stA);
      gload16(gA1 + k0, buf + 4096  + stA);
      gload16(gB0 + k0, buf + 8192  + stA);
      gload16(gB1 + k0, buf + 12288 + stA);
    }

    const ushort* buf = lds + (t & 3) * 16384;
    bf16x8 af[4], af2[4], bfv[4];
    #pragma unroll
    for (int n = 0; n < 4; ++n) bfv[n] = *(const bf16x8*)(buf + 8192 + roffB + n * 512);
    #pragma unroll
    for (int m = 0; m < 4; ++m) af[m] = *(const bf16x8*)(buf + roffA + m * 512);
    #pragma unroll
    for (int m = 0; m < 4; ++m) af2[m] = *(const bf16x8*)(buf + roffA + (m + 4) * 512);

    __builtin_amdgcn_s_setprio(1);
    #pragma unroll
    for (int m = 0; m < 4; ++m)
      #pragma unroll
      for (int n = 0; n < 4; ++n)
        acc[m][n] = __builtin_amdgcn_mfma_f32_16x16x32_bf16(af[m], bfv[n], acc[m][n], 0, 0, 0);
    #pragma unroll
    for (int m = 0; m < 4; ++m)
      #pragma unroll
      for (int n = 0; n < 4; ++n)
        acc[m + 4][n] = __builtin_amdgcn_mfma_f32_16x16x32_bf16(af2[m], bfv[n], acc[m + 4][n], 0, 0, 0);
    __builtin_amdgcn_s_setprio(0);
    // this buffer's ds_reads retired before any wave crosses the next barrier
    asm volatile("s_waitcnt lgkmcnt(0)" ::: "memory");
  }
}

#define ACC256_ZERO(acc) \
  _Pragma("unroll") for (int m_ = 0; m_ < 8; m_++) \
  _Pragma("unroll") for (int n_ = 0; n_ < 4; n_++) \
  _Pragma("unroll") for (int r_ = 0; r_ < 4; r_++) acc[m_][n_][r_] = 0.0f;

#define EPI256_BEGIN(acc) { \
  const int lane_ = threadIdx.x & 63; \
  const int wave_ = threadIdx.x >> 6; \
  const int wrb_ = (wave_ >> 2) * 128; \
  const int wnb_ = (wave_ & 3) * 64; \
  const int rb_ = (lane_ >> 4) << 2; \
  const int cb_ = lane_ & 15; \
  _Pragma("unroll") for (int m_ = 0; m_ < 8; m_++) \
  _Pragma("unroll") for (int n_ = 0; n_ < 4; n_++) \
  _Pragma("unroll") for (int r_ = 0; r_ < 4; r_++) { \
    const int rloc = wrb_ + m_ * 16 + rb_ + r_; \
    const int cloc = wnb_ + n_ * 16 + cb_; \
    const float aval = acc[m_][n_][r_];
#define EPI256_END() } }

// =====================================================================
// 128x128 GEMM core (scores/av): 256 thr = 4 waves (2x2), dbuf 2x16KB=32KB,
// depth-1 prefetch, counted vmcnt(4), one barrier/step, same swizzle.
// Layout per buf (ushorts): A [128][32] at 0, B [128][32] at 4096.
// =====================================================================
__device__ __forceinline__ void gemm_core(
    const ushort* __restrict__ Ablk, int lda,
    const ushort* __restrict__ Bblk, int ldb,
    int k_begin, int k_end,
    ushort* __restrict__ lds,
    f32x4 acc[4][4])
{
  const int tid  = threadIdx.x;
  const int lane = tid & 63;
  const int wr = ((tid >> 7) & 1) * 64;
  const int wc = ((tid >> 6) & 1) * 64;
  const int lr = lane & 15;
  const int seg = (lane >> 4) ^ ((lane >> 1) & 3);

  const int srow = tid >> 2;                       // 0..63
  const int gseg = (tid & 3) ^ ((tid >> 3) & 3);
  const ushort* gA0 = Ablk + (size_t)srow * lda + gseg * 8;
  const ushort* gA1 = Ablk + (size_t)(srow + 64) * lda + gseg * 8;
  const ushort* gB0 = Bblk + (size_t)srow * ldb + gseg * 8;
  const ushort* gB1 = Bblk + (size_t)(srow + 64) * ldb + gseg * 8;
  const int stA = (tid >> 6) * 512;                // wave-uniform base (ushorts)

  const int NT = (k_end - k_begin) >> 5;

  gload16(gA0 + k_begin, lds + stA);
  gload16(gA1 + k_begin, lds + 2048 + stA);
  gload16(gB0 + k_begin, lds + 4096 + stA);
  gload16(gB1 + k_begin, lds + 6144 + stA);

  for (int t = 0; t < NT; ++t) {
    if (t + 1 < NT) {
      ushort* buf = lds + ((t + 1) & 1) * 8192;
      const int k0 = k_begin + (t + 1) * 32;
      gload16(gA0 + k0, buf + stA);
      gload16(gA1 + k0, buf + 2048 + stA);
      gload16(gB0 + k0, buf + 4096 + stA);
      gload16(gB1 + k0, buf + 6144 + stA);
      asm volatile("s_waitcnt vmcnt(4)" ::: "memory");
    } else {
      asm volatile("s_waitcnt vmcnt(0)" ::: "memory");
    }
    __builtin_amdgcn_s_barrier();

    const ushort* buf = lds + (t & 1) * 8192;
    bf16x8 af[4], bfv[4];
    #pragma unroll
    for (int m = 0; m < 4; m++)
      af[m] = *(const bf16x8*)(buf + (wr + m * 16 + lr) * 32 + seg * 8);
    #pragma unroll
    for (int n = 0; n < 4; n++)
      bfv[n] = *(const bf16x8*)(buf + 4096 + (wc + n * 16 + lr) * 32 + seg * 8);

    __builtin_amdgcn_s_setprio(1);
    #pragma unroll
    for (int m = 0; m < 4; m++)
      #pragma unroll
      for (int n = 0; n < 4; n++)
        acc[m][n] = __builtin_amdgcn_mfma_f32_16x16x32_bf16(af[m], bfv[n], acc[m][n], 0, 0, 0);
    __builtin_amdgcn_s_setprio(0);
    asm volatile("s_waitcnt lgkmcnt(0)" ::: "memory");
  }
}

#define ACC_ZERO(acc) \
  _Pragma("unroll") for (int m_ = 0; m_ < 4; m_++) \
  _Pragma("unroll") for (int n_ = 0; n_ < 4; n_++) \
  _Pragma("unroll") for (int r_ = 0; r_ < 4; r_++) acc[m_][n_][r_] = 0.0f;

#define EPI_BEGIN(acc) { \
  const int lane_ = threadIdx.x & 63; \
  const int wr_ = ((threadIdx.x >> 7) & 1) * 64; \
  const int wc_ = ((threadIdx.x >> 6) & 1) * 64; \
  const int rb_ = (lane_ >> 4) << 2; \
  const int cb_ = lane_ & 15; \
  _Pragma("unroll") for (int m_ = 0; m_ < 4; m_++) \
  _Pragma("unroll") for (int n_ = 0; n_ < 4; n_++) \
  _Pragma("unroll") for (int r_ = 0; r_ < 4; r_++) { \
    const int rloc = wr_ + m_ * 16 + rb_ + r_; \
    const int cloc = wc_ + n_ * 16 + cb_; \
    const float aval = acc[m_][n_][r_];
#define EPI_END() } }

// ---------------- elementwise prep kernels ----------------
__global__ __launch_bounds__(256) void prep_x(const float* __restrict__ x, ushort* __restrict__ xb) {
  size_t idx = ((size_t)blockIdx.x * 256 + threadIdx.x) * 4;   // dest flat index (b,s,d)
  int d = (int)(idx & 1023);
  int s = (int)((idx >> 10) & 4095);
  int b = (int)(idx >> 22);
  float4 v = *(const float4*)(x + ((size_t)s * BATCH + b) * DIM + d);
  ushort4 o;
  o.x = f2bf(v.x); o.y = f2bf(v.y); o.z = f2bf(v.z); o.w = f2bf(v.w);
  *(ushort4*)(xb + idx) = o;
}

__global__ __launch_bounds__(256) void f2bf_vec(const float* __restrict__ src, ushort* __restrict__ dst, int n) {
  int idx = (blockIdx.x * 256 + threadIdx.x) * 4;
  if (idx >= n) return;
  float4 v = *(const float4*)(src + idx);
  ushort4 o;
  o.x = f2bf(v.x); o.y = f2bf(v.y); o.z = f2bf(v.z); o.w = f2bf(v.w);
  *(ushort4*)(dst + idx) = o;
}

// ---------------- big GEMMs on the 256 core ----------------
__global__ __launch_bounds__(512, 2) void qkv_gemm256(
    const ushort* __restrict__ xb, const ushort* __restrict__ wqkv,
    ushort* __restrict__ Kp, ushort* __restrict__ Qp, ushort* __restrict__ Vp)
{
  __shared__ ushort lds[65536];
  // XCD-chunked swizzle: 768 blocks, 96 contiguous tiles per XCD
  const int nid = (blockIdx.x & 7) * 96 + (blockIdx.x >> 3);
  const int by = nid / 12;     // 0..63
  const int bx = nid % 12;     // 0..11
  f32x4 acc[8][4];
  ACC256_ZERO(acc)
  gemm256_core(xb + (size_t)by * 256 * DIM, DIM,
               wqkv + (size_t)bx * 256 * DIM, DIM, DIM, lds, acc);
  ushort* dst = (bx < 4) ? Kp : (bx < 8) ? Qp : Vp;
  const int colb = (bx & 3) * 256;
  EPI256_BEGIN(acc)
    int row = by * 256 + rloc;
    int col = colb + cloc;
    dst[(size_t)row * DIM + col] = f2bf(aval);
  EPI256_END()
}

__global__ __launch_bounds__(512, 2) void wp_gemm256(
    const ushort* __restrict__ cbuf, const ushort* __restrict__ wpb,
    const float* __restrict__ x, float* __restrict__ y0)
{
  __shared__ ushort lds[65536];
  const int nid = (blockIdx.x & 7) * 32 + (blockIdx.x >> 3);   // 256 blocks
  const int by = nid >> 2;     // 0..63
  const int bx = nid & 3;      // 0..3
  f32x4 acc[8][4];
  ACC256_ZERO(acc)
  gemm256_core(cbuf + (size_t)by * 256 * DIM, DIM,
               wpb + (size_t)bx * 256 * DIM, DIM, DIM, lds, acc);
  EPI256_BEGIN(acc)
    int row = by * 256 + rloc;           // b*4096+s
    int col = bx * 256 + cloc;
    int b = row >> 12, s = row & 4095;
    y0[(size_t)row * DIM + col] = aval + x[((size_t)s * BATCH + b) * DIM + col];
  EPI256_END()
}

__global__ __launch_bounds__(512, 2) void ffn1_gemm256(
    const ushort* __restrict__ y1, const ushort* __restrict__ w1b,
    const float* __restrict__ b1, float* __restrict__ h0)
{
  __shared__ ushort lds[65536];
  const int nid = (blockIdx.x & 7) * 32 + (blockIdx.x >> 3);
  const int by = nid >> 2;
  const int bx = nid & 3;
  f32x4 acc[8][4];
  ACC256_ZERO(acc)
  gemm256_core(y1 + (size_t)by * 256 * DIM, DIM,
               w1b + (size_t)bx * 256 * DIM, DIM, DIM, lds, acc);
  EPI256_BEGIN(acc)
    int row = by * 256 + rloc;
    int col = bx * 256 + cloc;
    h0[(size_t)row * DIM + col] = fmaxf(aval + b1[col], 0.0f);
  EPI256_END()
}

// ---------------- attention path (128 core) ----------------
__global__ __launch_bounds__(256) void transpose_v(const ushort* __restrict__ V, ushort* __restrict__ VT) {
  __shared__ ushort tile[64][66];
  const int s0 = blockIdx.x * 64, d0 = blockIdx.y * 64, b = blockIdx.z;
  const ushort* Vb = V + (size_t)b * S_LEN * DIM;
  ushort* VTb = VT + (size_t)b * DIM * S_LEN;
  #pragma unroll
  for (int it = 0; it < 16; it++) {
    int flat = it * 256 + threadIdx.x;
    int r = flat >> 6, c = flat & 63;
    tile[r][c] = Vb[(size_t)(s0 + r) * DIM + d0 + c];
  }
  __syncthreads();
  #pragma unroll
  for (int it = 0; it < 16; it++) {
    int flat = it * 256 + threadIdx.x;
    int r = flat >> 6, c = flat & 63;      // r = d-local, c = s-local
    VTb[(size_t)(d0 + r) * S_LEN + s0 + c] = tile[c][r];
  }
}

__global__ __launch_bounds__(256) void scores_gemm(
    const ushort* __restrict__ Qp, const ushort* __restrict__ Kp,
    float* __restrict__ eband)
{
  const int nid = (blockIdx.x & 7) * 80 + (blockIdx.x >> 3);   // 640 blocks
  const int b   = nid / 160;
  const int rem = nid % 160;
  const int i   = rem / 5;
  const int jj  = rem % 5;
  const int j   = i - 2 + jj;
  if (j < 0 || j >= NBLK) return;
  __shared__ ushort lds[16384];
  f32x4 acc[4][4];
  ACC_ZERO(acc)
  gemm_core(Qp + ((size_t)b * S_LEN + i * 128) * DIM, DIM,
            Kp + ((size_t)b * S_LEN + j * 128) * DIM, DIM, 0, DIM, lds, acc);
  EPI_BEGIN(acc)
    int q = i * 128 + rloc;
    int k = j * 128 + cloc;
    float v = aval * SCALE;
    int dqk = q - k;
    if (dqk == 0 || dqk > AP || dqk < -AP) v = -INFINITY;
    eband[((size_t)b * S_LEN + q) * BANDC + jj * 128 + cloc] = v;
  EPI_END()
}

__global__ __launch_bounds__(256) void softmax_band(const float* __restrict__ eband,
                                                    ushort* __restrict__ aband)
{
  __shared__ float red[4];
  const int qg = blockIdx.x;          // 0..16383
  const int s  = qg & 4095;
  const int i  = s >> 7;
  const float* row = eband + (size_t)qg * BANDC;
  ushort* arow = aband + (size_t)qg * BANDC;

  float vals[3];
  bool  valid[3];
  float mx = -INFINITY;
  #pragma unroll
  for (int t = 0; t < 3; t++) {
    int idx = threadIdx.x + t * 256;
    int jj = idx >> 7;
    int j = i - 2 + jj;
    bool ok = (idx < BANDC) && (j >= 0) && (j < NBLK);
    valid[t] = ok;
    float v = ok ? row[idx] : -INFINITY;
    vals[t] = v;
    mx = fmaxf(mx, v);
  }
  float bmax = block_max(mx, red);
  float ss = 0.0f;
  #pragma unroll
  for (int t = 0; t < 3; t++) {
    float e = valid[t] ? __expf(vals[t] - bmax) : 0.0f;
    vals[t] = e;
    ss += e;
  }
  float inv = 1.0f / block_sum(ss, red);
  #pragma unroll
  for (int t = 0; t < 3; t++) {
    int idx = threadIdx.x + t * 256;
    if (idx < BANDC) arow[idx] = f2bf(vals[t] * inv);
  }
}

__global__ __launch_bounds__(256) void av_gemm(
    const ushort* __restrict__ aband, const ushort* __restrict__ VT,
    ushort* __restrict__ cbuf)
{
  const int nid = (blockIdx.x & 7) * 128 + (blockIdx.x >> 3); // 1024 blocks
  const int by = nid >> 3;            // 0..127: (b,i)
  const int b = by >> 5, i = by & 31;
  const int bx = nid & 7;             // d-block
  const int jj_lo = (i < 2) ? (2 - i) : 0;
  const int jj_hi = (i > 29) ? (34 - i) : 5;
  __shared__ ushort lds[16384];
  f32x4 acc[4][4];
  ACC_ZERO(acc)
  const ushort* Ablk = aband + ((size_t)b * S_LEN + i * 128) * BANDC;
  const ushort* Bblk = VT + (size_t)b * DIM * S_LEN + (size_t)bx * 128 * S_LEN + (i - 2) * 128;
  gemm_core(Ablk, BANDC, Bblk, S_LEN, jj_lo * 128, jj_hi * 128, lds, acc);
  EPI_BEGIN(acc)
    int row = b * S_LEN + i * 128 + rloc;
    int col = bx * 128 + cloc;
    cbuf[(size_t)row * DIM + col] = f2bf(aval);
  EPI_END()
}

// ---------------- norm / head ----------------
__global__ __launch_bounds__(256) void ln_kernel(const float* __restrict__ y0, ushort* __restrict__ y1,
                                                 const float* __restrict__ gamma, const float* __restrict__ beta)
{
  __shared__ float red[4];
  const size_t q = blockIdx.x;
  const float* row = y0 + q * DIM;
  float v[4];
  #pragma unroll
  for (int t = 0; t < 4; t++) v[t] = row[threadIdx.x + t * 256];
  float mean = block_sum(v[0] + v[1] + v[2] + v[3], red) * (1.0f / DIM);
  float q2 = 0.0f;
  #pragma unroll
  for (int t = 0; t < 4; t++) { float d = v[t] - mean; q2 += d * d; }
  float var = block_sum(q2, red) * (1.0f / DIM);
  float rstd = rsqrtf(var + 1e-6f);
  #pragma unroll
  for (int t = 0; t < 4; t++) {
    int d = threadIdx.x + t * 256;
    y1[q * DIM + d] = f2bf((v[t] - mean) * rstd * gamma[d] + beta[d]);
  }
}

__global__ __launch_bounds__(256) void head_kernel(const float* __restrict__ h0,
    const float* __restrict__ gamma, const float* __restrict__ beta,
    const float* __restrict__ W2, const float* __restrict__ b2,
    float* __restrict__ out)
{
  __shared__ float red[4];
  const int qg = blockIdx.x;
  const int b = qg >> 12, s = qg & 4095;
  const float* row = h0 + (size_t)qg * DIM;
  float v[4];
  #pragma unroll
  for (int t = 0; t < 4; t++) v[t] = row[threadIdx.x + t * 256];
  float mean = block_sum(v[0] + v[1] + v[2] + v[3], red) * (1.0f / DIM);
  float q2 = 0.0f;
  #pragma unroll
  for (int t = 0; t < 4; t++) { float d = v[t] - mean; q2 += d * d; }
  float var = block_sum(q2, red) * (1.0f / DIM);
  float rstd = rsqrtf(var + 1e-6f);
  float part = 0.0f;
  #pragma unroll
  for (int t = 0; t < 4; t++) {
    int d = threadIdx.x + t * 256;
    part += ((v[t] - mean) * rstd * gamma[d] + beta[d]) * W2[d];
  }
  float logit = block_sum(part, red) + b2[0];
  if (threadIdx.x == 0) out[(size_t)s * BATCH + b] = 1.0f / (1.0f + expf(-logit));
}

// ---------------- launch ----------------
extern "C" void kernel_launch(void* const* d_in, const int* in_sizes, int n_in,
                              void* d_out, int out_size, void* d_ws, size_t ws_size,
                              hipStream_t stream) {
  const float* x     = (const float*)d_in[0];
  const float* Wk    = (const float*)d_in[1];
  const float* Wq    = (const float*)d_in[2];
  const float* Wv    = (const float*)d_in[3];
  const float* Wp    = (const float*)d_in[4];
  const float* W1    = (const float*)d_in[5];
  const float* b1    = (const float*)d_in[6];
  const float* W2    = (const float*)d_in[7];
  const float* b2    = (const float*)d_in[8];
  const float* gamma = (const float*)d_in[9];
  const float* beta  = (const float*)d_in[10];
  float* out = (float*)d_out;

  char* w = (char*)d_ws;
  ushort* xb   = (ushort*)(w + 0);            // 33,554,432 B
  ushort* wqkv = (ushort*)(w + 33554432);     //  6,291,456 B
  ushort* wpb  = (ushort*)(w + 39845888);     //  2,097,152 B
  ushort* w1b  = (ushort*)(w + 41943040);     //  2,097,152 B
  ushort* Qp   = (ushort*)(w + 44040192);     // 33,554,432 B
  ushort* Kp   = (ushort*)(w + 77594624);     // 33,554,432 B
  ushort* Vp   = (ushort*)(w + 111149056);    // 33,554,432 B
  ushort* VT   = (ushort*)(w + 144703488);    // 33,554,432 B
  float*  big  = (float*)(w + 178257920);     // 67,108,864 B (eband -> y0 -> h0)
  // reuse (sequentially dead regions):
  ushort* aband = Qp;     // Q dead after scores
  ushort* cbuf  = Kp;     // K dead after scores
  ushort* y1    = Vp;     // V dead after transpose
  float* eband = big;
  float* y0    = big;
  float* h0    = big;

  prep_x<<<16384, 256, 0, stream>>>(x, xb);
  f2bf_vec<<<1024, 256, 0, stream>>>(Wk, wqkv,            1048576);
  f2bf_vec<<<1024, 256, 0, stream>>>(Wq, wqkv + 1048576,  1048576);
  f2bf_vec<<<1024, 256, 0, stream>>>(Wv, wqkv + 2097152,  1048576);
  f2bf_vec<<<1024, 256, 0, stream>>>(Wp, wpb, 1048576);
  f2bf_vec<<<1024, 256, 0, stream>>>(W1, w1b, 1048576);

  qkv_gemm256<<<768, 512, 0, stream>>>(xb, wqkv, Kp, Qp, Vp);
  transpose_v<<<dim3(64, 16, 4), 256, 0, stream>>>(Vp, VT);
  scores_gemm<<<640, 256, 0, stream>>>(Qp, Kp, eband);
  softmax_band<<<16384, 256, 0, stream>>>(eband, aband);
  av_gemm<<<1024, 256, 0, stream>>>(aband, VT, cbuf);
  wp_gemm256<<<256, 512, 0, stream>>>(cbuf, wpb, x, y0);
  ln_kernel<<<16384, 256, 0, stream>>>(y0, y1, gamma, beta);
  ffn1_gemm256<<<256, 512, 0, stream>>>(y1, w1b, b1, h0);
  head_kernel<<<16384, 256, 0, stream>>>(h0, gamma, beta, W2, b2, out);
}

// Round 6
// 383.362 us; speedup vs baseline: 5.0208x; 1.0047x over previous
//
#include <hip/hip_runtime.h>
#include <stdint.h>
#include <math.h>

// ---------------- problem constants ----------------
#define S_LEN 4096
#define BATCH 4
#define DIM   1024
#define AP    256
#define NBLK  32            // S_LEN/128 row-blocks per batch
#define BANDC 640           // 5*128 band columns
#define SCALE 0.03125f      // 1/sqrt(1024)

typedef __attribute__((ext_vector_type(4))) float f32x4;
typedef __attribute__((ext_vector_type(8))) short bf16x8;

// ---------------- helpers ----------------
__device__ __forceinline__ ushort f2bf(float f) {
  union { float f; uint32_t u; } v; v.f = f;
  uint32_t r = v.u + 0x7FFFu + ((v.u >> 16) & 1u);
  return (ushort)(r >> 16);
}

__device__ __forceinline__ void gload16(const void* g, void* l) {
  __builtin_amdgcn_global_load_lds((const __attribute__((address_space(1))) void*)g,
                                   (__attribute__((address_space(3))) void*)l,
                                   16, 0, 0);
}

__device__ __forceinline__ float block_sum(float v, float* red) {
  #pragma unroll
  for (int o = 32; o > 0; o >>= 1) v += __shfl_xor(v, o, 64);
  const int w = threadIdx.x >> 6;
  if ((threadIdx.x & 63) == 0) red[w] = v;
  __syncthreads();
  v = red[0] + red[1] + red[2] + red[3];
  __syncthreads();
  return v;
}

__device__ __forceinline__ float block_max(float v, float* red) {
  #pragma unroll
  for (int o = 32; o > 0; o >>= 1) v = fmaxf(v, __shfl_xor(v, o, 64));
  const int w = threadIdx.x >> 6;
  if ((threadIdx.x & 63) == 0) red[w] = v;
  __syncthreads();
  v = fmaxf(fmaxf(red[0], red[1]), fmaxf(red[2], red[3]));
  __syncthreads();
  return v;
}

// =====================================================================
// 256x256 4-phase/K-tile GEMM core (T2+T3+T4+T5):
//  512 thr = 8 waves (2M x 4N), per-wave C = 128x64, acc[8][4] f32x4.
//  BK=64 as two [256][32] slabs per operand; 2 LDS buffers (tile parity)
//  of 64 KB each = 128 KiB -> 1 block/CU.
//  Phase = {ds_read subtile ; stage 1 unit (2 gload_lds) ; [vmcnt] ;
//           s_barrier ; lgkmcnt(0) ; sched_barrier ; setprio(1) ;
//           16 MFMA ; setprio(0) ; sched_barrier ; s_barrier}.
//  vmcnt DISCIPLINE (round-5 bug fix): vmcnt is per-wave, staging is
//  cooperative -> every counted vmcnt must be followed by s_barrier
//  BEFORE the dependent ds_reads. Waits sit at phases 1 & 3 (and one
//  pre-loop), never directly before reads. vmcnt(4) counts: 2 loads per
//  STAGE2, newest 4 = the 2 units staged after the certified ones.
//  Quarter-wave conflict-free swizzle (verified conflicts=0): LDS slot
//  (row,s) holds global seg s^((row>>1)&3); source pre-swizzled, read
//  swizzled, LDS dest linear (global_load_lds requirement).
//  A: row-major [256 x K] (lda); B: row-major [256 n-rows x K] = B^T.
//  Requires K % 64 == 0, K >= 128.
// =====================================================================
#define STAGE2(dstbase, g0, g1, kcol) \
  gload16((g0) + (kcol), lds + (dstbase) + stOff); \
  gload16((g1) + (kcol), lds + (dstbase) + 4096 + stOff);

#define MFMA_QUAD(arow, bvec) \
  _Pragma("unroll") for (int m = 0; m < 4; ++m) \
  _Pragma("unroll") for (int n = 0; n < 4; ++n) \
    acc[(arow) + m][n] = __builtin_amdgcn_mfma_f32_16x16x32_bf16(a[m], bvec[n], acc[(arow) + m][n], 0, 0, 0);

#define PHASE_TAIL() \
  __builtin_amdgcn_s_barrier(); \
  asm volatile("s_waitcnt lgkmcnt(0)" ::: "memory"); \
  __builtin_amdgcn_sched_barrier(0); \
  __builtin_amdgcn_s_setprio(1);

#define PHASE_END() \
  __builtin_amdgcn_s_setprio(0); \
  __builtin_amdgcn_sched_barrier(0); \
  __builtin_amdgcn_s_barrier();

__device__ __forceinline__ void gemm256_core(
    const ushort* __restrict__ Ablk, int lda,
    const ushort* __restrict__ Bblk, int ldb,
    int K, ushort* __restrict__ lds,
    f32x4 acc[8][4])
{
  const int tid  = threadIdx.x;
  const int lane = tid & 63;
  const int wave = tid >> 6;
  const int wr = wave >> 2;       // 0..1
  const int wn = wave & 3;        // 0..3

  // staging: thread covers (srow = tid>>2, slot = tid&3); source pre-swizzled
  const int srow = tid >> 2;                       // 0..127
  const int gseg = (tid & 3) ^ ((tid >> 3) & 3);   // slot ^ ((srow>>1)&3)
  const ushort* gA0 = Ablk + (size_t)srow * lda + gseg * 8;
  const ushort* gA1 = Ablk + (size_t)(srow + 128) * lda + gseg * 8;
  const ushort* gB0 = Bblk + (size_t)srow * ldb + gseg * 8;
  const ushort* gB1 = Bblk + (size_t)(srow + 128) * ldb + gseg * 8;
  const int stOff = wave * 512;                    // wave-uniform LDS base (ushorts)

  // swizzled ds_read addressing
  const int l15 = lane & 15;
  const int seg = (lane >> 4) ^ ((lane >> 1) & 3); // kseg ^ ((row>>1)&3)
  const int raBase = (wr * 128 + l15) * 32 + seg * 8;   // + m*512
  const int rbBase = (wn * 64  + l15) * 32 + seg * 8;   // + n*512

  const int NT = K >> 6;   // BK = 64

  // buffer layout (ushorts): A-slab0 @0, A-slab1 @8192, B-slab0 @16384, B-slab1 @24576
  // prologue: stage all 4 units of tile 0 into buffer 0, certify slab0
  STAGE2(0,     gA0, gA1, 0)
  STAGE2(16384, gB0, gB1, 0)
  STAGE2(8192,  gA0, gA1, 32)
  STAGE2(24576, gB0, gB1, 32)
  asm volatile("s_waitcnt vmcnt(4)" ::: "memory");   // u0,u1 of tile 0 landed (this wave)
  __builtin_amdgcn_s_barrier();                      // ... and all waves

  for (int t = 0; t < NT; ++t) {
    const int rb = (t & 1) * 32768;          // read buffer
    const int sb = ((t + 1) & 1) * 32768;    // stage buffer
    const int k1 = (t + 1) << 6;
    const bool more = (t + 1 < NT);

    bf16x8 a[4], b0[4], b1[4];

    // ---- phase 0: kk0, m-frags 0-3 (slab0 certified by prior ph3/prologue) ----
    #pragma unroll
    for (int m = 0; m < 4; ++m) a[m] = *(const bf16x8*)(lds + rb + raBase + m * 512);
    #pragma unroll
    for (int n = 0; n < 4; ++n) b0[n] = *(const bf16x8*)(lds + rb + 16384 + rbBase + n * 512);
    if (more) { STAGE2(sb, gA0, gA1, k1) }              // u0: A-slab0 of t+1
    PHASE_TAIL()
    MFMA_QUAD(0, b0)
    PHASE_END()

    // ---- phase 1: kk0, m-frags 4-7 ; certify slab1 of tile t ----
    #pragma unroll
    for (int m = 0; m < 4; ++m) a[m] = *(const bf16x8*)(lds + rb + raBase + (m + 4) * 512);
    if (more) {
      STAGE2(sb + 16384, gB0, gB1, k1)                  // u1: B-slab0 of t+1
      asm volatile("s_waitcnt vmcnt(4)" ::: "memory");  // u2,u3 of t landed
    } else {
      asm volatile("s_waitcnt vmcnt(0)" ::: "memory");
    }
    PHASE_TAIL()
    MFMA_QUAD(4, b0)
    PHASE_END()

    // ---- phase 2: kk1, m-frags 0-3 (slab1 certified by ph1 vmcnt+barrier) ----
    #pragma unroll
    for (int m = 0; m < 4; ++m) a[m] = *(const bf16x8*)(lds + rb + 8192 + raBase + m * 512);
    #pragma unroll
    for (int n = 0; n < 4; ++n) b1[n] = *(const bf16x8*)(lds + rb + 24576 + rbBase + n * 512);
    if (more) { STAGE2(sb + 8192, gA0, gA1, k1 + 32) }  // u2: A-slab1 of t+1
    PHASE_TAIL()
    MFMA_QUAD(0, b1)
    PHASE_END()

    // ---- phase 3: kk1, m-frags 4-7 ; certify slab0 of tile t+1 ----
    #pragma unroll
    for (int m = 0; m < 4; ++m) a[m] = *(const bf16x8*)(lds + rb + 8192 + raBase + (m + 4) * 512);
    if (more) {
      STAGE2(sb + 24576, gB0, gB1, k1 + 32)             // u3: B-slab1 of t+1
      asm volatile("s_waitcnt vmcnt(4)" ::: "memory");  // u0,u1 of t+1 landed
    }
    PHASE_TAIL()
    MFMA_QUAD(4, b1)
    PHASE_END()
  }
}

#define ACC256_ZERO(acc) \
  _Pragma("unroll") for (int m_ = 0; m_ < 8; m_++) \
  _Pragma("unroll") for (int n_ = 0; n_ < 4; n_++) \
  _Pragma("unroll") for (int r_ = 0; r_ < 4; r_++) acc[m_][n_][r_] = 0.0f;

#define EPI256_BEGIN(acc) { \
  const int lane_ = threadIdx.x & 63; \
  const int wave_ = threadIdx.x >> 6; \
  const int wrb_ = (wave_ >> 2) * 128; \
  const int wnb_ = (wave_ & 3) * 64; \
  const int rb_ = (lane_ >> 4) << 2; \
  const int cb_ = lane_ & 15; \
  _Pragma("unroll") for (int m_ = 0; m_ < 8; m_++) \
  _Pragma("unroll") for (int n_ = 0; n_ < 4; n_++) \
  _Pragma("unroll") for (int r_ = 0; r_ < 4; r_++) { \
    const int rloc = wrb_ + m_ * 16 + rb_ + r_; \
    const int cloc = wnb_ + n_ * 16 + cb_; \
    const float aval = acc[m_][n_][r_];
#define EPI256_END() } }

// =====================================================================
// 128x128 GEMM core (scores/av): 256 thr = 4 waves (2x2), dbuf 2x16KB=32KB,
// depth-1 prefetch, counted vmcnt(4), one barrier/step, same swizzle.
// Layout per buf (ushorts): A [128][32] at 0, B [128][32] at 4096.
// =====================================================================
__device__ __forceinline__ void gemm_core(
    const ushort* __restrict__ Ablk, int lda,
    const ushort* __restrict__ Bblk, int ldb,
    int k_begin, int k_end,
    ushort* __restrict__ lds,
    f32x4 acc[4][4])
{
  const int tid  = threadIdx.x;
  const int lane = tid & 63;
  const int wr = ((tid >> 7) & 1) * 64;
  const int wc = ((tid >> 6) & 1) * 64;
  const int lr = lane & 15;
  const int seg = (lane >> 4) ^ ((lane >> 1) & 3);

  const int srow = tid >> 2;                       // 0..63
  const int gseg = (tid & 3) ^ ((tid >> 3) & 3);
  const ushort* gA0 = Ablk + (size_t)srow * lda + gseg * 8;
  const ushort* gA1 = Ablk + (size_t)(srow + 64) * lda + gseg * 8;
  const ushort* gB0 = Bblk + (size_t)srow * ldb + gseg * 8;
  const ushort* gB1 = Bblk + (size_t)(srow + 64) * ldb + gseg * 8;
  const int stA = (tid >> 6) * 512;                // wave-uniform base (ushorts)

  const int NT = (k_end - k_begin) >> 5;

  gload16(gA0 + k_begin, lds + stA);
  gload16(gA1 + k_begin, lds + 2048 + stA);
  gload16(gB0 + k_begin, lds + 4096 + stA);
  gload16(gB1 + k_begin, lds + 6144 + stA);

  for (int t = 0; t < NT; ++t) {
    if (t + 1 < NT) {
      ushort* buf = lds + ((t + 1) & 1) * 8192;
      const int k0 = k_begin + (t + 1) * 32;
      gload16(gA0 + k0, buf + stA);
      gload16(gA1 + k0, buf + 2048 + stA);
      gload16(gB0 + k0, buf + 4096 + stA);
      gload16(gB1 + k0, buf + 6144 + stA);
      asm volatile("s_waitcnt vmcnt(4)" ::: "memory");
    } else {
      asm volatile("s_waitcnt vmcnt(0)" ::: "memory");
    }
    __builtin_amdgcn_s_barrier();

    const ushort* buf = lds + (t & 1) * 8192;
    bf16x8 af[4], bfv[4];
    #pragma unroll
    for (int m = 0; m < 4; m++)
      af[m] = *(const bf16x8*)(buf + (wr + m * 16 + lr) * 32 + seg * 8);
    #pragma unroll
    for (int n = 0; n < 4; n++)
      bfv[n] = *(const bf16x8*)(buf + 4096 + (wc + n * 16 + lr) * 32 + seg * 8);

    __builtin_amdgcn_s_setprio(1);
    #pragma unroll
    for (int m = 0; m < 4; m++)
      #pragma unroll
      for (int n = 0; n < 4; n++)
        acc[m][n] = __builtin_amdgcn_mfma_f32_16x16x32_bf16(af[m], bfv[n], acc[m][n], 0, 0, 0);
    __builtin_amdgcn_s_setprio(0);
    asm volatile("s_waitcnt lgkmcnt(0)" ::: "memory");
  }
}

#define ACC_ZERO(acc) \
  _Pragma("unroll") for (int m_ = 0; m_ < 4; m_++) \
  _Pragma("unroll") for (int n_ = 0; n_ < 4; n_++) \
  _Pragma("unroll") for (int r_ = 0; r_ < 4; r_++) acc[m_][n_][r_] = 0.0f;

#define EPI_BEGIN(acc) { \
  const int lane_ = threadIdx.x & 63; \
  const int wr_ = ((threadIdx.x >> 7) & 1) * 64; \
  const int wc_ = ((threadIdx.x >> 6) & 1) * 64; \
  const int rb_ = (lane_ >> 4) << 2; \
  const int cb_ = lane_ & 15; \
  _Pragma("unroll") for (int m_ = 0; m_ < 4; m_++) \
  _Pragma("unroll") for (int n_ = 0; n_ < 4; n_++) \
  _Pragma("unroll") for (int r_ = 0; r_ < 4; r_++) { \
    const int rloc = wr_ + m_ * 16 + rb_ + r_; \
    const int cloc = wc_ + n_ * 16 + cb_; \
    const float aval = acc[m_][n_][r_];
#define EPI_END() } }

// ---------------- elementwise prep kernels ----------------
__global__ __launch_bounds__(256) void prep_x(const float* __restrict__ x, ushort* __restrict__ xb) {
  size_t idx = ((size_t)blockIdx.x * 256 + threadIdx.x) * 4;   // dest flat index (b,s,d)
  int d = (int)(idx & 1023);
  int s = (int)((idx >> 10) & 4095);
  int b = (int)(idx >> 22);
  float4 v = *(const float4*)(x + ((size_t)s * BATCH + b) * DIM + d);
  ushort4 o;
  o.x = f2bf(v.x); o.y = f2bf(v.y); o.z = f2bf(v.z); o.w = f2bf(v.w);
  *(ushort4*)(xb + idx) = o;
}

__global__ __launch_bounds__(256) void f2bf_vec(const float* __restrict__ src, ushort* __restrict__ dst, int n) {
  int idx = (blockIdx.x * 256 + threadIdx.x) * 4;
  if (idx >= n) return;
  float4 v = *(const float4*)(src + idx);
  ushort4 o;
  o.x = f2bf(v.x); o.y = f2bf(v.y); o.z = f2bf(v.z); o.w = f2bf(v.w);
  *(ushort4*)(dst + idx) = o;
}

// ---------------- big GEMMs on the 256 core ----------------
__global__ __launch_bounds__(512, 2) void qkv_gemm256(
    const ushort* __restrict__ xb, const ushort* __restrict__ wqkv,
    ushort* __restrict__ Kp, ushort* __restrict__ Qp, ushort* __restrict__ Vp)
{
  __shared__ ushort lds[65536];
  // XCD-chunked swizzle: 768 blocks, 96 contiguous tiles per XCD
  const int nid = (blockIdx.x & 7) * 96 + (blockIdx.x >> 3);
  const int by = nid / 12;     // 0..63
  const int bx = nid % 12;     // 0..11
  f32x4 acc[8][4];
  ACC256_ZERO(acc)
  gemm256_core(xb + (size_t)by * 256 * DIM, DIM,
               wqkv + (size_t)bx * 256 * DIM, DIM, DIM, lds, acc);
  ushort* dst = (bx < 4) ? Kp : (bx < 8) ? Qp : Vp;
  const int colb = (bx & 3) * 256;
  EPI256_BEGIN(acc)
    int row = by * 256 + rloc;
    int col = colb + cloc;
    dst[(size_t)row * DIM + col] = f2bf(aval);
  EPI256_END()
}

__global__ __launch_bounds__(512, 2) void wp_gemm256(
    const ushort* __restrict__ cbuf, const ushort* __restrict__ wpb,
    const float* __restrict__ x, float* __restrict__ y0)
{
  __shared__ ushort lds[65536];
  const int nid = (blockIdx.x & 7) * 32 + (blockIdx.x >> 3);   // 256 blocks
  const int by = nid >> 2;     // 0..63
  const int bx = nid & 3;      // 0..3
  f32x4 acc[8][4];
  ACC256_ZERO(acc)
  gemm256_core(cbuf + (size_t)by * 256 * DIM, DIM,
               wpb + (size_t)bx * 256 * DIM, DIM, DIM, lds, acc);
  EPI256_BEGIN(acc)
    int row = by * 256 + rloc;           // b*4096+s
    int col = bx * 256 + cloc;
    int b = row >> 12, s = row & 4095;
    y0[(size_t)row * DIM + col] = aval + x[((size_t)s * BATCH + b) * DIM + col];
  EPI256_END()
}

__global__ __launch_bounds__(512, 2) void ffn1_gemm256(
    const ushort* __restrict__ y1, const ushort* __restrict__ w1b,
    const float* __restrict__ b1, float* __restrict__ h0)
{
  __shared__ ushort lds[65536];
  const int nid = (blockIdx.x & 7) * 32 + (blockIdx.x >> 3);
  const int by = nid >> 2;
  const int bx = nid & 3;
  f32x4 acc[8][4];
  ACC256_ZERO(acc)
  gemm256_core(y1 + (size_t)by * 256 * DIM, DIM,
               w1b + (size_t)bx * 256 * DIM, DIM, DIM, lds, acc);
  EPI256_BEGIN(acc)
    int row = by * 256 + rloc;
    int col = bx * 256 + cloc;
    h0[(size_t)row * DIM + col] = fmaxf(aval + b1[col], 0.0f);
  EPI256_END()
}

// ---------------- attention path (128 core) ----------------
__global__ __launch_bounds__(256) void transpose_v(const ushort* __restrict__ V, ushort* __restrict__ VT) {
  __shared__ ushort tile[64][66];
  const int s0 = blockIdx.x * 64, d0 = blockIdx.y * 64, b = blockIdx.z;
  const ushort* Vb = V + (size_t)b * S_LEN * DIM;
  ushort* VTb = VT + (size_t)b * DIM * S_LEN;
  #pragma unroll
  for (int it = 0; it < 16; it++) {
    int flat = it * 256 + threadIdx.x;
    int r = flat >> 6, c = flat & 63;
    tile[r][c] = Vb[(size_t)(s0 + r) * DIM + d0 + c];
  }
  __syncthreads();
  #pragma unroll
  for (int it = 0; it < 16; it++) {
    int flat = it * 256 + threadIdx.x;
    int r = flat >> 6, c = flat & 63;      // r = d-local, c = s-local
    VTb[(size_t)(d0 + r) * S_LEN + s0 + c] = tile[c][r];
  }
}

__global__ __launch_bounds__(256) void scores_gemm(
    const ushort* __restrict__ Qp, const ushort* __restrict__ Kp,
    float* __restrict__ eband)
{
  const int nid = (blockIdx.x & 7) * 80 + (blockIdx.x >> 3);   // 640 blocks
  const int b   = nid / 160;
  const int rem = nid % 160;
  const int i   = rem / 5;
  const int jj  = rem % 5;
  const int j   = i - 2 + jj;
  if (j < 0 || j >= NBLK) return;
  __shared__ ushort lds[16384];
  f32x4 acc[4][4];
  ACC_ZERO(acc)
  gemm_core(Qp + ((size_t)b * S_LEN + i * 128) * DIM, DIM,
            Kp + ((size_t)b * S_LEN + j * 128) * DIM, DIM, 0, DIM, lds, acc);
  EPI_BEGIN(acc)
    int q = i * 128 + rloc;
    int k = j * 128 + cloc;
    float v = aval * SCALE;
    int dqk = q - k;
    if (dqk == 0 || dqk > AP || dqk < -AP) v = -INFINITY;
    eband[((size_t)b * S_LEN + q) * BANDC + jj * 128 + cloc] = v;
  EPI_END()
}

__global__ __launch_bounds__(256) void softmax_band(const float* __restrict__ eband,
                                                    ushort* __restrict__ aband)
{
  __shared__ float red[4];
  const int qg = blockIdx.x;          // 0..16383
  const int s  = qg & 4095;
  const int i  = s >> 7;
  const float* row = eband + (size_t)qg * BANDC;
  ushort* arow = aband + (size_t)qg * BANDC;

  float vals[3];
  bool  valid[3];
  float mx = -INFINITY;
  #pragma unroll
  for (int t = 0; t < 3; t++) {
    int idx = threadIdx.x + t * 256;
    int jj = idx >> 7;
    int j = i - 2 + jj;
    bool ok = (idx < BANDC) && (j >= 0) && (j < NBLK);
    valid[t] = ok;
    float v = ok ? row[idx] : -INFINITY;
    vals[t] = v;
    mx = fmaxf(mx, v);
  }
  float bmax = block_max(mx, red);
  float ss = 0.0f;
  #pragma unroll
  for (int t = 0; t < 3; t++) {
    float e = valid[t] ? __expf(vals[t] - bmax) : 0.0f;
    vals[t] = e;
    ss += e;
  }
  float inv = 1.0f / block_sum(ss, red);
  #pragma unroll
  for (int t = 0; t < 3; t++) {
    int idx = threadIdx.x + t * 256;
    if (idx < BANDC) arow[idx] = f2bf(vals[t] * inv);
  }
}

__global__ __launch_bounds__(256) void av_gemm(
    const ushort* __restrict__ aband, const ushort* __restrict__ VT,
    ushort* __restrict__ cbuf)
{
  const int nid = (blockIdx.x & 7) * 128 + (blockIdx.x >> 3); // 1024 blocks
  const int by = nid >> 3;            // 0..127: (b,i)
  const int b = by >> 5, i = by & 31;
  const int bx = nid & 7;             // d-block
  const int jj_lo = (i < 2) ? (2 - i) : 0;
  const int jj_hi = (i > 29) ? (34 - i) : 5;
  __shared__ ushort lds[16384];
  f32x4 acc[4][4];
  ACC_ZERO(acc)
  const ushort* Ablk = aband + ((size_t)b * S_LEN + i * 128) * BANDC;
  const ushort* Bblk = VT + (size_t)b * DIM * S_LEN + (size_t)bx * 128 * S_LEN + (i - 2) * 128;
  gemm_core(Ablk, BANDC, Bblk, S_LEN, jj_lo * 128, jj_hi * 128, lds, acc);
  EPI_BEGIN(acc)
    int row = b * S_LEN + i * 128 + rloc;
    int col = bx * 128 + cloc;
    cbuf[(size_t)row * DIM + col] = f2bf(aval);
  EPI_END()
}

// ---------------- norm / head ----------------
__global__ __launch_bounds__(256) void ln_kernel(const float* __restrict__ y0, ushort* __restrict__ y1,
                                                 const float* __restrict__ gamma, const float* __restrict__ beta)
{
  __shared__ float red[4];
  const size_t q = blockIdx.x;
  const float* row = y0 + q * DIM;
  float v[4];
  #pragma unroll
  for (int t = 0; t < 4; t++) v[t] = row[threadIdx.x + t * 256];
  float mean = block_sum(v[0] + v[1] + v[2] + v[3], red) * (1.0f / DIM);
  float q2 = 0.0f;
  #pragma unroll
  for (int t = 0; t < 4; t++) { float d = v[t] - mean; q2 += d * d; }
  float var = block_sum(q2, red) * (1.0f / DIM);
  float rstd = rsqrtf(var + 1e-6f);
  #pragma unroll
  for (int t = 0; t < 4; t++) {
    int d = threadIdx.x + t * 256;
    y1[q * DIM + d] = f2bf((v[t] - mean) * rstd * gamma[d] + beta[d]);
  }
}

__global__ __launch_bounds__(256) void head_kernel(const float* __restrict__ h0,
    const float* __restrict__ gamma, const float* __restrict__ beta,
    const float* __restrict__ W2, const float* __restrict__ b2,
    float* __restrict__ out)
{
  __shared__ float red[4];
  const int qg = blockIdx.x;
  const int b = qg >> 12, s = qg & 4095;
  const float* row = h0 + (size_t)qg * DIM;
  float v[4];
  #pragma unroll
  for (int t = 0; t < 4; t++) v[t] = row[threadIdx.x + t * 256];
  float mean = block_sum(v[0] + v[1] + v[2] + v[3], red) * (1.0f / DIM);
  float q2 = 0.0f;
  #pragma unroll
  for (int t = 0; t < 4; t++) { float d = v[t] - mean; q2 += d * d; }
  float var = block_sum(q2, red) * (1.0f / DIM);
  float rstd = rsqrtf(var + 1e-6f);
  float part = 0.0f;
  #pragma unroll
  for (int t = 0; t < 4; t++) {
    int d = threadIdx.x + t * 256;
    part += ((v[t] - mean) * rstd * gamma[d] + beta[d]) * W2[d];
  }
  float logit = block_sum(part, red) + b2[0];
  if (threadIdx.x == 0) out[(size_t)s * BATCH + b] = 1.0f / (1.0f + expf(-logit));
}

// ---------------- launch ----------------
extern "C" void kernel_launch(void* const* d_in, const int* in_sizes, int n_in,
                              void* d_out, int out_size, void* d_ws, size_t ws_size,
                              hipStream_t stream) {
  const float* x     = (const float*)d_in[0];
  const float* Wk    = (const float*)d_in[1];
  const float* Wq    = (const float*)d_in[2];
  const float* Wv    = (const float*)d_in[3];
  const float* Wp    = (const float*)d_in[4];
  const float* W1    = (const float*)d_in[5];
  const float* b1    = (const float*)d_in[6];
  const float* W2    = (const float*)d_in[7];
  const float* b2    = (const float*)d_in[8];
  const float* gamma = (const float*)d_in[9];
  const float* beta  = (const float*)d_in[10];
  float* out = (float*)d_out;

  char* w = (char*)d_ws;
  ushort* xb   = (ushort*)(w + 0);            // 33,554,432 B
  ushort* wqkv = (ushort*)(w + 33554432);     //  6,291,456 B
  ushort* wpb  = (ushort*)(w + 39845888);     //  2,097,152 B
  ushort* w1b  = (ushort*)(w + 41943040);     //  2,097,152 B
  ushort* Qp   = (ushort*)(w + 44040192);     // 33,554,432 B
  ushort* Kp   = (ushort*)(w + 77594624);     // 33,554,432 B
  ushort* Vp   = (ushort*)(w + 111149056);    // 33,554,432 B
  ushort* VT   = (ushort*)(w + 144703488);    // 33,554,432 B
  float*  big  = (float*)(w + 178257920);     // 67,108,864 B (eband -> y0 -> h0)
  // reuse (sequentially dead regions):
  ushort* aband = Qp;     // Q dead after scores
  ushort* cbuf  = Kp;     // K dead after scores
  ushort* y1    = Vp;     // V dead after transpose
  float* eband = big;
  float* y0    = big;
  float* h0    = big;

  prep_x<<<16384, 256, 0, stream>>>(x, xb);
  f2bf_vec<<<1024, 256, 0, stream>>>(Wk, wqkv,            1048576);
  f2bf_vec<<<1024, 256, 0, stream>>>(Wq, wqkv + 1048576,  1048576);
  f2bf_vec<<<1024, 256, 0, stream>>>(Wv, wqkv + 2097152,  1048576);
  f2bf_vec<<<1024, 256, 0, stream>>>(Wp, wpb, 1048576);
  f2bf_vec<<<1024, 256, 0, stream>>>(W1, w1b, 1048576);

  qkv_gemm256<<<768, 512, 0, stream>>>(xb, wqkv, Kp, Qp, Vp);
  transpose_v<<<dim3(64, 16, 4), 256, 0, stream>>>(Vp, VT);
  scores_gemm<<<640, 256, 0, stream>>>(Qp, Kp, eband);
  softmax_band<<<16384, 256, 0, stream>>>(eband, aband);
  av_gemm<<<1024, 256, 0, stream>>>(aband, VT, cbuf);
  wp_gemm256<<<256, 512, 0, stream>>>(cbuf, wpb, x, y0);
  ln_kernel<<<16384, 256, 0, stream>>>(y0, y1, gamma, beta);
  ffn1_gemm256<<<256, 512, 0, stream>>>(y1, w1b, b1, h0);
  head_kernel<<<16384, 256, 0, stream>>>(h0, gamma, beta, W2, b2, out);
}

// Round 7
// 377.530 us; speedup vs baseline: 5.0984x; 1.0154x over previous
//
#include <hip/hip_runtime.h>
#include <stdint.h>
#include <math.h>

// ---------------- problem constants ----------------
#define S_LEN 4096
#define BATCH 4
#define DIM   1024
#define AP    256
#define NBLK  32            // S_LEN/128 row-blocks per batch
#define BANDC 640           // 5*128 band columns
#define SCALE 0.03125f      // 1/sqrt(1024)

typedef __attribute__((ext_vector_type(4))) float f32x4;
typedef __attribute__((ext_vector_type(8))) short bf16x8;

// ---------------- helpers ----------------
__device__ __forceinline__ ushort f2bf(float f) {
  union { float f; uint32_t u; } v; v.f = f;
  uint32_t r = v.u + 0x7FFFu + ((v.u >> 16) & 1u);
  return (ushort)(r >> 16);
}

__device__ __forceinline__ void gload16(const void* g, void* l) {
  __builtin_amdgcn_global_load_lds((const __attribute__((address_space(1))) void*)g,
                                   (__attribute__((address_space(3))) void*)l,
                                   16, 0, 0);
}

__device__ __forceinline__ float block_sum(float v, float* red) {
  #pragma unroll
  for (int o = 32; o > 0; o >>= 1) v += __shfl_xor(v, o, 64);
  const int w = threadIdx.x >> 6;
  if ((threadIdx.x & 63) == 0) red[w] = v;
  __syncthreads();
  v = red[0] + red[1] + red[2] + red[3];
  __syncthreads();
  return v;
}

__device__ __forceinline__ float block_max(float v, float* red) {
  #pragma unroll
  for (int o = 32; o > 0; o >>= 1) v = fmaxf(v, __shfl_xor(v, o, 64));
  const int w = threadIdx.x >> 6;
  if ((threadIdx.x & 63) == 0) red[w] = v;
  __syncthreads();
  v = fmaxf(fmaxf(red[0], red[1]), fmaxf(red[2], red[3]));
  __syncthreads();
  return v;
}

// =====================================================================
// 256x256 4-phase/K-tile GEMM core (T2+T3+T4+T5):
//  512 thr = 8 waves (2M x 4N), per-wave C = 128x64, acc[8][4] f32x4.
//  BK=64 as two [256][32] slabs per operand; 2 LDS buffers (tile parity)
//  of 64 KB each = 128 KiB -> 1 block/CU.
//  Phase = {ds_read subtile ; stage 1 unit (2 gload_lds) ; [vmcnt] ;
//           s_barrier ; lgkmcnt(0) ; setprio(1) ; 16 MFMA ; setprio(0) ;
//           s_barrier}.  NO sched_barrier: ds_reads are C-level loads so
//  data-deps are modeled; pinning serialized LDS vs MFMA pipes (r6 37%).
//  vmcnt DISCIPLINE: vmcnt is per-wave, staging cooperative -> every
//  counted vmcnt followed by s_barrier BEFORE dependent ds_reads.
//  Quarter-wave conflict-free swizzle (verified conflicts=0): LDS slot
//  (row,s) holds global seg s^((row>>1)&3); source pre-swizzled, read
//  swizzled, LDS dest linear (global_load_lds requirement).
//  A: row-major [256 x K] (lda); B: row-major [256 n-rows x K] = B^T.
//  Requires K % 64 == 0, K >= 128.
// =====================================================================
#define STAGE2(dstbase, g0, g1, kcol) \
  gload16((g0) + (kcol), lds + (dstbase) + stOff); \
  gload16((g1) + (kcol), lds + (dstbase) + 4096 + stOff);

#define MFMA_QUAD(arow, bvec) \
  _Pragma("unroll") for (int m = 0; m < 4; ++m) \
  _Pragma("unroll") for (int n = 0; n < 4; ++n) \
    acc[(arow) + m][n] = __builtin_amdgcn_mfma_f32_16x16x32_bf16(a[m], bvec[n], acc[(arow) + m][n], 0, 0, 0);

#define PHASE_TAIL() \
  __builtin_amdgcn_s_barrier(); \
  asm volatile("s_waitcnt lgkmcnt(0)" ::: "memory"); \
  __builtin_amdgcn_s_setprio(1);

#define PHASE_END() \
  __builtin_amdgcn_s_setprio(0); \
  __builtin_amdgcn_s_barrier();

__device__ __forceinline__ void gemm256_core(
    const ushort* __restrict__ Ablk, int lda,
    const ushort* __restrict__ Bblk, int ldb,
    int K, ushort* __restrict__ lds,
    f32x4 acc[8][4])
{
  const int tid  = threadIdx.x;
  const int lane = tid & 63;
  const int wave = tid >> 6;
  const int wr = wave >> 2;       // 0..1
  const int wn = wave & 3;        // 0..3

  // staging: thread covers (srow = tid>>2, slot = tid&3); source pre-swizzled
  const int srow = tid >> 2;                       // 0..127
  const int gseg = (tid & 3) ^ ((tid >> 3) & 3);   // slot ^ ((srow>>1)&3)
  const ushort* gA0 = Ablk + (size_t)srow * lda + gseg * 8;
  const ushort* gA1 = Ablk + (size_t)(srow + 128) * lda + gseg * 8;
  const ushort* gB0 = Bblk + (size_t)srow * ldb + gseg * 8;
  const ushort* gB1 = Bblk + (size_t)(srow + 128) * ldb + gseg * 8;
  const int stOff = wave * 512;                    // wave-uniform LDS base (ushorts)

  // swizzled ds_read addressing
  const int l15 = lane & 15;
  const int seg = (lane >> 4) ^ ((lane >> 1) & 3); // kseg ^ ((row>>1)&3)
  const int raBase = (wr * 128 + l15) * 32 + seg * 8;   // + m*512
  const int rbBase = (wn * 64  + l15) * 32 + seg * 8;   // + n*512

  const int NT = K >> 6;   // BK = 64

  // buffer layout (ushorts): A-slab0 @0, A-slab1 @8192, B-slab0 @16384, B-slab1 @24576
  // prologue: stage all 4 units of tile 0 into buffer 0, certify slab0
  STAGE2(0,     gA0, gA1, 0)
  STAGE2(16384, gB0, gB1, 0)
  STAGE2(8192,  gA0, gA1, 32)
  STAGE2(24576, gB0, gB1, 32)
  asm volatile("s_waitcnt vmcnt(4)" ::: "memory");   // u0,u1 of tile 0 landed (this wave)
  __builtin_amdgcn_s_barrier();                      // ... and all waves

  for (int t = 0; t < NT; ++t) {
    const int rb = (t & 1) * 32768;          // read buffer
    const int sb = ((t + 1) & 1) * 32768;    // stage buffer
    const int k1 = (t + 1) << 6;
    const bool more = (t + 1 < NT);

    bf16x8 a[4], b0[4], b1[4];

    // ---- phase 0: kk0, m-frags 0-3 (slab0 certified by prior ph3/prologue) ----
    #pragma unroll
    for (int m = 0; m < 4; ++m) a[m] = *(const bf16x8*)(lds + rb + raBase + m * 512);
    #pragma unroll
    for (int n = 0; n < 4; ++n) b0[n] = *(const bf16x8*)(lds + rb + 16384 + rbBase + n * 512);
    if (more) { STAGE2(sb, gA0, gA1, k1) }              // u0: A-slab0 of t+1
    PHASE_TAIL()
    MFMA_QUAD(0, b0)
    PHASE_END()

    // ---- phase 1: kk0, m-frags 4-7 ; certify slab1 of tile t ----
    #pragma unroll
    for (int m = 0; m < 4; ++m) a[m] = *(const bf16x8*)(lds + rb + raBase + (m + 4) * 512);
    if (more) {
      STAGE2(sb + 16384, gB0, gB1, k1)                  // u1: B-slab0 of t+1
      asm volatile("s_waitcnt vmcnt(4)" ::: "memory");  // u2,u3 of t landed
    } else {
      asm volatile("s_waitcnt vmcnt(0)" ::: "memory");
    }
    PHASE_TAIL()
    MFMA_QUAD(4, b0)
    PHASE_END()

    // ---- phase 2: kk1, m-frags 0-3 (slab1 certified by ph1 vmcnt+barrier) ----
    #pragma unroll
    for (int m = 0; m < 4; ++m) a[m] = *(const bf16x8*)(lds + rb + 8192 + raBase + m * 512);
    #pragma unroll
    for (int n = 0; n < 4; ++n) b1[n] = *(const bf16x8*)(lds + rb + 24576 + rbBase + n * 512);
    if (more) { STAGE2(sb + 8192, gA0, gA1, k1 + 32) }  // u2: A-slab1 of t+1
    PHASE_TAIL()
    MFMA_QUAD(0, b1)
    PHASE_END()

    // ---- phase 3: kk1, m-frags 4-7 ; certify slab0 of tile t+1 ----
    #pragma unroll
    for (int m = 0; m < 4; ++m) a[m] = *(const bf16x8*)(lds + rb + 8192 + raBase + (m + 4) * 512);
    if (more) {
      STAGE2(sb + 24576, gB0, gB1, k1 + 32)             // u3: B-slab1 of t+1
      asm volatile("s_waitcnt vmcnt(4)" ::: "memory");  // u0,u1 of t+1 landed
    }
    PHASE_TAIL()
    MFMA_QUAD(4, b1)
    PHASE_END()
  }
}

#define ACC256_ZERO(acc) \
  _Pragma("unroll") for (int m_ = 0; m_ < 8; m_++) \
  _Pragma("unroll") for (int n_ = 0; n_ < 4; n_++) \
  _Pragma("unroll") for (int r_ = 0; r_ < 4; r_++) acc[m_][n_][r_] = 0.0f;

// coalesced bf16 epilogue for the 256-core: acc -> LDS (col-XOR, conflict-free)
// -> 16B/lane coalesced global stores. LDS reuse is safe: all K-loop ds_reads
// retired before the final PHASE_END barrier (data-dep waits precede MFMA issue).
__device__ __forceinline__ void epi256_store_bf16(
    f32x4 acc[8][4], ushort* __restrict__ lds,
    ushort* __restrict__ dst, int rowbase, int colb)
{
  __syncthreads();
  const int lane_ = threadIdx.x & 63;
  const int wave_ = threadIdx.x >> 6;
  const int wrb_ = (wave_ >> 2) * 128;
  const int wnb_ = (wave_ & 3) * 64;
  const int rb_ = (lane_ >> 4) << 2;
  const int cb_ = lane_ & 15;
  #pragma unroll
  for (int m = 0; m < 8; m++)
    #pragma unroll
    for (int n = 0; n < 4; n++)
      #pragma unroll
      for (int r = 0; r < 4; r++) {
        const int rl = wrb_ + m * 16 + rb_ + r;
        const int cl = wnb_ + n * 16 + cb_;
        const int cs = cl ^ (((rl >> 2) & 3) << 4);
        lds[rl * 256 + cs] = f2bf(acc[m][n][r]);
      }
  __syncthreads();
  #pragma unroll
  for (int it = 0; it < 16; ++it) {
    const int chunk = it * 512 + threadIdx.x;   // 16B chunk id, 8192 total
    const int rl = chunk >> 5;                  // 32 chunks per 512B row
    const int c16 = chunk & 31;
    const int csw = (c16 * 16) ^ (((rl >> 2) & 3) << 5);
    bf16x8 v = *(const bf16x8*)((const char*)lds + rl * 512 + csw);
    *(bf16x8*)(dst + (size_t)(rowbase + rl) * DIM + colb + c16 * 8) = v;
  }
}

#define EPI256_BEGIN(acc) { \
  const int lane_ = threadIdx.x & 63; \
  const int wave_ = threadIdx.x >> 6; \
  const int wrb_ = (wave_ >> 2) * 128; \
  const int wnb_ = (wave_ & 3) * 64; \
  const int rb_ = (lane_ >> 4) << 2; \
  const int cb_ = lane_ & 15; \
  _Pragma("unroll") for (int m_ = 0; m_ < 8; m_++) \
  _Pragma("unroll") for (int n_ = 0; n_ < 4; n_++) \
  _Pragma("unroll") for (int r_ = 0; r_ < 4; r_++) { \
    const int rloc = wrb_ + m_ * 16 + rb_ + r_; \
    const int cloc = wnb_ + n_ * 16 + cb_; \
    const float aval = acc[m_][n_][r_];
#define EPI256_END() } }

// =====================================================================
// 128x128 GEMM core (scores/av): 256 thr = 4 waves (2x2), dbuf 2x16KB=32KB,
// depth-1 prefetch, counted vmcnt(4), one barrier/step, same swizzle.
// Layout per buf (ushorts): A [128][32] at 0, B [128][32] at 4096.
// =====================================================================
__device__ __forceinline__ void gemm_core(
    const ushort* __restrict__ Ablk, int lda,
    const ushort* __restrict__ Bblk, int ldb,
    int k_begin, int k_end,
    ushort* __restrict__ lds,
    f32x4 acc[4][4])
{
  const int tid  = threadIdx.x;
  const int lane = tid & 63;
  const int wr = ((tid >> 7) & 1) * 64;
  const int wc = ((tid >> 6) & 1) * 64;
  const int lr = lane & 15;
  const int seg = (lane >> 4) ^ ((lane >> 1) & 3);

  const int srow = tid >> 2;                       // 0..63
  const int gseg = (tid & 3) ^ ((tid >> 3) & 3);
  const ushort* gA0 = Ablk + (size_t)srow * lda + gseg * 8;
  const ushort* gA1 = Ablk + (size_t)(srow + 64) * lda + gseg * 8;
  const ushort* gB0 = Bblk + (size_t)srow * ldb + gseg * 8;
  const ushort* gB1 = Bblk + (size_t)(srow + 64) * ldb + gseg * 8;
  const int stA = (tid >> 6) * 512;                // wave-uniform base (ushorts)

  const int NT = (k_end - k_begin) >> 5;

  gload16(gA0 + k_begin, lds + stA);
  gload16(gA1 + k_begin, lds + 2048 + stA);
  gload16(gB0 + k_begin, lds + 4096 + stA);
  gload16(gB1 + k_begin, lds + 6144 + stA);

  for (int t = 0; t < NT; ++t) {
    if (t + 1 < NT) {
      ushort* buf = lds + ((t + 1) & 1) * 8192;
      const int k0 = k_begin + (t + 1) * 32;
      gload16(gA0 + k0, buf + stA);
      gload16(gA1 + k0, buf + 2048 + stA);
      gload16(gB0 + k0, buf + 4096 + stA);
      gload16(gB1 + k0, buf + 6144 + stA);
      asm volatile("s_waitcnt vmcnt(4)" ::: "memory");
    } else {
      asm volatile("s_waitcnt vmcnt(0)" ::: "memory");
    }
    __builtin_amdgcn_s_barrier();

    const ushort* buf = lds + (t & 1) * 8192;
    bf16x8 af[4], bfv[4];
    #pragma unroll
    for (int m = 0; m < 4; m++)
      af[m] = *(const bf16x8*)(buf + (wr + m * 16 + lr) * 32 + seg * 8);
    #pragma unroll
    for (int n = 0; n < 4; n++)
      bfv[n] = *(const bf16x8*)(buf + 4096 + (wc + n * 16 + lr) * 32 + seg * 8);

    __builtin_amdgcn_s_setprio(1);
    #pragma unroll
    for (int m = 0; m < 4; m++)
      #pragma unroll
      for (int n = 0; n < 4; n++)
        acc[m][n] = __builtin_amdgcn_mfma_f32_16x16x32_bf16(af[m], bfv[n], acc[m][n], 0, 0, 0);
    __builtin_amdgcn_s_setprio(0);
    asm volatile("s_waitcnt lgkmcnt(0)" ::: "memory");
  }
}

#define ACC_ZERO(acc) \
  _Pragma("unroll") for (int m_ = 0; m_ < 4; m_++) \
  _Pragma("unroll") for (int n_ = 0; n_ < 4; n_++) \
  _Pragma("unroll") for (int r_ = 0; r_ < 4; r_++) acc[m_][n_][r_] = 0.0f;

#define EPI_BEGIN(acc) { \
  const int lane_ = threadIdx.x & 63; \
  const int wr_ = ((threadIdx.x >> 7) & 1) * 64; \
  const int wc_ = ((threadIdx.x >> 6) & 1) * 64; \
  const int rb_ = (lane_ >> 4) << 2; \
  const int cb_ = lane_ & 15; \
  _Pragma("unroll") for (int m_ = 0; m_ < 4; m_++) \
  _Pragma("unroll") for (int n_ = 0; n_ < 4; n_++) \
  _Pragma("unroll") for (int r_ = 0; r_ < 4; r_++) { \
    const int rloc = wr_ + m_ * 16 + rb_ + r_; \
    const int cloc = wc_ + n_ * 16 + cb_; \
    const float aval = acc[m_][n_][r_];
#define EPI_END() } }

// ---------------- elementwise prep kernels ----------------
__global__ __launch_bounds__(256) void prep_x(const float* __restrict__ x, ushort* __restrict__ xb) {
  size_t idx = ((size_t)blockIdx.x * 256 + threadIdx.x) * 4;   // dest flat index (b,s,d)
  int d = (int)(idx & 1023);
  int s = (int)((idx >> 10) & 4095);
  int b = (int)(idx >> 22);
  float4 v = *(const float4*)(x + ((size_t)s * BATCH + b) * DIM + d);
  ushort4 o;
  o.x = f2bf(v.x); o.y = f2bf(v.y); o.z = f2bf(v.z); o.w = f2bf(v.w);
  *(ushort4*)(xb + idx) = o;
}

// all 5 weight conversions in one launch (5120 blocks)
__global__ __launch_bounds__(256) void f2bf_all(
    const float* __restrict__ Wk, const float* __restrict__ Wq, const float* __restrict__ Wv,
    const float* __restrict__ Wp, const float* __restrict__ W1,
    ushort* __restrict__ wqkv, ushort* __restrict__ wpb, ushort* __restrict__ w1b)
{
  const int g = blockIdx.x;
  const int which = g >> 10;
  const int idx = ((g & 1023) * 256 + threadIdx.x) * 4;
  const float* src = (which == 0) ? Wk : (which == 1) ? Wq : (which == 2) ? Wv
                   : (which == 3) ? Wp : W1;
  ushort* dst = (which == 0) ? wqkv : (which == 1) ? wqkv + 1048576
              : (which == 2) ? wqkv + 2097152 : (which == 3) ? wpb : w1b;
  float4 v = *(const float4*)(src + idx);
  ushort4 o;
  o.x = f2bf(v.x); o.y = f2bf(v.y); o.z = f2bf(v.z); o.w = f2bf(v.w);
  *(ushort4*)(dst + idx) = o;
}

// ---------------- big GEMMs on the 256 core ----------------
__global__ __launch_bounds__(512, 2) void qkv_gemm256(
    const ushort* __restrict__ xb, const ushort* __restrict__ wqkv,
    ushort* __restrict__ Kp, ushort* __restrict__ Qp, ushort* __restrict__ Vp)
{
  __shared__ ushort lds[65536];
  // XCD-chunked swizzle: 768 blocks, 96 contiguous tiles per XCD
  const int nid = (blockIdx.x & 7) * 96 + (blockIdx.x >> 3);
  const int by = nid / 12;     // 0..63
  const int bx = nid % 12;     // 0..11
  f32x4 acc[8][4];
  ACC256_ZERO(acc)
  gemm256_core(xb + (size_t)by * 256 * DIM, DIM,
               wqkv + (size_t)bx * 256 * DIM, DIM, DIM, lds, acc);
  ushort* dst = (bx < 4) ? Kp : (bx < 8) ? Qp : Vp;
  epi256_store_bf16(acc, lds, dst, by * 256, (bx & 3) * 256);
}

__global__ __launch_bounds__(512, 2) void wp_gemm256(
    const ushort* __restrict__ cbuf, const ushort* __restrict__ wpb,
    const float* __restrict__ x, float* __restrict__ y0)
{
  __shared__ ushort lds[65536];
  const int nid = (blockIdx.x & 7) * 32 + (blockIdx.x >> 3);   // 256 blocks
  const int by = nid >> 2;     // 0..63
  const int bx = nid & 3;      // 0..3
  f32x4 acc[8][4];
  ACC256_ZERO(acc)
  gemm256_core(cbuf + (size_t)by * 256 * DIM, DIM,
               wpb + (size_t)bx * 256 * DIM, DIM, DIM, lds, acc);
  EPI256_BEGIN(acc)
    int row = by * 256 + rloc;           // b*4096+s
    int col = bx * 256 + cloc;
    int b = row >> 12, s = row & 4095;
    y0[(size_t)row * DIM + col] = aval + x[((size_t)s * BATCH + b) * DIM + col];
  EPI256_END()
}

__global__ __launch_bounds__(512, 2) void ffn1_gemm256(
    const ushort* __restrict__ y1, const ushort* __restrict__ w1b,
    const float* __restrict__ b1, float* __restrict__ h0)
{
  __shared__ ushort lds[65536];
  const int nid = (blockIdx.x & 7) * 32 + (blockIdx.x >> 3);
  const int by = nid >> 2;
  const int bx = nid & 3;
  f32x4 acc[8][4];
  ACC256_ZERO(acc)
  gemm256_core(y1 + (size_t)by * 256 * DIM, DIM,
               w1b + (size_t)bx * 256 * DIM, DIM, DIM, lds, acc);
  EPI256_BEGIN(acc)
    int row = by * 256 + rloc;
    int col = bx * 256 + cloc;
    h0[(size_t)row * DIM + col] = fmaxf(aval + b1[col], 0.0f);
  EPI256_END()
}

// ---------------- attention path (128 core) ----------------
__global__ __launch_bounds__(256) void transpose_v(const ushort* __restrict__ V, ushort* __restrict__ VT) {
  __shared__ ushort tile[64][66];
  const int s0 = blockIdx.x * 64, d0 = blockIdx.y * 64, b = blockIdx.z;
  const ushort* Vb = V + (size_t)b * S_LEN * DIM;
  ushort* VTb = VT + (size_t)b * DIM * S_LEN;
  #pragma unroll
  for (int it = 0; it < 16; it++) {
    int flat = it * 256 + threadIdx.x;
    int r = flat >> 6, c = flat & 63;
    tile[r][c] = Vb[(size_t)(s0 + r) * DIM + d0 + c];
  }
  __syncthreads();
  #pragma unroll
  for (int it = 0; it < 16; it++) {
    int flat = it * 256 + threadIdx.x;
    int r = flat >> 6, c = flat & 63;      // r = d-local, c = s-local
    VTb[(size_t)(d0 + r) * S_LEN + s0 + c] = tile[c][r];
  }
}

__global__ __launch_bounds__(256) void scores_gemm(
    const ushort* __restrict__ Qp, const ushort* __restrict__ Kp,
    float* __restrict__ eband)
{
  const int nid = (blockIdx.x & 7) * 80 + (blockIdx.x >> 3);   // 640 blocks
  const int b   = nid / 160;
  const int rem = nid % 160;
  const int i   = rem / 5;
  const int jj  = rem % 5;
  const int j   = i - 2 + jj;
  if (j < 0 || j >= NBLK) return;
  __shared__ ushort lds[16384];
  f32x4 acc[4][4];
  ACC_ZERO(acc)
  gemm_core(Qp + ((size_t)b * S_LEN + i * 128) * DIM, DIM,
            Kp + ((size_t)b * S_LEN + j * 128) * DIM, DIM, 0, DIM, lds, acc);
  EPI_BEGIN(acc)
    int q = i * 128 + rloc;
    int k = j * 128 + cloc;
    float v = aval * SCALE;
    int dqk = q - k;
    if (dqk == 0 || dqk > AP || dqk < -AP) v = -INFINITY;
    eband[((size_t)b * S_LEN + q) * BANDC + jj * 128 + cloc] = v;
  EPI_END()
}

__global__ __launch_bounds__(256) void softmax_band(const float* __restrict__ eband,
                                                    ushort* __restrict__ aband)
{
  __shared__ float red[4];
  const int qg = blockIdx.x;          // 0..16383
  const int s  = qg & 4095;
  const int i  = s >> 7;
  const float* row = eband + (size_t)qg * BANDC;
  ushort* arow = aband + (size_t)qg * BANDC;

  float vals[3];
  bool  valid[3];
  float mx = -INFINITY;
  #pragma unroll
  for (int t = 0; t < 3; t++) {
    int idx = threadIdx.x + t * 256;
    int jj = idx >> 7;
    int j = i - 2 + jj;
    bool ok = (idx < BANDC) && (j >= 0) && (j < NBLK);
    valid[t] = ok;
    float v = ok ? row[idx] : -INFINITY;
    vals[t] = v;
    mx = fmaxf(mx, v);
  }
  float bmax = block_max(mx, red);
  float ss = 0.0f;
  #pragma unroll
  for (int t = 0; t < 3; t++) {
    float e = valid[t] ? __expf(vals[t] - bmax) : 0.0f;
    vals[t] = e;
    ss += e;
  }
  float inv = 1.0f / block_sum(ss, red);
  #pragma unroll
  for (int t = 0; t < 3; t++) {
    int idx = threadIdx.x + t * 256;
    if (idx < BANDC) arow[idx] = f2bf(vals[t] * inv);
  }
}

__global__ __launch_bounds__(256) void av_gemm(
    const ushort* __restrict__ aband, const ushort* __restrict__ VT,
    ushort* __restrict__ cbuf)
{
  const int nid = (blockIdx.x & 7) * 128 + (blockIdx.x >> 3); // 1024 blocks
  const int by = nid >> 3;            // 0..127: (b,i)
  const int b = by >> 5, i = by & 31;
  const int bx = nid & 7;             // d-block
  const int jj_lo = (i < 2) ? (2 - i) : 0;
  const int jj_hi = (i > 29) ? (34 - i) : 5;
  __shared__ ushort lds[16384];
  f32x4 acc[4][4];
  ACC_ZERO(acc)
  const ushort* Ablk = aband + ((size_t)b * S_LEN + i * 128) * BANDC;
  const ushort* Bblk = VT + (size_t)b * DIM * S_LEN + (size_t)bx * 128 * S_LEN + (i - 2) * 128;
  gemm_core(Ablk, BANDC, Bblk, S_LEN, jj_lo * 128, jj_hi * 128, lds, acc);

  // coalesced bf16 epilogue via LDS repack (32KB, exactly the dbuf space)
  __syncthreads();
  {
    const int lane_ = threadIdx.x & 63;
    const int wr_ = ((threadIdx.x >> 7) & 1) * 64;
    const int wc_ = ((threadIdx.x >> 6) & 1) * 64;
    const int rb_ = (lane_ >> 4) << 2;
    const int cb_ = lane_ & 15;
    #pragma unroll
    for (int m = 0; m < 4; m++)
      #pragma unroll
      for (int n = 0; n < 4; n++)
        #pragma unroll
        for (int r = 0; r < 4; r++) {
          const int rl = wr_ + m * 16 + rb_ + r;
          const int cl = wc_ + n * 16 + cb_;
          const int cs = cl ^ (((rl >> 2) & 3) << 4);
          lds[rl * 128 + cs] = f2bf(acc[m][n][r]);
        }
  }
  __syncthreads();
  ushort* dst = cbuf + ((size_t)b * S_LEN + i * 128) * DIM + bx * 128;
  #pragma unroll
  for (int it = 0; it < 8; ++it) {
    const int chunk = it * 256 + threadIdx.x;   // 16B chunks, 2048 total
    const int rl = chunk >> 4;                  // 16 chunks per 256B row
    const int c16 = chunk & 15;
    const int csw = (c16 * 16) ^ (((rl >> 2) & 3) << 5);
    bf16x8 v = *(const bf16x8*)((const char*)lds + rl * 256 + csw);
    *(bf16x8*)(dst + (size_t)rl * DIM + c16 * 8) = v;
  }
}

// ---------------- norm / head ----------------
__global__ __launch_bounds__(256) void ln_kernel(const float* __restrict__ y0, ushort* __restrict__ y1,
                                                 const float* __restrict__ gamma, const float* __restrict__ beta)
{
  __shared__ float red[4];
  const size_t q = blockIdx.x;
  const float* row = y0 + q * DIM;
  float v[4];
  #pragma unroll
  for (int t = 0; t < 4; t++) v[t] = row[threadIdx.x + t * 256];
  float mean = block_sum(v[0] + v[1] + v[2] + v[3], red) * (1.0f / DIM);
  float q2 = 0.0f;
  #pragma unroll
  for (int t = 0; t < 4; t++) { float d = v[t] - mean; q2 += d * d; }
  float var = block_sum(q2, red) * (1.0f / DIM);
  float rstd = rsqrtf(var + 1e-6f);
  #pragma unroll
  for (int t = 0; t < 4; t++) {
    int d = threadIdx.x + t * 256;
    y1[q * DIM + d] = f2bf((v[t] - mean) * rstd * gamma[d] + beta[d]);
  }
}

__global__ __launch_bounds__(256) void head_kernel(const float* __restrict__ h0,
    const float* __restrict__ gamma, const float* __restrict__ beta,
    const float* __restrict__ W2, const float* __restrict__ b2,
    float* __restrict__ out)
{
  __shared__ float red[4];
  const int qg = blockIdx.x;
  const int b = qg >> 12, s = qg & 4095;
  const float* row = h0 + (size_t)qg * DIM;
  float v[4];
  #pragma unroll
  for (int t = 0; t < 4; t++) v[t] = row[threadIdx.x + t * 256];
  float mean = block_sum(v[0] + v[1] + v[2] + v[3], red) * (1.0f / DIM);
  float q2 = 0.0f;
  #pragma unroll
  for (int t = 0; t < 4; t++) { float d = v[t] - mean; q2 += d * d; }
  float var = block_sum(q2, red) * (1.0f / DIM);
  float rstd = rsqrtf(var + 1e-6f);
  float part = 0.0f;
  #pragma unroll
  for (int t = 0; t < 4; t++) {
    int d = threadIdx.x + t * 256;
    part += ((v[t] - mean) * rstd * gamma[d] + beta[d]) * W2[d];
  }
  float logit = block_sum(part, red) + b2[0];
  if (threadIdx.x == 0) out[(size_t)s * BATCH + b] = 1.0f / (1.0f + expf(-logit));
}

// ---------------- launch ----------------
extern "C" void kernel_launch(void* const* d_in, const int* in_sizes, int n_in,
                              void* d_out, int out_size, void* d_ws, size_t ws_size,
                              hipStream_t stream) {
  const float* x     = (const float*)d_in[0];
  const float* Wk    = (const float*)d_in[1];
  const float* Wq    = (const float*)d_in[2];
  const float* Wv    = (const float*)d_in[3];
  const float* Wp    = (const float*)d_in[4];
  const float* W1    = (const float*)d_in[5];
  const float* b1    = (const float*)d_in[6];
  const float* W2    = (const float*)d_in[7];
  const float* b2    = (const float*)d_in[8];
  const float* gamma = (const float*)d_in[9];
  const float* beta  = (const float*)d_in[10];
  float* out = (float*)d_out;

  char* w = (char*)d_ws;
  ushort* xb   = (ushort*)(w + 0);            // 33,554,432 B
  ushort* wqkv = (ushort*)(w + 33554432);     //  6,291,456 B
  ushort* wpb  = (ushort*)(w + 39845888);     //  2,097,152 B
  ushort* w1b  = (ushort*)(w + 41943040);     //  2,097,152 B
  ushort* Qp   = (ushort*)(w + 44040192);     // 33,554,432 B
  ushort* Kp   = (ushort*)(w + 77594624);     // 33,554,432 B
  ushort* Vp   = (ushort*)(w + 111149056);    // 33,554,432 B
  ushort* VT   = (ushort*)(w + 144703488);    // 33,554,432 B
  float*  big  = (float*)(w + 178257920);     // 67,108,864 B (eband -> y0 -> h0)
  // reuse (sequentially dead regions):
  ushort* aband = Qp;     // Q dead after scores
  ushort* cbuf  = Kp;     // K dead after scores
  ushort* y1    = Vp;     // V dead after transpose
  float* eband = big;
  float* y0    = big;
  float* h0    = big;

  prep_x<<<16384, 256, 0, stream>>>(x, xb);
  f2bf_all<<<5120, 256, 0, stream>>>(Wk, Wq, Wv, Wp, W1, wqkv, wpb, w1b);

  qkv_gemm256<<<768, 512, 0, stream>>>(xb, wqkv, Kp, Qp, Vp);
  transpose_v<<<dim3(64, 16, 4), 256, 0, stream>>>(Vp, VT);
  scores_gemm<<<640, 256, 0, stream>>>(Qp, Kp, eband);
  softmax_band<<<16384, 256, 0, stream>>>(eband, aband);
  av_gemm<<<1024, 256, 0, stream>>>(aband, VT, cbuf);
  wp_gemm256<<<256, 512, 0, stream>>>(cbuf, wpb, x, y0);
  ln_kernel<<<16384, 256, 0, stream>>>(y0, y1, gamma, beta);
  ffn1_gemm256<<<256, 512, 0, stream>>>(y1, w1b, b1, h0);
  head_kernel<<<16384, 256, 0, stream>>>(h0, gamma, beta, W2, b2, out);
}

// Round 8
// 376.248 us; speedup vs baseline: 5.1158x; 1.0034x over previous
//
#include <hip/hip_runtime.h>
#include <stdint.h>
#include <math.h>

// ---------------- problem constants ----------------
#define S_LEN 4096
#define BATCH 4
#define DIM   1024
#define AP    256
#define NBLK  32            // S_LEN/128 row-blocks per batch
#define BANDC 640           // 5*128 band columns
#define SCALE 0.03125f      // 1/sqrt(1024)

typedef __attribute__((ext_vector_type(4))) float f32x4;
typedef __attribute__((ext_vector_type(8))) short bf16x8;

// ---------------- helpers ----------------
__device__ __forceinline__ ushort f2bf(float f) {
  union { float f; uint32_t u; } v; v.f = f;
  uint32_t r = v.u + 0x7FFFu + ((v.u >> 16) & 1u);
  return (ushort)(r >> 16);
}

__device__ __forceinline__ void gload16(const void* g, void* l) {
  __builtin_amdgcn_global_load_lds((const __attribute__((address_space(1))) void*)g,
                                   (__attribute__((address_space(3))) void*)l,
                                   16, 0, 0);
}

__device__ __forceinline__ float block_sum(float v, float* red) {
  #pragma unroll
  for (int o = 32; o > 0; o >>= 1) v += __shfl_xor(v, o, 64);
  const int w = threadIdx.x >> 6;
  if ((threadIdx.x & 63) == 0) red[w] = v;
  __syncthreads();
  v = red[0] + red[1] + red[2] + red[3];
  __syncthreads();
  return v;
}

__device__ __forceinline__ float block_max(float v, float* red) {
  #pragma unroll
  for (int o = 32; o > 0; o >>= 1) v = fmaxf(v, __shfl_xor(v, o, 64));
  const int w = threadIdx.x >> 6;
  if ((threadIdx.x & 63) == 0) red[w] = v;
  __syncthreads();
  v = fmaxf(fmaxf(red[0], red[1]), fmaxf(red[2], red[3]));
  __syncthreads();
  return v;
}

// =====================================================================
// 256x256 pipelined GEMM core v3:
//  512 thr = 8 waves (2M x 4N), per-wave C = 128x64, acc[8][4] f32x4.
//  BK=64 as two [256][32] slabs per operand; 2 LDS buffers (tile parity)
//  of 64 KB each = 128 KiB -> 1 block/CU.
//  KEY (round-8): fragment ds_reads are issued ONE PHASE AHEAD and there
//  are NO intra-tile barriers / NO inline lgkm waits. The compiler's
//  dependence-tracked counted lgkmcnt lets phase p+1's LDS drain overlap
//  phase p's MFMA cluster (the 37% ceiling of r4-r7 was read/MFMA
//  serialization from same-phase read+lgkmcnt(0)).
//  Intra-tile hazard-free: reads hit buffer rb, staging writes buffer sb.
//  All 4 stage units issue in phases 0-1 -> boundary vmcnt(0) distance
//  ~2.5 phases (~1500cy) > HBM latency. ONE vmcnt(0)+s_barrier per tile:
//  reads of rb retire before their consuming MFMAs issue, so the barrier
//  also certifies rb is re-stageable by all waves.
//  Quarter-wave conflict-free swizzle (verified conflicts=0): LDS slot
//  (row,s) holds global seg s^((row>>1)&3); source pre-swizzled, read
//  swizzled, LDS dest linear (global_load_lds requirement).
//  A: row-major [256 x K] (lda); B: row-major [256 n-rows x K] = B^T.
//  Requires K % 64 == 0, K >= 128.
// =====================================================================
#define STAGE2(dstbase, g0, g1, kcol) \
  gload16((g0) + (kcol), lds + (dstbase) + stOff); \
  gload16((g1) + (kcol), lds + (dstbase) + 4096 + stOff);

#define MFMA_QUAD(arow, av, bv) \
  __builtin_amdgcn_s_setprio(1); \
  _Pragma("unroll") for (int m = 0; m < 4; ++m) \
  _Pragma("unroll") for (int n = 0; n < 4; ++n) \
    acc[(arow) + m][n] = __builtin_amdgcn_mfma_f32_16x16x32_bf16(av[m], bv[n], acc[(arow) + m][n], 0, 0, 0); \
  __builtin_amdgcn_s_setprio(0);

__device__ __forceinline__ void gemm256_core(
    const ushort* __restrict__ Ablk, int lda,
    const ushort* __restrict__ Bblk, int ldb,
    int K, ushort* __restrict__ lds,
    f32x4 acc[8][4])
{
  const int tid  = threadIdx.x;
  const int lane = tid & 63;
  const int wave = tid >> 6;
  const int wr = wave >> 2;       // 0..1
  const int wn = wave & 3;        // 0..3

  // staging: thread covers (srow = tid>>2, slot = tid&3); source pre-swizzled
  const int srow = tid >> 2;                       // 0..127
  const int gseg = (tid & 3) ^ ((tid >> 3) & 3);   // slot ^ ((srow>>1)&3)
  const ushort* gA0 = Ablk + (size_t)srow * lda + gseg * 8;
  const ushort* gA1 = Ablk + (size_t)(srow + 128) * lda + gseg * 8;
  const ushort* gB0 = Bblk + (size_t)srow * ldb + gseg * 8;
  const ushort* gB1 = Bblk + (size_t)(srow + 128) * ldb + gseg * 8;
  const int stOff = wave * 512;                    // wave-uniform LDS base (ushorts)

  // swizzled ds_read addressing
  const int l15 = lane & 15;
  const int seg = (lane >> 4) ^ ((lane >> 1) & 3); // kseg ^ ((row>>1)&3)
  const int raBase = (wr * 128 + l15) * 32 + seg * 8;   // + m*512
  const int rbBase = (wn * 64  + l15) * 32 + seg * 8;   // + n*512

  const int NT = K >> 6;   // BK = 64

  // buffer layout (ushorts): A-slab0 @0, A-slab1 @8192, B-slab0 @16384, B-slab1 @24576
  // prologue: stage all 4 units of tile 0 into buffer 0
  STAGE2(0,     gA0, gA1, 0)
  STAGE2(16384, gB0, gB1, 0)
  STAGE2(8192,  gA0, gA1, 32)
  STAGE2(24576, gB0, gB1, 32)
  asm volatile("s_waitcnt vmcnt(0)" ::: "memory");
  __builtin_amdgcn_s_barrier();

  for (int t = 0; t < NT; ++t) {
    const int rb = (t & 1) * 32768;          // read buffer
    const int sb = ((t + 1) & 1) * 32768;    // stage buffer
    const int k1 = (t + 1) << 6;
    const bool more = (t + 1 < NT);

    bf16x8 aA[4], aB[4], bA[4], bB[4];

    // --- pre-issue ph0 + ph1 fragment reads ---
    #pragma unroll
    for (int m = 0; m < 4; ++m) aA[m] = *(const bf16x8*)(lds + rb + raBase + m * 512);
    #pragma unroll
    for (int n = 0; n < 4; ++n) bA[n] = *(const bf16x8*)(lds + rb + 16384 + rbBase + n * 512);
    #pragma unroll
    for (int m = 0; m < 4; ++m) aB[m] = *(const bf16x8*)(lds + rb + raBase + (m + 4) * 512);
    // stage units u0,u1 of tile t+1
    if (more) {
      STAGE2(sb,         gA0, gA1, k1)
      STAGE2(sb + 16384, gB0, gB1, k1)
    }

    // --- phase 0: MFMA (m0-3, kk0) ; compiler waits counted lgkm on aA,bA ---
    MFMA_QUAD(0, aA, bA)

    // --- pre-issue ph2 reads (kk1) ---
    #pragma unroll
    for (int m = 0; m < 4; ++m) aA[m] = *(const bf16x8*)(lds + rb + 8192 + raBase + m * 512);
    #pragma unroll
    for (int n = 0; n < 4; ++n) bB[n] = *(const bf16x8*)(lds + rb + 24576 + rbBase + n * 512);
    // stage units u2,u3 of tile t+1
    if (more) {
      STAGE2(sb + 8192,  gA0, gA1, k1 + 32)
      STAGE2(sb + 24576, gB0, gB1, k1 + 32)
    }

    // --- phase 1: MFMA (m4-7, kk0) ---
    MFMA_QUAD(4, aB, bA)

    // --- pre-issue ph3 reads ---
    #pragma unroll
    for (int m = 0; m < 4; ++m) aB[m] = *(const bf16x8*)(lds + rb + 8192 + raBase + (m + 4) * 512);

    // --- phase 2: MFMA (m0-3, kk1) ---
    MFMA_QUAD(0, aA, bB)

    // --- phase 3: MFMA (m4-7, kk1) ---
    MFMA_QUAD(4, aB, bB)

    // --- tile boundary: certify sb staged (own loads) + collectivize ---
    asm volatile("s_waitcnt vmcnt(0)" ::: "memory");
    __builtin_amdgcn_s_barrier();
  }
}

#define ACC256_ZERO(acc) \
  _Pragma("unroll") for (int m_ = 0; m_ < 8; m_++) \
  _Pragma("unroll") for (int n_ = 0; n_ < 4; n_++) \
  _Pragma("unroll") for (int r_ = 0; r_ < 4; r_++) acc[m_][n_][r_] = 0.0f;

// coalesced bf16 epilogue for the 256-core: acc -> LDS (col-XOR, conflict-free)
// -> 16B/lane coalesced global stores.
__device__ __forceinline__ void epi256_store_bf16(
    f32x4 acc[8][4], ushort* __restrict__ lds,
    ushort* __restrict__ dst, int rowbase, int colb)
{
  __syncthreads();
  const int lane_ = threadIdx.x & 63;
  const int wave_ = threadIdx.x >> 6;
  const int wrb_ = (wave_ >> 2) * 128;
  const int wnb_ = (wave_ & 3) * 64;
  const int rb_ = (lane_ >> 4) << 2;
  const int cb_ = lane_ & 15;
  #pragma unroll
  for (int m = 0; m < 8; m++)
    #pragma unroll
    for (int n = 0; n < 4; n++)
      #pragma unroll
      for (int r = 0; r < 4; r++) {
        const int rl = wrb_ + m * 16 + rb_ + r;
        const int cl = wnb_ + n * 16 + cb_;
        const int cs = cl ^ (((rl >> 2) & 3) << 4);
        lds[rl * 256 + cs] = f2bf(acc[m][n][r]);
      }
  __syncthreads();
  #pragma unroll
  for (int it = 0; it < 16; ++it) {
    const int chunk = it * 512 + threadIdx.x;   // 16B chunk id, 8192 total
    const int rl = chunk >> 5;                  // 32 chunks per 512B row
    const int c16 = chunk & 31;
    const int csw = (c16 * 16) ^ (((rl >> 2) & 3) << 5);
    bf16x8 v = *(const bf16x8*)((const char*)lds + rl * 512 + csw);
    *(bf16x8*)(dst + (size_t)(rowbase + rl) * DIM + colb + c16 * 8) = v;
  }
}

#define EPI256_BEGIN(acc) { \
  const int lane_ = threadIdx.x & 63; \
  const int wave_ = threadIdx.x >> 6; \
  const int wrb_ = (wave_ >> 2) * 128; \
  const int wnb_ = (wave_ & 3) * 64; \
  const int rb_ = (lane_ >> 4) << 2; \
  const int cb_ = lane_ & 15; \
  _Pragma("unroll") for (int m_ = 0; m_ < 8; m_++) \
  _Pragma("unroll") for (int n_ = 0; n_ < 4; n_++) \
  _Pragma("unroll") for (int r_ = 0; r_ < 4; r_++) { \
    const int rloc = wrb_ + m_ * 16 + rb_ + r_; \
    const int cloc = wnb_ + n_ * 16 + cb_; \
    const float aval = acc[m_][n_][r_];
#define EPI256_END() } }

// =====================================================================
// 128x128 GEMM core (scores/av): 256 thr = 4 waves (2x2), dbuf 2x16KB=32KB,
// depth-1 prefetch, counted vmcnt(4), one barrier/step, same swizzle.
// Layout per buf (ushorts): A [128][32] at 0, B [128][32] at 4096.
// =====================================================================
__device__ __forceinline__ void gemm_core(
    const ushort* __restrict__ Ablk, int lda,
    const ushort* __restrict__ Bblk, int ldb,
    int k_begin, int k_end,
    ushort* __restrict__ lds,
    f32x4 acc[4][4])
{
  const int tid  = threadIdx.x;
  const int lane = tid & 63;
  const int wr = ((tid >> 7) & 1) * 64;
  const int wc = ((tid >> 6) & 1) * 64;
  const int lr = lane & 15;
  const int seg = (lane >> 4) ^ ((lane >> 1) & 3);

  const int srow = tid >> 2;                       // 0..63
  const int gseg = (tid & 3) ^ ((tid >> 3) & 3);
  const ushort* gA0 = Ablk + (size_t)srow * lda + gseg * 8;
  const ushort* gA1 = Ablk + (size_t)(srow + 64) * lda + gseg * 8;
  const ushort* gB0 = Bblk + (size_t)srow * ldb + gseg * 8;
  const ushort* gB1 = Bblk + (size_t)(srow + 64) * ldb + gseg * 8;
  const int stA = (tid >> 6) * 512;                // wave-uniform base (ushorts)

  const int NT = (k_end - k_begin) >> 5;

  gload16(gA0 + k_begin, lds + stA);
  gload16(gA1 + k_begin, lds + 2048 + stA);
  gload16(gB0 + k_begin, lds + 4096 + stA);
  gload16(gB1 + k_begin, lds + 6144 + stA);

  for (int t = 0; t < NT; ++t) {
    if (t + 1 < NT) {
      ushort* buf = lds + ((t + 1) & 1) * 8192;
      const int k0 = k_begin + (t + 1) * 32;
      gload16(gA0 + k0, buf + stA);
      gload16(gA1 + k0, buf + 2048 + stA);
      gload16(gB0 + k0, buf + 4096 + stA);
      gload16(gB1 + k0, buf + 6144 + stA);
      asm volatile("s_waitcnt vmcnt(4)" ::: "memory");
    } else {
      asm volatile("s_waitcnt vmcnt(0)" ::: "memory");
    }
    __builtin_amdgcn_s_barrier();

    const ushort* buf = lds + (t & 1) * 8192;
    bf16x8 af[4], bfv[4];
    #pragma unroll
    for (int m = 0; m < 4; m++)
      af[m] = *(const bf16x8*)(buf + (wr + m * 16 + lr) * 32 + seg * 8);
    #pragma unroll
    for (int n = 0; n < 4; n++)
      bfv[n] = *(const bf16x8*)(buf + 4096 + (wc + n * 16 + lr) * 32 + seg * 8);

    __builtin_amdgcn_s_setprio(1);
    #pragma unroll
    for (int m = 0; m < 4; m++)
      #pragma unroll
      for (int n = 0; n < 4; n++)
        acc[m][n] = __builtin_amdgcn_mfma_f32_16x16x32_bf16(af[m], bfv[n], acc[m][n], 0, 0, 0);
    __builtin_amdgcn_s_setprio(0);
    asm volatile("s_waitcnt lgkmcnt(0)" ::: "memory");
  }
}

#define ACC_ZERO(acc) \
  _Pragma("unroll") for (int m_ = 0; m_ < 4; m_++) \
  _Pragma("unroll") for (int n_ = 0; n_ < 4; n_++) \
  _Pragma("unroll") for (int r_ = 0; r_ < 4; r_++) acc[m_][n_][r_] = 0.0f;

#define EPI_BEGIN(acc) { \
  const int lane_ = threadIdx.x & 63; \
  const int wr_ = ((threadIdx.x >> 7) & 1) * 64; \
  const int wc_ = ((threadIdx.x >> 6) & 1) * 64; \
  const int rb_ = (lane_ >> 4) << 2; \
  const int cb_ = lane_ & 15; \
  _Pragma("unroll") for (int m_ = 0; m_ < 4; m_++) \
  _Pragma("unroll") for (int n_ = 0; n_ < 4; n_++) \
  _Pragma("unroll") for (int r_ = 0; r_ < 4; r_++) { \
    const int rloc = wr_ + m_ * 16 + rb_ + r_; \
    const int cloc = wc_ + n_ * 16 + cb_; \
    const float aval = acc[m_][n_][r_];
#define EPI_END() } }

// ---------------- elementwise prep kernels ----------------
__global__ __launch_bounds__(256) void prep_x(const float* __restrict__ x, ushort* __restrict__ xb) {
  size_t idx = ((size_t)blockIdx.x * 256 + threadIdx.x) * 4;   // dest flat index (b,s,d)
  int d = (int)(idx & 1023);
  int s = (int)((idx >> 10) & 4095);
  int b = (int)(idx >> 22);
  float4 v = *(const float4*)(x + ((size_t)s * BATCH + b) * DIM + d);
  ushort4 o;
  o.x = f2bf(v.x); o.y = f2bf(v.y); o.z = f2bf(v.z); o.w = f2bf(v.w);
  *(ushort4*)(xb + idx) = o;
}

// all 5 weight conversions in one launch (5120 blocks)
__global__ __launch_bounds__(256) void f2bf_all(
    const float* __restrict__ Wk, const float* __restrict__ Wq, const float* __restrict__ Wv,
    const float* __restrict__ Wp, const float* __restrict__ W1,
    ushort* __restrict__ wqkv, ushort* __restrict__ wpb, ushort* __restrict__ w1b)
{
  const int g = blockIdx.x;
  const int which = g >> 10;
  const int idx = ((g & 1023) * 256 + threadIdx.x) * 4;
  const float* src = (which == 0) ? Wk : (which == 1) ? Wq : (which == 2) ? Wv
                   : (which == 3) ? Wp : W1;
  ushort* dst = (which == 0) ? wqkv : (which == 1) ? wqkv + 1048576
              : (which == 2) ? wqkv + 2097152 : (which == 3) ? wpb : w1b;
  float4 v = *(const float4*)(src + idx);
  ushort4 o;
  o.x = f2bf(v.x); o.y = f2bf(v.y); o.z = f2bf(v.z); o.w = f2bf(v.w);
  *(ushort4*)(dst + idx) = o;
}

// ---------------- big GEMMs on the 256 core ----------------
__global__ __launch_bounds__(512, 2) void qkv_gemm256(
    const ushort* __restrict__ xb, const ushort* __restrict__ wqkv,
    ushort* __restrict__ Kp, ushort* __restrict__ Qp, ushort* __restrict__ Vp)
{
  __shared__ ushort lds[65536];
  // XCD-chunked swizzle: 768 blocks, 96 contiguous tiles per XCD
  const int nid = (blockIdx.x & 7) * 96 + (blockIdx.x >> 3);
  const int by = nid / 12;     // 0..63
  const int bx = nid % 12;     // 0..11
  f32x4 acc[8][4];
  ACC256_ZERO(acc)
  gemm256_core(xb + (size_t)by * 256 * DIM, DIM,
               wqkv + (size_t)bx * 256 * DIM, DIM, DIM, lds, acc);
  ushort* dst = (bx < 4) ? Kp : (bx < 8) ? Qp : Vp;
  epi256_store_bf16(acc, lds, dst, by * 256, (bx & 3) * 256);
}

__global__ __launch_bounds__(512, 2) void wp_gemm256(
    const ushort* __restrict__ cbuf, const ushort* __restrict__ wpb,
    const float* __restrict__ x, float* __restrict__ y0)
{
  __shared__ ushort lds[65536];
  const int nid = (blockIdx.x & 7) * 32 + (blockIdx.x >> 3);   // 256 blocks
  const int by = nid >> 2;     // 0..63
  const int bx = nid & 3;      // 0..3
  f32x4 acc[8][4];
  ACC256_ZERO(acc)
  gemm256_core(cbuf + (size_t)by * 256 * DIM, DIM,
               wpb + (size_t)bx * 256 * DIM, DIM, DIM, lds, acc);
  EPI256_BEGIN(acc)
    int row = by * 256 + rloc;           // b*4096+s
    int col = bx * 256 + cloc;
    int b = row >> 12, s = row & 4095;
    y0[(size_t)row * DIM + col] = aval + x[((size_t)s * BATCH + b) * DIM + col];
  EPI256_END()
}

__global__ __launch_bounds__(512, 2) void ffn1_gemm256(
    const ushort* __restrict__ y1, const ushort* __restrict__ w1b,
    const float* __restrict__ b1, float* __restrict__ h0)
{
  __shared__ ushort lds[65536];
  const int nid = (blockIdx.x & 7) * 32 + (blockIdx.x >> 3);
  const int by = nid >> 2;
  const int bx = nid & 3;
  f32x4 acc[8][4];
  ACC256_ZERO(acc)
  gemm256_core(y1 + (size_t)by * 256 * DIM, DIM,
               w1b + (size_t)bx * 256 * DIM, DIM, DIM, lds, acc);
  EPI256_BEGIN(acc)
    int row = by * 256 + rloc;
    int col = bx * 256 + cloc;
    h0[(size_t)row * DIM + col] = fmaxf(aval + b1[col], 0.0f);
  EPI256_END()
}

// ---------------- attention path (128 core) ----------------
__global__ __launch_bounds__(256) void transpose_v(const ushort* __restrict__ V, ushort* __restrict__ VT) {
  __shared__ ushort tile[64][66];
  const int s0 = blockIdx.x * 64, d0 = blockIdx.y * 64, b = blockIdx.z;
  const ushort* Vb = V + (size_t)b * S_LEN * DIM;
  ushort* VTb = VT + (size_t)b * DIM * S_LEN;
  #pragma unroll
  for (int it = 0; it < 16; it++) {
    int flat = it * 256 + threadIdx.x;
    int r = flat >> 6, c = flat & 63;
    tile[r][c] = Vb[(size_t)(s0 + r) * DIM + d0 + c];
  }
  __syncthreads();
  #pragma unroll
  for (int it = 0; it < 16; it++) {
    int flat = it * 256 + threadIdx.x;
    int r = flat >> 6, c = flat & 63;      // r = d-local, c = s-local
    VTb[(size_t)(d0 + r) * S_LEN + s0 + c] = tile[c][r];
  }
}

__global__ __launch_bounds__(256) void scores_gemm(
    const ushort* __restrict__ Qp, const ushort* __restrict__ Kp,
    float* __restrict__ eband)
{
  const int nid = (blockIdx.x & 7) * 80 + (blockIdx.x >> 3);   // 640 blocks
  const int b   = nid / 160;
  const int rem = nid % 160;
  const int i   = rem / 5;
  const int jj  = rem % 5;
  const int j   = i - 2 + jj;
  if (j < 0 || j >= NBLK) return;
  __shared__ ushort lds[16384];
  f32x4 acc[4][4];
  ACC_ZERO(acc)
  gemm_core(Qp + ((size_t)b * S_LEN + i * 128) * DIM, DIM,
            Kp + ((size_t)b * S_LEN + j * 128) * DIM, DIM, 0, DIM, lds, acc);
  EPI_BEGIN(acc)
    int q = i * 128 + rloc;
    int k = j * 128 + cloc;
    float v = aval * SCALE;
    int dqk = q - k;
    if (dqk == 0 || dqk > AP || dqk < -AP) v = -INFINITY;
    eband[((size_t)b * S_LEN + q) * BANDC + jj * 128 + cloc] = v;
  EPI_END()
}

__global__ __launch_bounds__(256) void softmax_band(const float* __restrict__ eband,
                                                    ushort* __restrict__ aband)
{
  __shared__ float red[4];
  const int qg = blockIdx.x;          // 0..16383
  const int s  = qg & 4095;
  const int i  = s >> 7;
  const float* row = eband + (size_t)qg * BANDC;
  ushort* arow = aband + (size_t)qg * BANDC;

  float vals[3];
  bool  valid[3];
  float mx = -INFINITY;
  #pragma unroll
  for (int t = 0; t < 3; t++) {
    int idx = threadIdx.x + t * 256;
    int jj = idx >> 7;
    int j = i - 2 + jj;
    bool ok = (idx < BANDC) && (j >= 0) && (j < NBLK);
    valid[t] = ok;
    float v = ok ? row[idx] : -INFINITY;
    vals[t] = v;
    mx = fmaxf(mx, v);
  }
  float bmax = block_max(mx, red);
  float ss = 0.0f;
  #pragma unroll
  for (int t = 0; t < 3; t++) {
    float e = valid[t] ? __expf(vals[t] - bmax) : 0.0f;
    vals[t] = e;
    ss += e;
  }
  float inv = 1.0f / block_sum(ss, red);
  #pragma unroll
  for (int t = 0; t < 3; t++) {
    int idx = threadIdx.x + t * 256;
    if (idx < BANDC) arow[idx] = f2bf(vals[t] * inv);
  }
}

__global__ __launch_bounds__(256) void av_gemm(
    const ushort* __restrict__ aband, const ushort* __restrict__ VT,
    ushort* __restrict__ cbuf)
{
  const int nid = (blockIdx.x & 7) * 128 + (blockIdx.x >> 3); // 1024 blocks
  const int by = nid >> 3;            // 0..127: (b,i)
  const int b = by >> 5, i = by & 31;
  const int bx = nid & 7;             // d-block
  const int jj_lo = (i < 2) ? (2 - i) : 0;
  const int jj_hi = (i > 29) ? (34 - i) : 5;
  __shared__ ushort lds[16384];
  f32x4 acc[4][4];
  ACC_ZERO(acc)
  const ushort* Ablk = aband + ((size_t)b * S_LEN + i * 128) * BANDC;
  const ushort* Bblk = VT + (size_t)b * DIM * S_LEN + (size_t)bx * 128 * S_LEN + (i - 2) * 128;
  gemm_core(Ablk, BANDC, Bblk, S_LEN, jj_lo * 128, jj_hi * 128, lds, acc);

  // coalesced bf16 epilogue via LDS repack (32KB, exactly the dbuf space)
  __syncthreads();
  {
    const int lane_ = threadIdx.x & 63;
    const int wr_ = ((threadIdx.x >> 7) & 1) * 64;
    const int wc_ = ((threadIdx.x >> 6) & 1) * 64;
    const int rb_ = (lane_ >> 4) << 2;
    const int cb_ = lane_ & 15;
    #pragma unroll
    for (int m = 0; m < 4; m++)
      #pragma unroll
      for (int n = 0; n < 4; n++)
        #pragma unroll
        for (int r = 0; r < 4; r++) {
          const int rl = wr_ + m * 16 + rb_ + r;
          const int cl = wc_ + n * 16 + cb_;
          const int cs = cl ^ (((rl >> 2) & 3) << 4);
          lds[rl * 128 + cs] = f2bf(acc[m][n][r]);
        }
  }
  __syncthreads();
  ushort* dst = cbuf + ((size_t)b * S_LEN + i * 128) * DIM + bx * 128;
  #pragma unroll
  for (int it = 0; it < 8; ++it) {
    const int chunk = it * 256 + threadIdx.x;   // 16B chunks, 2048 total
    const int rl = chunk >> 4;                  // 16 chunks per 256B row
    const int c16 = chunk & 15;
    const int csw = (c16 * 16) ^ (((rl >> 2) & 3) << 5);
    bf16x8 v = *(const bf16x8*)((const char*)lds + rl * 256 + csw);
    *(bf16x8*)(dst + (size_t)rl * DIM + c16 * 8) = v;
  }
}

// ---------------- norm / head ----------------
__global__ __launch_bounds__(256) void ln_kernel(const float* __restrict__ y0, ushort* __restrict__ y1,
                                                 const float* __restrict__ gamma, const float* __restrict__ beta)
{
  __shared__ float red[4];
  const size_t q = blockIdx.x;
  const float* row = y0 + q * DIM;
  float v[4];
  #pragma unroll
  for (int t = 0; t < 4; t++) v[t] = row[threadIdx.x + t * 256];
  float mean = block_sum(v[0] + v[1] + v[2] + v[3], red) * (1.0f / DIM);
  float q2 = 0.0f;
  #pragma unroll
  for (int t = 0; t < 4; t++) { float d = v[t] - mean; q2 += d * d; }
  float var = block_sum(q2, red) * (1.0f / DIM);
  float rstd = rsqrtf(var + 1e-6f);
  #pragma unroll
  for (int t = 0; t < 4; t++) {
    int d = threadIdx.x + t * 256;
    y1[q * DIM + d] = f2bf((v[t] - mean) * rstd * gamma[d] + beta[d]);
  }
}

__global__ __launch_bounds__(256) void head_kernel(const float* __restrict__ h0,
    const float* __restrict__ gamma, const float* __restrict__ beta,
    const float* __restrict__ W2, const float* __restrict__ b2,
    float* __restrict__ out)
{
  __shared__ float red[4];
  const int qg = blockIdx.x;
  const int b = qg >> 12, s = qg & 4095;
  const float* row = h0 + (size_t)qg * DIM;
  float v[4];
  #pragma unroll
  for (int t = 0; t < 4; t++) v[t] = row[threadIdx.x + t * 256];
  float mean = block_sum(v[0] + v[1] + v[2] + v[3], red) * (1.0f / DIM);
  float q2 = 0.0f;
  #pragma unroll
  for (int t = 0; t < 4; t++) { float d = v[t] - mean; q2 += d * d; }
  float var = block_sum(q2, red) * (1.0f / DIM);
  float rstd = rsqrtf(var + 1e-6f);
  float part = 0.0f;
  #pragma unroll
  for (int t = 0; t < 4; t++) {
    int d = threadIdx.x + t * 256;
    part += ((v[t] - mean) * rstd * gamma[d] + beta[d]) * W2[d];
  }
  float logit = block_sum(part, red) + b2[0];
  if (threadIdx.x == 0) out[(size_t)s * BATCH + b] = 1.0f / (1.0f + expf(-logit));
}

// ---------------- launch ----------------
extern "C" void kernel_launch(void* const* d_in, const int* in_sizes, int n_in,
                              void* d_out, int out_size, void* d_ws, size_t ws_size,
                              hipStream_t stream) {
  const float* x     = (const float*)d_in[0];
  const float* Wk    = (const float*)d_in[1];
  const float* Wq    = (const float*)d_in[2];
  const float* Wv    = (const float*)d_in[3];
  const float* Wp    = (const float*)d_in[4];
  const float* W1    = (const float*)d_in[5];
  const float* b1    = (const float*)d_in[6];
  const float* W2    = (const float*)d_in[7];
  const float* b2    = (const float*)d_in[8];
  const float* gamma = (const float*)d_in[9];
  const float* beta  = (const float*)d_in[10];
  float* out = (float*)d_out;

  char* w = (char*)d_ws;
  ushort* xb   = (ushort*)(w + 0);            // 33,554,432 B
  ushort* wqkv = (ushort*)(w + 33554432);     //  6,291,456 B
  ushort* wpb  = (ushort*)(w + 39845888);     //  2,097,152 B
  ushort* w1b  = (ushort*)(w + 41943040);     //  2,097,152 B
  ushort* Qp   = (ushort*)(w + 44040192);     // 33,554,432 B
  ushort* Kp   = (ushort*)(w + 77594624);     // 33,554,432 B
  ushort* Vp   = (ushort*)(w + 111149056);    // 33,554,432 B
  ushort* VT   = (ushort*)(w + 144703488);    // 33,554,432 B
  float*  big  = (float*)(w + 178257920);     // 67,108,864 B (eband -> y0 -> h0)
  // reuse (sequentially dead regions):
  ushort* aband = Qp;     // Q dead after scores
  ushort* cbuf  = Kp;     // K dead after scores
  ushort* y1    = Vp;     // V dead after transpose
  float* eband = big;
  float* y0    = big;
  float* h0    = big;

  prep_x<<<16384, 256, 0, stream>>>(x, xb);
  f2bf_all<<<5120, 256, 0, stream>>>(Wk, Wq, Wv, Wp, W1, wqkv, wpb, w1b);

  qkv_gemm256<<<768, 512, 0, stream>>>(xb, wqkv, Kp, Qp, Vp);
  transpose_v<<<dim3(64, 16, 4), 256, 0, stream>>>(Vp, VT);
  scores_gemm<<<640, 256, 0, stream>>>(Qp, Kp, eband);
  softmax_band<<<16384, 256, 0, stream>>>(eband, aband);
  av_gemm<<<1024, 256, 0, stream>>>(aband, VT, cbuf);
  wp_gemm256<<<256, 512, 0, stream>>>(cbuf, wpb, x, y0);
  ln_kernel<<<16384, 256, 0, stream>>>(y0, y1, gamma, beta);
  ffn1_gemm256<<<256, 512, 0, stream>>>(y1, w1b, b1, h0);
  head_kernel<<<16384, 256, 0, stream>>>(h0, gamma, beta, W2, b2, out);
}

// Round 9
// 373.467 us; speedup vs baseline: 5.1539x; 1.0074x over previous
//
#include <hip/hip_runtime.h>
#include <stdint.h>
#include <math.h>

// ---------------- problem constants ----------------
#define S_LEN 4096
#define BATCH 4
#define DIM   1024
#define AP    256
#define NBLK  32            // S_LEN/128 row-blocks per batch
#define BANDC 640           // 5*128 band columns
#define SCALE 0.03125f      // 1/sqrt(1024)

typedef __attribute__((ext_vector_type(4))) float f32x4;
typedef __attribute__((ext_vector_type(8))) short bf16x8;

// ---------------- helpers ----------------
__device__ __forceinline__ ushort f2bf(float f) {
  union { float f; uint32_t u; } v; v.f = f;
  uint32_t r = v.u + 0x7FFFu + ((v.u >> 16) & 1u);
  return (ushort)(r >> 16);
}
__device__ __forceinline__ float bf2f(ushort u) {
  union { uint32_t u; float f; } v; v.u = ((uint32_t)u) << 16; return v.f;
}

__device__ __forceinline__ void gload16(const void* g, void* l) {
  __builtin_amdgcn_global_load_lds((const __attribute__((address_space(1))) void*)g,
                                   (__attribute__((address_space(3))) void*)l,
                                   16, 0, 0);
}

__device__ __forceinline__ float block_sum(float v, float* red) {
  #pragma unroll
  for (int o = 32; o > 0; o >>= 1) v += __shfl_xor(v, o, 64);
  const int w = threadIdx.x >> 6;
  if ((threadIdx.x & 63) == 0) red[w] = v;
  __syncthreads();
  v = red[0] + red[1] + red[2] + red[3];
  __syncthreads();
  return v;
}

__device__ __forceinline__ float block_max(float v, float* red) {
  #pragma unroll
  for (int o = 32; o > 0; o >>= 1) v = fmaxf(v, __shfl_xor(v, o, 64));
  const int w = threadIdx.x >> 6;
  if ((threadIdx.x & 63) == 0) red[w] = v;
  __syncthreads();
  v = fmaxf(fmaxf(red[0], red[1]), fmaxf(red[2], red[3]));
  __syncthreads();
  return v;
}

// =====================================================================
// 256x256 GEMM core v5 — read-ONE-PHASE-AHEAD schedule:
//  512 thr = 8 waves (2M x 4N), per-wave C = 128x64, acc[8][4] f32x4.
//  BK=64 as two [256][32] slabs/operand; 2 LDS buffers = 128 KiB.
//  Per phase: {ds_read NEXT phase's frags (4 or 8 b128) ; stage (0|2 units);
//              setprio(1) 16 MFMA on THIS phase's frags setprio(0) ;
//              [vmcnt] ; sched_barrier(0) ; s_barrier}.
//  - MFMA(p) waits a compiler-emitted COUNTED lgkm for frags read in p-1;
//    reads(p+1) drain under MFMA(p)  -> LDS/MFMA pipes overlap.
//  - Boundary-only sched_barrier(0) pins phases w/o intra-phase pinning.
//  - vmcnt(4)+barrier at ph0/ph2 ends (certify-before-barrier; vmcnt is
//    per-wave so every counted wait precedes a barrier before dep reads).
//    Last tile: ph0 uses vmcnt(0) (only 2 loads outstanding).
//  Quarter-wave conflict-free swizzle (verified conflicts=0): LDS slot
//  (row,s) holds global seg s^((row>>1)&3); source pre-swizzled, read
//  swizzled, LDS dest linear. A,B row-major [256 x K] (B^T). K%64==0.
// =====================================================================
#define STAGE2(dstbase, g0, g1, kcol) \
  gload16((g0) + (kcol), lds + (dstbase) + stOff); \
  gload16((g1) + (kcol), lds + (dstbase) + 4096 + stOff);

#define MFMA16(arow, av, bv) \
  __builtin_amdgcn_s_setprio(1); \
  _Pragma("unroll") for (int m = 0; m < 4; ++m) \
  _Pragma("unroll") for (int n = 0; n < 4; ++n) \
    acc[(arow) + m][n] = __builtin_amdgcn_mfma_f32_16x16x32_bf16(av[m], bv[n], acc[(arow) + m][n], 0, 0, 0); \
  __builtin_amdgcn_s_setprio(0);

#define PHASE_CUT() \
  __builtin_amdgcn_sched_barrier(0); \
  asm volatile("s_barrier" ::: "memory");

__device__ __forceinline__ void gemm256_core(
    const ushort* __restrict__ Ablk, int lda,
    const ushort* __restrict__ Bblk, int ldb,
    int K, ushort* __restrict__ lds,
    f32x4 acc[8][4])
{
  const int tid  = threadIdx.x;
  const int lane = tid & 63;
  const int wave = tid >> 6;
  const int wr = wave >> 2;       // 0..1
  const int wn = wave & 3;        // 0..3

  // staging: thread covers (srow = tid>>2, slot = tid&3); source pre-swizzled
  const int srow = tid >> 2;                       // 0..127
  const int gseg = (tid & 3) ^ ((tid >> 3) & 3);   // slot ^ ((srow>>1)&3)
  const ushort* gA0 = Ablk + (size_t)srow * lda + gseg * 8;
  const ushort* gA1 = Ablk + (size_t)(srow + 128) * lda + gseg * 8;
  const ushort* gB0 = Bblk + (size_t)srow * ldb + gseg * 8;
  const ushort* gB1 = Bblk + (size_t)(srow + 128) * ldb + gseg * 8;
  const int stOff = wave * 512;                    // wave-uniform LDS base (ushorts)

  // swizzled ds_read addressing
  const int l15 = lane & 15;
  const int seg = (lane >> 4) ^ ((lane >> 1) & 3); // kseg ^ ((row>>1)&3)
  const int raBase = (wr * 128 + l15) * 32 + seg * 8;   // + m*512
  const int rbBase = (wn * 64  + l15) * 32 + seg * 8;   // + n*512

  const int NT = K >> 6;   // BK = 64

  // buffer layout (ushorts): A-slab0 @0, A-slab1 @8192, B-slab0 @16384, B-slab1 @24576
  // units: u0=A-slab0, u1=B-slab0, u2=A-slab1, u3=B-slab1 (2 loads each)
  STAGE2(0,     gA0, gA1, 0)      // u0
  STAGE2(16384, gB0, gB1, 0)      // u1
  STAGE2(8192,  gA0, gA1, 32)     // u2
  STAGE2(24576, gB0, gB1, 32)     // u3
  asm volatile("s_waitcnt vmcnt(4)" ::: "memory");   // u0,u1 landed (own loads)
  asm volatile("s_barrier" ::: "memory");            // ...all waves'

  bf16x8 aE[4], aO[4], bE[4], bO[4];
  // F0(t=0): A m0-3 kk0 + B n0-3 kk0 (certified u0,u1)
  #pragma unroll
  for (int m = 0; m < 4; ++m) aE[m] = *(const bf16x8*)(lds + raBase + m * 512);
  #pragma unroll
  for (int n = 0; n < 4; ++n) bE[n] = *(const bf16x8*)(lds + 16384 + rbBase + n * 512);

  for (int t = 0; t < NT; ++t) {
    const int rb = (t & 1) * 32768;
    const int sb = rb ^ 32768;
    const int k1 = (t + 1) << 6;
    const bool more = (t + 1 < NT);

    // ---- phase 0: MFMA(m0-3,kk0) ; read aO kk0 ; stage u0,u1(t+1) ----
    #pragma unroll
    for (int m = 0; m < 4; ++m) aO[m] = *(const bf16x8*)(lds + rb + raBase + (m + 4) * 512);
    if (more) {
      STAGE2(sb,         gA0, gA1, k1)
      STAGE2(sb + 16384, gB0, gB1, k1)
    }
    MFMA16(0, aE, bE)
    if (more) asm volatile("s_waitcnt vmcnt(4)" ::: "memory");  // u2,u3(t) landed
    else      asm volatile("s_waitcnt vmcnt(0)" ::: "memory");
    PHASE_CUT()

    // ---- phase 1: MFMA(m4-7,kk0) ; read aE kk1 + bO kk1 ; stage u2,u3(t+1) ----
    #pragma unroll
    for (int m = 0; m < 4; ++m) aE[m] = *(const bf16x8*)(lds + rb + 8192 + raBase + m * 512);
    #pragma unroll
    for (int n = 0; n < 4; ++n) bO[n] = *(const bf16x8*)(lds + rb + 24576 + rbBase + n * 512);
    if (more) {
      STAGE2(sb + 8192,  gA0, gA1, k1 + 32)
      STAGE2(sb + 24576, gB0, gB1, k1 + 32)
    }
    MFMA16(4, aO, bE)
    PHASE_CUT()

    // ---- phase 2: MFMA(m0-3,kk1) ; read aO kk1 ----
    #pragma unroll
    for (int m = 0; m < 4; ++m) aO[m] = *(const bf16x8*)(lds + rb + 8192 + raBase + (m + 4) * 512);
    MFMA16(0, aE, bO)
    if (more) asm volatile("s_waitcnt vmcnt(4)" ::: "memory");  // u0,u1(t+1) landed
    PHASE_CUT()

    // ---- phase 3: MFMA(m4-7,kk1) ; read F0(t+1) from sb ----
    if (more) {
      #pragma unroll
      for (int m = 0; m < 4; ++m) aE[m] = *(const bf16x8*)(lds + sb + raBase + m * 512);
      #pragma unroll
      for (int n = 0; n < 4; ++n) bE[n] = *(const bf16x8*)(lds + sb + 16384 + rbBase + n * 512);
    }
    MFMA16(4, aO, bO)
    PHASE_CUT()
  }
}

#define ACC256_ZERO(acc) \
  _Pragma("unroll") for (int m_ = 0; m_ < 8; m_++) \
  _Pragma("unroll") for (int n_ = 0; n_ < 4; n_++) \
  _Pragma("unroll") for (int r_ = 0; r_ < 4; r_++) acc[m_][n_][r_] = 0.0f;

// coalesced bf16 epilogue: acc -> LDS (col-XOR, conflict-free) -> 16B/lane stores
__device__ __forceinline__ void epi256_store_bf16(
    f32x4 acc[8][4], ushort* __restrict__ lds,
    ushort* __restrict__ dst, int rowbase, int colb)
{
  __syncthreads();
  const int lane_ = threadIdx.x & 63;
  const int wave_ = threadIdx.x >> 6;
  const int wrb_ = (wave_ >> 2) * 128;
  const int wnb_ = (wave_ & 3) * 64;
  const int rb_ = (lane_ >> 4) << 2;
  const int cb_ = lane_ & 15;
  #pragma unroll
  for (int m = 0; m < 8; m++)
    #pragma unroll
    for (int n = 0; n < 4; n++)
      #pragma unroll
      for (int r = 0; r < 4; r++) {
        const int rl = wrb_ + m * 16 + rb_ + r;
        const int cl = wnb_ + n * 16 + cb_;
        const int cs = cl ^ (((rl >> 2) & 3) << 4);
        lds[rl * 256 + cs] = f2bf(acc[m][n][r]);
      }
  __syncthreads();
  #pragma unroll
  for (int it = 0; it < 16; ++it) {
    const int chunk = it * 512 + threadIdx.x;
    const int rl = chunk >> 5;
    const int c16 = chunk & 31;
    const int csw = (c16 * 16) ^ (((rl >> 2) & 3) << 5);
    bf16x8 v = *(const bf16x8*)((const char*)lds + rl * 512 + csw);
    *(bf16x8*)(dst + (size_t)(rowbase + rl) * DIM + colb + c16 * 8) = v;
  }
}

// same, with bias + ReLU applied (for ffn1 -> bf16 h0)
__device__ __forceinline__ void epi256_store_relu_bf16(
    f32x4 acc[8][4], ushort* __restrict__ lds,
    ushort* __restrict__ dst, int rowbase, int colb,
    const float* __restrict__ bias)
{
  __syncthreads();
  const int lane_ = threadIdx.x & 63;
  const int wave_ = threadIdx.x >> 6;
  const int wrb_ = (wave_ >> 2) * 128;
  const int wnb_ = (wave_ & 3) * 64;
  const int rb_ = (lane_ >> 4) << 2;
  const int cb_ = lane_ & 15;
  #pragma unroll
  for (int m = 0; m < 8; m++)
    #pragma unroll
    for (int n = 0; n < 4; n++) {
      const int cl = wnb_ + n * 16 + cb_;
      const float bv = bias[colb + cl];
      #pragma unroll
      for (int r = 0; r < 4; r++) {
        const int rl = wrb_ + m * 16 + rb_ + r;
        const int cs = cl ^ (((rl >> 2) & 3) << 4);
        lds[rl * 256 + cs] = f2bf(fmaxf(acc[m][n][r] + bv, 0.0f));
      }
    }
  __syncthreads();
  #pragma unroll
  for (int it = 0; it < 16; ++it) {
    const int chunk = it * 512 + threadIdx.x;
    const int rl = chunk >> 5;
    const int c16 = chunk & 31;
    const int csw = (c16 * 16) ^ (((rl >> 2) & 3) << 5);
    bf16x8 v = *(const bf16x8*)((const char*)lds + rl * 512 + csw);
    *(bf16x8*)(dst + (size_t)(rowbase + rl) * DIM + colb + c16 * 8) = v;
  }
}

#define EPI256_BEGIN(acc) { \
  const int lane_ = threadIdx.x & 63; \
  const int wave_ = threadIdx.x >> 6; \
  const int wrb_ = (wave_ >> 2) * 128; \
  const int wnb_ = (wave_ & 3) * 64; \
  const int rb_ = (lane_ >> 4) << 2; \
  const int cb_ = lane_ & 15; \
  _Pragma("unroll") for (int m_ = 0; m_ < 8; m_++) \
  _Pragma("unroll") for (int n_ = 0; n_ < 4; n_++) \
  _Pragma("unroll") for (int r_ = 0; r_ < 4; r_++) { \
    const int rloc = wrb_ + m_ * 16 + rb_ + r_; \
    const int cloc = wnb_ + n_ * 16 + cb_; \
    const float aval = acc[m_][n_][r_];
#define EPI256_END() } }

// =====================================================================
// 128x128 GEMM core (scores/av): unchanged from r7 (passing, conflicts=0)
// =====================================================================
__device__ __forceinline__ void gemm_core(
    const ushort* __restrict__ Ablk, int lda,
    const ushort* __restrict__ Bblk, int ldb,
    int k_begin, int k_end,
    ushort* __restrict__ lds,
    f32x4 acc[4][4])
{
  const int tid  = threadIdx.x;
  const int lane = tid & 63;
  const int wr = ((tid >> 7) & 1) * 64;
  const int wc = ((tid >> 6) & 1) * 64;
  const int lr = lane & 15;
  const int seg = (lane >> 4) ^ ((lane >> 1) & 3);

  const int srow = tid >> 2;                       // 0..63
  const int gseg = (tid & 3) ^ ((tid >> 3) & 3);
  const ushort* gA0 = Ablk + (size_t)srow * lda + gseg * 8;
  const ushort* gA1 = Ablk + (size_t)(srow + 64) * lda + gseg * 8;
  const ushort* gB0 = Bblk + (size_t)srow * ldb + gseg * 8;
  const ushort* gB1 = Bblk + (size_t)(srow + 64) * ldb + gseg * 8;
  const int stA = (tid >> 6) * 512;                // wave-uniform base (ushorts)

  const int NT = (k_end - k_begin) >> 5;

  gload16(gA0 + k_begin, lds + stA);
  gload16(gA1 + k_begin, lds + 2048 + stA);
  gload16(gB0 + k_begin, lds + 4096 + stA);
  gload16(gB1 + k_begin, lds + 6144 + stA);

  for (int t = 0; t < NT; ++t) {
    if (t + 1 < NT) {
      ushort* buf = lds + ((t + 1) & 1) * 8192;
      const int k0 = k_begin + (t + 1) * 32;
      gload16(gA0 + k0, buf + stA);
      gload16(gA1 + k0, buf + 2048 + stA);
      gload16(gB0 + k0, buf + 4096 + stA);
      gload16(gB1 + k0, buf + 6144 + stA);
      asm volatile("s_waitcnt vmcnt(4)" ::: "memory");
    } else {
      asm volatile("s_waitcnt vmcnt(0)" ::: "memory");
    }
    __builtin_amdgcn_s_barrier();

    const ushort* buf = lds + (t & 1) * 8192;
    bf16x8 af[4], bfv[4];
    #pragma unroll
    for (int m = 0; m < 4; m++)
      af[m] = *(const bf16x8*)(buf + (wr + m * 16 + lr) * 32 + seg * 8);
    #pragma unroll
    for (int n = 0; n < 4; n++)
      bfv[n] = *(const bf16x8*)(buf + 4096 + (wc + n * 16 + lr) * 32 + seg * 8);

    __builtin_amdgcn_s_setprio(1);
    #pragma unroll
    for (int m = 0; m < 4; m++)
      #pragma unroll
      for (int n = 0; n < 4; n++)
        acc[m][n] = __builtin_amdgcn_mfma_f32_16x16x32_bf16(af[m], bfv[n], acc[m][n], 0, 0, 0);
    __builtin_amdgcn_s_setprio(0);
    asm volatile("s_waitcnt lgkmcnt(0)" ::: "memory");
  }
}

#define ACC_ZERO(acc) \
  _Pragma("unroll") for (int m_ = 0; m_ < 4; m_++) \
  _Pragma("unroll") for (int n_ = 0; n_ < 4; n_++) \
  _Pragma("unroll") for (int r_ = 0; r_ < 4; r_++) acc[m_][n_][r_] = 0.0f;

#define EPI_BEGIN(acc) { \
  const int lane_ = threadIdx.x & 63; \
  const int wr_ = ((threadIdx.x >> 7) & 1) * 64; \
  const int wc_ = ((threadIdx.x >> 6) & 1) * 64; \
  const int rb_ = (lane_ >> 4) << 2; \
  const int cb_ = lane_ & 15; \
  _Pragma("unroll") for (int m_ = 0; m_ < 4; m_++) \
  _Pragma("unroll") for (int n_ = 0; n_ < 4; n_++) \
  _Pragma("unroll") for (int r_ = 0; r_ < 4; r_++) { \
    const int rloc = wr_ + m_ * 16 + rb_ + r_; \
    const int cloc = wc_ + n_ * 16 + cb_; \
    const float aval = acc[m_][n_][r_];
#define EPI_END() } }

// ---------------- elementwise prep kernels ----------------
__global__ __launch_bounds__(256) void prep_x(const float* __restrict__ x, ushort* __restrict__ xb) {
  size_t idx = ((size_t)blockIdx.x * 256 + threadIdx.x) * 4;   // dest flat index (b,s,d)
  int d = (int)(idx & 1023);
  int s = (int)((idx >> 10) & 4095);
  int b = (int)(idx >> 22);
  float4 v = *(const float4*)(x + ((size_t)s * BATCH + b) * DIM + d);
  ushort4 o;
  o.x = f2bf(v.x); o.y = f2bf(v.y); o.z = f2bf(v.z); o.w = f2bf(v.w);
  *(ushort4*)(xb + idx) = o;
}

__global__ __launch_bounds__(256) void f2bf_all(
    const float* __restrict__ Wk, const float* __restrict__ Wq, const float* __restrict__ Wv,
    const float* __restrict__ Wp, const float* __restrict__ W1,
    ushort* __restrict__ wqkv, ushort* __restrict__ wpb, ushort* __restrict__ w1b)
{
  const int g = blockIdx.x;
  const int which = g >> 10;
  const int idx = ((g & 1023) * 256 + threadIdx.x) * 4;
  const float* src = (which == 0) ? Wk : (which == 1) ? Wq : (which == 2) ? Wv
                   : (which == 3) ? Wp : W1;
  ushort* dst = (which == 0) ? wqkv : (which == 1) ? wqkv + 1048576
              : (which == 2) ? wqkv + 2097152 : (which == 3) ? wpb : w1b;
  float4 v = *(const float4*)(src + idx);
  ushort4 o;
  o.x = f2bf(v.x); o.y = f2bf(v.y); o.z = f2bf(v.z); o.w = f2bf(v.w);
  *(ushort4*)(dst + idx) = o;
}

// ---------------- big GEMMs on the 256 core ----------------
__global__ __launch_bounds__(512, 2) void qkv_gemm256(
    const ushort* __restrict__ xb, const ushort* __restrict__ wqkv,
    ushort* __restrict__ Kp, ushort* __restrict__ Qp, ushort* __restrict__ Vp)
{
  __shared__ ushort lds[65536];
  const int nid = (blockIdx.x & 7) * 96 + (blockIdx.x >> 3);
  const int by = nid / 12;     // 0..63
  const int bx = nid % 12;     // 0..11
  f32x4 acc[8][4];
  ACC256_ZERO(acc)
  gemm256_core(xb + (size_t)by * 256 * DIM, DIM,
               wqkv + (size_t)bx * 256 * DIM, DIM, DIM, lds, acc);
  ushort* dst = (bx < 4) ? Kp : (bx < 8) ? Qp : Vp;
  epi256_store_bf16(acc, lds, dst, by * 256, (bx & 3) * 256);
}

__global__ __launch_bounds__(512, 2) void wp_gemm256(
    const ushort* __restrict__ cbuf, const ushort* __restrict__ wpb,
    const float* __restrict__ x, float* __restrict__ y0)
{
  __shared__ ushort lds[65536];
  const int nid = (blockIdx.x & 7) * 32 + (blockIdx.x >> 3);   // 256 blocks
  const int by = nid >> 2;     // 0..63
  const int bx = nid & 3;      // 0..3
  f32x4 acc[8][4];
  ACC256_ZERO(acc)
  gemm256_core(cbuf + (size_t)by * 256 * DIM, DIM,
               wpb + (size_t)bx * 256 * DIM, DIM, DIM, lds, acc);
  EPI256_BEGIN(acc)
    int row = by * 256 + rloc;           // b*4096+s
    int col = bx * 256 + cloc;
    int b = row >> 12, s = row & 4095;
    y0[(size_t)row * DIM + col] = aval + x[((size_t)s * BATCH + b) * DIM + col];
  EPI256_END()
}

__global__ __launch_bounds__(512, 2) void ffn1_gemm256(
    const ushort* __restrict__ y1, const ushort* __restrict__ w1b,
    const float* __restrict__ b1, ushort* __restrict__ h0)
{
  __shared__ ushort lds[65536];
  const int nid = (blockIdx.x & 7) * 32 + (blockIdx.x >> 3);
  const int by = nid >> 2;
  const int bx = nid & 3;
  f32x4 acc[8][4];
  ACC256_ZERO(acc)
  gemm256_core(y1 + (size_t)by * 256 * DIM, DIM,
               w1b + (size_t)bx * 256 * DIM, DIM, DIM, lds, acc);
  epi256_store_relu_bf16(acc, lds, h0, by * 256, bx * 256, b1);
}

// ---------------- attention path (128 core) ----------------
__global__ __launch_bounds__(256) void transpose_v(const ushort* __restrict__ V, ushort* __restrict__ VT) {
  __shared__ ushort tile[64][66];
  const int s0 = blockIdx.x * 64, d0 = blockIdx.y * 64, b = blockIdx.z;
  const ushort* Vb = V + (size_t)b * S_LEN * DIM;
  ushort* VTb = VT + (size_t)b * DIM * S_LEN;
  #pragma unroll
  for (int it = 0; it < 16; it++) {
    int flat = it * 256 + threadIdx.x;
    int r = flat >> 6, c = flat & 63;
    tile[r][c] = Vb[(size_t)(s0 + r) * DIM + d0 + c];
  }
  __syncthreads();
  #pragma unroll
  for (int it = 0; it < 16; it++) {
    int flat = it * 256 + threadIdx.x;
    int r = flat >> 6, c = flat & 63;
    VTb[(size_t)(d0 + r) * S_LEN + s0 + c] = tile[c][r];
  }
}

__global__ __launch_bounds__(256) void scores_gemm(
    const ushort* __restrict__ Qp, const ushort* __restrict__ Kp,
    float* __restrict__ eband)
{
  const int nid = (blockIdx.x & 7) * 80 + (blockIdx.x >> 3);   // 640 blocks
  const int b   = nid / 160;
  const int rem = nid % 160;
  const int i   = rem / 5;
  const int jj  = rem % 5;
  const int j   = i - 2 + jj;
  if (j < 0 || j >= NBLK) return;
  __shared__ ushort lds[16384];
  f32x4 acc[4][4];
  ACC_ZERO(acc)
  gemm_core(Qp + ((size_t)b * S_LEN + i * 128) * DIM, DIM,
            Kp + ((size_t)b * S_LEN + j * 128) * DIM, DIM, 0, DIM, lds, acc);
  EPI_BEGIN(acc)
    int q = i * 128 + rloc;
    int k = j * 128 + cloc;
    float v = aval * SCALE;
    int dqk = q - k;
    if (dqk == 0 || dqk > AP || dqk < -AP) v = -INFINITY;
    eband[((size_t)b * S_LEN + q) * BANDC + jj * 128 + cloc] = v;
  EPI_END()
}

__global__ __launch_bounds__(256) void softmax_band(const float* __restrict__ eband,
                                                    ushort* __restrict__ aband)
{
  __shared__ float red[4];
  const int qg = blockIdx.x;          // 0..16383
  const int s  = qg & 4095;
  const int i  = s >> 7;
  const float* row = eband + (size_t)qg * BANDC;
  ushort* arow = aband + (size_t)qg * BANDC;

  float vals[3];
  bool  valid[3];
  float mx = -INFINITY;
  #pragma unroll
  for (int t = 0; t < 3; t++) {
    int idx = threadIdx.x + t * 256;
    int jj = idx >> 7;
    int j = i - 2 + jj;
    bool ok = (idx < BANDC) && (j >= 0) && (j < NBLK);
    valid[t] = ok;
    float v = ok ? row[idx] : -INFINITY;
    vals[t] = v;
    mx = fmaxf(mx, v);
  }
  float bmax = block_max(mx, red);
  float ss = 0.0f;
  #pragma unroll
  for (int t = 0; t < 3; t++) {
    float e = valid[t] ? __expf(vals[t] - bmax) : 0.0f;
    vals[t] = e;
    ss += e;
  }
  float inv = 1.0f / block_sum(ss, red);
  #pragma unroll
  for (int t = 0; t < 3; t++) {
    int idx = threadIdx.x + t * 256;
    if (idx < BANDC) arow[idx] = f2bf(vals[t] * inv);
  }
}

__global__ __launch_bounds__(256) void av_gemm(
    const ushort* __restrict__ aband, const ushort* __restrict__ VT,
    ushort* __restrict__ cbuf)
{
  const int nid = (blockIdx.x & 7) * 128 + (blockIdx.x >> 3); // 1024 blocks
  const int by = nid >> 3;            // 0..127: (b,i)
  const int b = by >> 5, i = by & 31;
  const int bx = nid & 7;             // d-block
  const int jj_lo = (i < 2) ? (2 - i) : 0;
  const int jj_hi = (i > 29) ? (34 - i) : 5;
  __shared__ ushort lds[16384];
  f32x4 acc[4][4];
  ACC_ZERO(acc)
  const ushort* Ablk = aband + ((size_t)b * S_LEN + i * 128) * BANDC;
  const ushort* Bblk = VT + (size_t)b * DIM * S_LEN + (size_t)bx * 128 * S_LEN + (i - 2) * 128;
  gemm_core(Ablk, BANDC, Bblk, S_LEN, jj_lo * 128, jj_hi * 128, lds, acc);

  __syncthreads();
  {
    const int lane_ = threadIdx.x & 63;
    const int wr_ = ((threadIdx.x >> 7) & 1) * 64;
    const int wc_ = ((threadIdx.x >> 6) & 1) * 64;
    const int rb_ = (lane_ >> 4) << 2;
    const int cb_ = lane_ & 15;
    #pragma unroll
    for (int m = 0; m < 4; m++)
      #pragma unroll
      for (int n = 0; n < 4; n++)
        #pragma unroll
        for (int r = 0; r < 4; r++) {
          const int rl = wr_ + m * 16 + rb_ + r;
          const int cl = wc_ + n * 16 + cb_;
          const int cs = cl ^ (((rl >> 2) & 3) << 4);
          lds[rl * 128 + cs] = f2bf(acc[m][n][r]);
        }
  }
  __syncthreads();
  ushort* dst = cbuf + ((size_t)b * S_LEN + i * 128) * DIM + bx * 128;
  #pragma unroll
  for (int it = 0; it < 8; ++it) {
    const int chunk = it * 256 + threadIdx.x;
    const int rl = chunk >> 4;
    const int c16 = chunk & 15;
    const int csw = (c16 * 16) ^ (((rl >> 2) & 3) << 5);
    bf16x8 v = *(const bf16x8*)((const char*)lds + rl * 256 + csw);
    *(bf16x8*)(dst + (size_t)rl * DIM + c16 * 8) = v;
  }
}

// ---------------- norm / head ----------------
__global__ __launch_bounds__(256) void ln_kernel(const float* __restrict__ y0, ushort* __restrict__ y1,
                                                 const float* __restrict__ gamma, const float* __restrict__ beta)
{
  __shared__ float red[4];
  const size_t q = blockIdx.x;
  const int d0 = threadIdx.x * 4;
  float4 v = *(const float4*)(y0 + q * DIM + d0);
  float mean = block_sum(v.x + v.y + v.z + v.w, red) * (1.0f / DIM);
  float q2 = (v.x - mean) * (v.x - mean) + (v.y - mean) * (v.y - mean)
           + (v.z - mean) * (v.z - mean) + (v.w - mean) * (v.w - mean);
  float var = block_sum(q2, red) * (1.0f / DIM);
  float rstd = rsqrtf(var + 1e-6f);
  float4 g = *(const float4*)(gamma + d0);
  float4 bb = *(const float4*)(beta + d0);
  ushort4 o;
  o.x = f2bf((v.x - mean) * rstd * g.x + bb.x);
  o.y = f2bf((v.y - mean) * rstd * g.y + bb.y);
  o.z = f2bf((v.z - mean) * rstd * g.z + bb.z);
  o.w = f2bf((v.w - mean) * rstd * g.w + bb.w);
  *(ushort4*)(y1 + q * DIM + d0) = o;
}

__global__ __launch_bounds__(256) void head_kernel(const ushort* __restrict__ h0,
    const float* __restrict__ gamma, const float* __restrict__ beta,
    const float* __restrict__ W2, const float* __restrict__ b2,
    float* __restrict__ out)
{
  __shared__ float red[4];
  const int qg = blockIdx.x;
  const int b = qg >> 12, s = qg & 4095;
  const int d0 = threadIdx.x * 4;
  ushort4 u = *(const ushort4*)(h0 + (size_t)qg * DIM + d0);
  float v0 = bf2f(u.x), v1 = bf2f(u.y), v2 = bf2f(u.z), v3 = bf2f(u.w);
  float mean = block_sum(v0 + v1 + v2 + v3, red) * (1.0f / DIM);
  float q2 = (v0 - mean) * (v0 - mean) + (v1 - mean) * (v1 - mean)
           + (v2 - mean) * (v2 - mean) + (v3 - mean) * (v3 - mean);
  float var = block_sum(q2, red) * (1.0f / DIM);
  float rstd = rsqrtf(var + 1e-6f);
  float4 g = *(const float4*)(gamma + d0);
  float4 bb = *(const float4*)(beta + d0);
  float4 w2 = *(const float4*)(W2 + d0);
  float part = ((v0 - mean) * rstd * g.x + bb.x) * w2.x
             + ((v1 - mean) * rstd * g.y + bb.y) * w2.y
             + ((v2 - mean) * rstd * g.z + bb.z) * w2.z
             + ((v3 - mean) * rstd * g.w + bb.w) * w2.w;
  float logit = block_sum(part, red) + b2[0];
  if (threadIdx.x == 0) out[(size_t)s * BATCH + b] = 1.0f / (1.0f + expf(-logit));
}

// ---------------- launch ----------------
extern "C" void kernel_launch(void* const* d_in, const int* in_sizes, int n_in,
                              void* d_out, int out_size, void* d_ws, size_t ws_size,
                              hipStream_t stream) {
  const float* x     = (const float*)d_in[0];
  const float* Wk    = (const float*)d_in[1];
  const float* Wq    = (const float*)d_in[2];
  const float* Wv    = (const float*)d_in[3];
  const float* Wp    = (const float*)d_in[4];
  const float* W1    = (const float*)d_in[5];
  const float* b1    = (const float*)d_in[6];
  const float* W2    = (const float*)d_in[7];
  const float* b2    = (const float*)d_in[8];
  const float* gamma = (const float*)d_in[9];
  const float* beta  = (const float*)d_in[10];
  float* out = (float*)d_out;

  char* w = (char*)d_ws;
  ushort* xb   = (ushort*)(w + 0);            // 33,554,432 B
  ushort* wqkv = (ushort*)(w + 33554432);     //  6,291,456 B
  ushort* wpb  = (ushort*)(w + 39845888);     //  2,097,152 B
  ushort* w1b  = (ushort*)(w + 41943040);     //  2,097,152 B
  ushort* Qp   = (ushort*)(w + 44040192);     // 33,554,432 B
  ushort* Kp   = (ushort*)(w + 77594624);     // 33,554,432 B
  ushort* Vp   = (ushort*)(w + 111149056);    // 33,554,432 B
  ushort* VT   = (ushort*)(w + 144703488);    // 33,554,432 B
  float*  big  = (float*)(w + 178257920);     // 67,108,864 B (eband -> y0)
  // reuse (sequentially dead regions):
  ushort* aband = Qp;     // Q dead after scores
  ushort* cbuf  = Kp;     // K dead after scores
  ushort* y1    = Vp;     // V dead after transpose
  ushort* h0    = xb;     // xb dead after qkv (bf16 h0)
  float* eband = big;
  float* y0    = big;

  prep_x<<<16384, 256, 0, stream>>>(x, xb);
  f2bf_all<<<5120, 256, 0, stream>>>(Wk, Wq, Wv, Wp, W1, wqkv, wpb, w1b);

  qkv_gemm256<<<768, 512, 0, stream>>>(xb, wqkv, Kp, Qp, Vp);
  transpose_v<<<dim3(64, 16, 4), 256, 0, stream>>>(Vp, VT);
  scores_gemm<<<640, 256, 0, stream>>>(Qp, Kp, eband);
  softmax_band<<<16384, 256, 0, stream>>>(eband, aband);
  av_gemm<<<1024, 256, 0, stream>>>(aband, VT, cbuf);
  wp_gemm256<<<256, 512, 0, stream>>>(cbuf, wpb, x, y0);
  ln_kernel<<<16384, 256, 0, stream>>>(y0, y1, gamma, beta);
  ffn1_gemm256<<<256, 512, 0, stream>>>(y1, w1b, b1, h0);
  head_kernel<<<16384, 256, 0, stream>>>(h0, gamma, beta, W2, b2, out);
}

// Round 10
// 363.434 us; speedup vs baseline: 5.2961x; 1.0276x over previous
//
#include <hip/hip_runtime.h>
#include <stdint.h>
#include <math.h>

// ---------------- problem constants ----------------
#define S_LEN 4096
#define BATCH 4
#define DIM   1024
#define AP    256
#define BANDC 768           // 3*256 band columns for 256-row blocks
#define SCALE 0.03125f      // 1/sqrt(1024)

typedef __attribute__((ext_vector_type(4))) float f32x4;
typedef __attribute__((ext_vector_type(8))) short bf16x8;

// ---------------- helpers ----------------
__device__ __forceinline__ ushort f2bf(float f) {
  union { float f; uint32_t u; } v; v.f = f;
  uint32_t r = v.u + 0x7FFFu + ((v.u >> 16) & 1u);
  return (ushort)(r >> 16);
}
__device__ __forceinline__ float bf2f(ushort u) {
  union { uint32_t u; float f; } v; v.u = ((uint32_t)u) << 16; return v.f;
}
__device__ __forceinline__ ushort f2h(float f) {
  union { _Float16 h; ushort u; } v; v.h = (_Float16)f; return v.u;
}
__device__ __forceinline__ float h2f(ushort u) {
  union { ushort u; _Float16 h; } v; v.u = u; return (float)v.h;
}

__device__ __forceinline__ void gload16(const void* g, void* l) {
  __builtin_amdgcn_global_load_lds((const __attribute__((address_space(1))) void*)g,
                                   (__attribute__((address_space(3))) void*)l,
                                   16, 0, 0);
}

__device__ __forceinline__ float wave_sum(float v) {
  #pragma unroll
  for (int o = 32; o > 0; o >>= 1) v += __shfl_xor(v, o, 64);
  return v;
}
__device__ __forceinline__ float wave_max(float v) {
  #pragma unroll
  for (int o = 32; o > 0; o >>= 1) v = fmaxf(v, __shfl_xor(v, o, 64));
  return v;
}

// =====================================================================
// 256x256 GEMM core (best-measured variant, ~900 GF):
//  512 thr = 8 waves (2M x 4N), per-wave C = 128x64, acc[8][4] f32x4.
//  BK=64 as two [256][32] slabs/operand; 2 LDS buffers = 128 KiB.
//  Read-one-phase-ahead; vmcnt certify-before-barrier discipline.
//  Quarter-wave conflict-free swizzle (verified conflicts=0).
//  A,B row-major [256 x K] (B = B^T). Requires K % 64 == 0, K >= 128.
// =====================================================================
#define STAGE2(dstbase, g0, g1, kcol) \
  gload16((g0) + (kcol), lds + (dstbase) + stOff); \
  gload16((g1) + (kcol), lds + (dstbase) + 4096 + stOff);

#define MFMA16(arow, av, bv) \
  __builtin_amdgcn_s_setprio(1); \
  _Pragma("unroll") for (int m = 0; m < 4; ++m) \
  _Pragma("unroll") for (int n = 0; n < 4; ++n) \
    acc[(arow) + m][n] = __builtin_amdgcn_mfma_f32_16x16x32_bf16(av[m], bv[n], acc[(arow) + m][n], 0, 0, 0); \
  __builtin_amdgcn_s_setprio(0);

#define PHASE_CUT() \
  __builtin_amdgcn_sched_barrier(0); \
  asm volatile("s_barrier" ::: "memory");

__device__ __forceinline__ void gemm256_core(
    const ushort* __restrict__ Ablk, int lda,
    const ushort* __restrict__ Bblk, int ldb,
    int K, ushort* __restrict__ lds,
    f32x4 acc[8][4])
{
  const int tid  = threadIdx.x;
  const int lane = tid & 63;
  const int wave = tid >> 6;
  const int wr = wave >> 2;       // 0..1
  const int wn = wave & 3;        // 0..3

  const int srow = tid >> 2;                       // 0..127
  const int gseg = (tid & 3) ^ ((tid >> 3) & 3);   // slot ^ ((srow>>1)&3)
  const ushort* gA0 = Ablk + (size_t)srow * lda + gseg * 8;
  const ushort* gA1 = Ablk + (size_t)(srow + 128) * lda + gseg * 8;
  const ushort* gB0 = Bblk + (size_t)srow * ldb + gseg * 8;
  const ushort* gB1 = Bblk + (size_t)(srow + 128) * ldb + gseg * 8;
  const int stOff = wave * 512;                    // wave-uniform LDS base (ushorts)

  const int l15 = lane & 15;
  const int seg = (lane >> 4) ^ ((lane >> 1) & 3); // kseg ^ ((row>>1)&3)
  const int raBase = (wr * 128 + l15) * 32 + seg * 8;   // + m*512
  const int rbBase = (wn * 64  + l15) * 32 + seg * 8;   // + n*512

  const int NT = K >> 6;   // BK = 64

  // buffer layout (ushorts): A-slab0 @0, A-slab1 @8192, B-slab0 @16384, B-slab1 @24576
  STAGE2(0,     gA0, gA1, 0)      // u0
  STAGE2(16384, gB0, gB1, 0)      // u1
  STAGE2(8192,  gA0, gA1, 32)     // u2
  STAGE2(24576, gB0, gB1, 32)     // u3
  asm volatile("s_waitcnt vmcnt(4)" ::: "memory");   // u0,u1 landed (own loads)
  asm volatile("s_barrier" ::: "memory");            // ...all waves'

  bf16x8 aE[4], aO[4], bE[4], bO[4];
  #pragma unroll
  for (int m = 0; m < 4; ++m) aE[m] = *(const bf16x8*)(lds + raBase + m * 512);
  #pragma unroll
  for (int n = 0; n < 4; ++n) bE[n] = *(const bf16x8*)(lds + 16384 + rbBase + n * 512);

  for (int t = 0; t < NT; ++t) {
    const int rb = (t & 1) * 32768;
    const int sb = rb ^ 32768;
    const int k1 = (t + 1) << 6;
    const bool more = (t + 1 < NT);

    // ---- phase 0 ----
    #pragma unroll
    for (int m = 0; m < 4; ++m) aO[m] = *(const bf16x8*)(lds + rb + raBase + (m + 4) * 512);
    if (more) {
      STAGE2(sb,         gA0, gA1, k1)
      STAGE2(sb + 16384, gB0, gB1, k1)
    }
    MFMA16(0, aE, bE)
    if (more) asm volatile("s_waitcnt vmcnt(4)" ::: "memory");  // u2,u3(t) landed
    else      asm volatile("s_waitcnt vmcnt(0)" ::: "memory");
    PHASE_CUT()

    // ---- phase 1 ----
    #pragma unroll
    for (int m = 0; m < 4; ++m) aE[m] = *(const bf16x8*)(lds + rb + 8192 + raBase + m * 512);
    #pragma unroll
    for (int n = 0; n < 4; ++n) bO[n] = *(const bf16x8*)(lds + rb + 24576 + rbBase + n * 512);
    if (more) {
      STAGE2(sb + 8192,  gA0, gA1, k1 + 32)
      STAGE2(sb + 24576, gB0, gB1, k1 + 32)
    }
    MFMA16(4, aO, bE)
    PHASE_CUT()

    // ---- phase 2 ----
    #pragma unroll
    for (int m = 0; m < 4; ++m) aO[m] = *(const bf16x8*)(lds + rb + 8192 + raBase + (m + 4) * 512);
    MFMA16(0, aE, bO)
    if (more) asm volatile("s_waitcnt vmcnt(4)" ::: "memory");  // u0,u1(t+1) landed
    PHASE_CUT()

    // ---- phase 3 ----
    if (more) {
      #pragma unroll
      for (int m = 0; m < 4; ++m) aE[m] = *(const bf16x8*)(lds + sb + raBase + m * 512);
      #pragma unroll
      for (int n = 0; n < 4; ++n) bE[n] = *(const bf16x8*)(lds + sb + 16384 + rbBase + n * 512);
    }
    MFMA16(4, aO, bO)
    PHASE_CUT()
  }
}

#define ACC256_ZERO(acc) \
  _Pragma("unroll") for (int m_ = 0; m_ < 8; m_++) \
  _Pragma("unroll") for (int n_ = 0; n_ < 4; n_++) \
  _Pragma("unroll") for (int r_ = 0; r_ < 4; r_++) acc[m_][n_][r_] = 0.0f;

// coalesced bf16 epilogue: acc -> LDS (col-XOR, conflict-free) -> 16B/lane stores
__device__ __forceinline__ void epi256_store_bf16(
    f32x4 acc[8][4], ushort* __restrict__ lds,
    ushort* __restrict__ dst, int rowbase, int colb)
{
  __syncthreads();
  const int lane_ = threadIdx.x & 63;
  const int wave_ = threadIdx.x >> 6;
  const int wrb_ = (wave_ >> 2) * 128;
  const int wnb_ = (wave_ & 3) * 64;
  const int rb_ = (lane_ >> 4) << 2;
  const int cb_ = lane_ & 15;
  #pragma unroll
  for (int m = 0; m < 8; m++)
    #pragma unroll
    for (int n = 0; n < 4; n++)
      #pragma unroll
      for (int r = 0; r < 4; r++) {
        const int rl = wrb_ + m * 16 + rb_ + r;
        const int cl = wnb_ + n * 16 + cb_;
        const int cs = cl ^ (((rl >> 2) & 3) << 4);
        lds[rl * 256 + cs] = f2bf(acc[m][n][r]);
      }
  __syncthreads();
  #pragma unroll
  for (int it = 0; it < 16; ++it) {
    const int chunk = it * 512 + threadIdx.x;
    const int rl = chunk >> 5;
    const int c16 = chunk & 31;
    const int csw = (c16 * 16) ^ (((rl >> 2) & 3) << 5);
    bf16x8 v = *(const bf16x8*)((const char*)lds + rl * 512 + csw);
    *(bf16x8*)(dst + (size_t)(rowbase + rl) * DIM + colb + c16 * 8) = v;
  }
}

// bias + ReLU variant (ffn1 -> bf16 h0)
__device__ __forceinline__ void epi256_store_relu_bf16(
    f32x4 acc[8][4], ushort* __restrict__ lds,
    ushort* __restrict__ dst, int rowbase, int colb,
    const float* __restrict__ bias)
{
  __syncthreads();
  const int lane_ = threadIdx.x & 63;
  const int wave_ = threadIdx.x >> 6;
  const int wrb_ = (wave_ >> 2) * 128;
  const int wnb_ = (wave_ & 3) * 64;
  const int rb_ = (lane_ >> 4) << 2;
  const int cb_ = lane_ & 15;
  #pragma unroll
  for (int m = 0; m < 8; m++)
    #pragma unroll
    for (int n = 0; n < 4; n++) {
      const int cl = wnb_ + n * 16 + cb_;
      const float bv = bias[colb + cl];
      #pragma unroll
      for (int r = 0; r < 4; r++) {
        const int rl = wrb_ + m * 16 + rb_ + r;
        const int cs = cl ^ (((rl >> 2) & 3) << 4);
        lds[rl * 256 + cs] = f2bf(fmaxf(acc[m][n][r] + bv, 0.0f));
      }
    }
  __syncthreads();
  #pragma unroll
  for (int it = 0; it < 16; ++it) {
    const int chunk = it * 512 + threadIdx.x;
    const int rl = chunk >> 5;
    const int c16 = chunk & 31;
    const int csw = (c16 * 16) ^ (((rl >> 2) & 3) << 5);
    bf16x8 v = *(const bf16x8*)((const char*)lds + rl * 512 + csw);
    *(bf16x8*)(dst + (size_t)(rowbase + rl) * DIM + colb + c16 * 8) = v;
  }
}

#define EPI256_BEGIN(acc) { \
  const int lane_ = threadIdx.x & 63; \
  const int wave_ = threadIdx.x >> 6; \
  const int wrb_ = (wave_ >> 2) * 128; \
  const int wnb_ = (wave_ & 3) * 64; \
  const int rb_ = (lane_ >> 4) << 2; \
  const int cb_ = lane_ & 15; \
  _Pragma("unroll") for (int m_ = 0; m_ < 8; m_++) \
  _Pragma("unroll") for (int n_ = 0; n_ < 4; n_++) \
  _Pragma("unroll") for (int r_ = 0; r_ < 4; r_++) { \
    const int rloc = wrb_ + m_ * 16 + rb_ + r_; \
    const int cloc = wnb_ + n_ * 16 + cb_; \
    const float aval = acc[m_][n_][r_];
#define EPI256_END() } }

// ---------------- elementwise prep kernels ----------------
__global__ __launch_bounds__(256) void prep_x(const float* __restrict__ x, ushort* __restrict__ xb) {
  size_t idx = ((size_t)blockIdx.x * 256 + threadIdx.x) * 4;   // dest flat index (b,s,d)
  int d = (int)(idx & 1023);
  int s = (int)((idx >> 10) & 4095);
  int b = (int)(idx >> 22);
  float4 v = *(const float4*)(x + ((size_t)s * BATCH + b) * DIM + d);
  ushort4 o;
  o.x = f2bf(v.x); o.y = f2bf(v.y); o.z = f2bf(v.z); o.w = f2bf(v.w);
  *(ushort4*)(xb + idx) = o;
}

__global__ __launch_bounds__(256) void f2bf_all(
    const float* __restrict__ Wk, const float* __restrict__ Wq, const float* __restrict__ Wv,
    const float* __restrict__ Wp, const float* __restrict__ W1,
    ushort* __restrict__ wqkv, ushort* __restrict__ wpb, ushort* __restrict__ w1b)
{
  const int g = blockIdx.x;
  const int which = g >> 10;
  const int idx = ((g & 1023) * 256 + threadIdx.x) * 4;
  const float* src = (which == 0) ? Wk : (which == 1) ? Wq : (which == 2) ? Wv
                   : (which == 3) ? Wp : W1;
  ushort* dst = (which == 0) ? wqkv : (which == 1) ? wqkv + 1048576
              : (which == 2) ? wqkv + 2097152 : (which == 3) ? wpb : w1b;
  float4 v = *(const float4*)(src + idx);
  ushort4 o;
  o.x = f2bf(v.x); o.y = f2bf(v.y); o.z = f2bf(v.z); o.w = f2bf(v.w);
  *(ushort4*)(dst + idx) = o;
}

// ---------------- GEMMs on the 256 core ----------------
__global__ __launch_bounds__(512, 2) void qkv_gemm256(
    const ushort* __restrict__ xb, const ushort* __restrict__ wqkv,
    ushort* __restrict__ Kp, ushort* __restrict__ Qp, ushort* __restrict__ Vp)
{
  __shared__ ushort lds[65536];
  const int nid = (blockIdx.x & 7) * 96 + (blockIdx.x >> 3);  // XCD-chunked
  const int by = nid / 12;     // 0..63
  const int bx = nid % 12;     // 0..11
  f32x4 acc[8][4];
  ACC256_ZERO(acc)
  gemm256_core(xb + (size_t)by * 256 * DIM, DIM,
               wqkv + (size_t)bx * 256 * DIM, DIM, DIM, lds, acc);
  ushort* dst = (bx < 4) ? Kp : (bx < 8) ? Qp : Vp;
  epi256_store_bf16(acc, lds, dst, by * 256, (bx & 3) * 256);
}

__global__ __launch_bounds__(512, 2) void scores_gemm256(
    const ushort* __restrict__ Qp, const ushort* __restrict__ Kp,
    ushort* __restrict__ eb)
{
  const int bid = blockIdx.x;          // 192
  const int b   = bid / 48;
  const int rem = bid % 48;
  const int i   = rem / 3;             // 0..15 (256-row block)
  const int jj  = rem % 3;             // 0..2  (256-col band block)
  const int jblk = i + jj - 1;
  if (jblk < 0 || jblk >= 16) return;
  __shared__ ushort lds[65536];
  f32x4 acc[8][4];
  ACC256_ZERO(acc)
  gemm256_core(Qp + ((size_t)b * S_LEN + i * 256) * DIM, DIM,
               Kp + ((size_t)b * S_LEN + jblk * 256) * DIM, DIM, DIM, lds, acc);
  EPI256_BEGIN(acc)
    int q = i * 256 + rloc;
    int k = jblk * 256 + cloc;
    float v = aval * SCALE;
    int d = q - k;
    if (d == 0 || d > AP || d < -AP) v = -INFINITY;
    eb[((size_t)(b * S_LEN + q)) * BANDC + jj * 256 + cloc] = f2h(v);
  EPI256_END()
}

__global__ __launch_bounds__(512, 2) void av_gemm256(
    const ushort* __restrict__ aband, const ushort* __restrict__ VT,
    ushort* __restrict__ cbuf)
{
  __shared__ ushort lds[65536];
  const int bid  = blockIdx.x;     // 256
  const int b    = bid >> 6;
  const int i    = (bid >> 2) & 15;
  const int dblk = bid & 3;
  const int klo = (i == 0) ? 256 : 0;
  const int khi = (i == 15) ? 512 : BANDC;
  f32x4 acc[8][4];
  ACC256_ZERO(acc)
  const ushort* Ablk = aband + ((size_t)(b * S_LEN + i * 256)) * BANDC + klo;
  const ushort* Bblk = VT + (size_t)b * DIM * S_LEN + (size_t)dblk * 256 * S_LEN
                     + ((i - 1) * 256 + klo);
  gemm256_core(Ablk, BANDC, Bblk, S_LEN, khi - klo, lds, acc);
  epi256_store_bf16(acc, lds, cbuf, b * S_LEN + i * 256, dblk * 256);
}

__global__ __launch_bounds__(512, 2) void wp_gemm256(
    const ushort* __restrict__ cbuf, const ushort* __restrict__ wpb,
    const float* __restrict__ x, float* __restrict__ y0)
{
  __shared__ ushort lds[65536];
  const int nid = (blockIdx.x & 7) * 32 + (blockIdx.x >> 3);   // 256 blocks
  const int by = nid >> 2;     // 0..63
  const int bx = nid & 3;      // 0..3
  f32x4 acc[8][4];
  ACC256_ZERO(acc)
  gemm256_core(cbuf + (size_t)by * 256 * DIM, DIM,
               wpb + (size_t)bx * 256 * DIM, DIM, DIM, lds, acc);
  EPI256_BEGIN(acc)
    int row = by * 256 + rloc;           // b*4096+s
    int col = bx * 256 + cloc;
    int b = row >> 12, s = row & 4095;
    y0[(size_t)row * DIM + col] = aval + x[((size_t)s * BATCH + b) * DIM + col];
  EPI256_END()
}

__global__ __launch_bounds__(512, 2) void ffn1_gemm256(
    const ushort* __restrict__ y1, const ushort* __restrict__ w1b,
    const float* __restrict__ b1, ushort* __restrict__ h0)
{
  __shared__ ushort lds[65536];
  const int nid = (blockIdx.x & 7) * 32 + (blockIdx.x >> 3);
  const int by = nid >> 2;
  const int bx = nid & 3;
  f32x4 acc[8][4];
  ACC256_ZERO(acc)
  gemm256_core(y1 + (size_t)by * 256 * DIM, DIM,
               w1b + (size_t)bx * 256 * DIM, DIM, DIM, lds, acc);
  epi256_store_relu_bf16(acc, lds, h0, by * 256, bx * 256, b1);
}

// ---------------- transpose V ----------------
__global__ __launch_bounds__(256) void transpose_v(const ushort* __restrict__ V, ushort* __restrict__ VT) {
  __shared__ ushort tile[64][66];
  const int s0 = blockIdx.x * 64, d0 = blockIdx.y * 64, b = blockIdx.z;
  const ushort* Vb = V + (size_t)b * S_LEN * DIM;
  ushort* VTb = VT + (size_t)b * DIM * S_LEN;
  #pragma unroll
  for (int it = 0; it < 16; it++) {
    int flat = it * 256 + threadIdx.x;
    int r = flat >> 6, c = flat & 63;
    tile[r][c] = Vb[(size_t)(s0 + r) * DIM + d0 + c];
  }
  __syncthreads();
  #pragma unroll
  for (int it = 0; it < 16; it++) {
    int flat = it * 256 + threadIdx.x;
    int r = flat >> 6, c = flat & 63;
    VTb[(size_t)(d0 + r) * S_LEN + s0 + c] = tile[c][r];
  }
}

// ---------------- softmax over the 768-band (wave-per-row) ----------------
__global__ __launch_bounds__(256) void softmax768(const ushort* __restrict__ eb,
                                                  ushort* __restrict__ aband)
{
  const int row  = blockIdx.x * 4 + (threadIdx.x >> 6);   // 0..16383
  const int lane = threadIdx.x & 63;
  const int s    = row & 4095;
  const int i256 = s >> 8;
  const ushort* e = eb + (size_t)row * BANDC;
  ushort* ab = aband + (size_t)row * BANDC;

  float vals[12];
  bool  ok[12];
  float mx = -INFINITY;
  #pragma unroll
  for (int j = 0; j < 6; ++j) {
    const int c0 = (j * 64 + lane) * 2;
    ushort2 u = *(const ushort2*)(e + c0);
    #pragma unroll
    for (int t = 0; t < 2; ++t) {
      const int c = c0 + t;
      const int jblk = i256 + (c >> 8) - 1;
      const int k = jblk * 256 + (c & 255);
      const int d = s - k;
      const bool valid = (jblk >= 0) && (jblk < 16) && (d != 0) && (d <= AP) && (d >= -AP);
      ok[j * 2 + t] = valid;
      float v = valid ? h2f(t ? u.y : u.x) : -INFINITY;
      vals[j * 2 + t] = v;
      mx = fmaxf(mx, v);
    }
  }
  mx = wave_max(mx);
  float ss = 0.0f;
  #pragma unroll
  for (int t = 0; t < 12; ++t) {
    float ev = ok[t] ? __expf(vals[t] - mx) : 0.0f;
    vals[t] = ev;
    ss += ev;
  }
  float inv = 1.0f / wave_sum(ss);
  #pragma unroll
  for (int j = 0; j < 6; ++j) {
    const int c0 = (j * 64 + lane) * 2;
    ushort2 o;
    o.x = f2bf(vals[j * 2 + 0] * inv);
    o.y = f2bf(vals[j * 2 + 1] * inv);
    *(ushort2*)(ab + c0) = o;
  }
}

// ---------------- norm / head (wave-per-row) ----------------
__global__ __launch_bounds__(256) void ln4(const float* __restrict__ y0, ushort* __restrict__ y1,
                                           const float* __restrict__ gamma, const float* __restrict__ beta)
{
  const int row  = blockIdx.x * 4 + (threadIdx.x >> 6);
  const int lane = threadIdx.x & 63;
  const float* r = y0 + (size_t)row * DIM;
  float4 v[4];
  float sum = 0.0f;
  #pragma unroll
  for (int j = 0; j < 4; ++j) {
    v[j] = *(const float4*)(r + j * 256 + lane * 4);
    sum += v[j].x + v[j].y + v[j].z + v[j].w;
  }
  const float mean = wave_sum(sum) * (1.0f / DIM);
  float q2 = 0.0f;
  #pragma unroll
  for (int j = 0; j < 4; ++j) {
    float a = v[j].x - mean, bq = v[j].y - mean, c = v[j].z - mean, d = v[j].w - mean;
    q2 += a * a + bq * bq + c * c + d * d;
  }
  const float rstd = rsqrtf(wave_sum(q2) * (1.0f / DIM) + 1e-6f);
  #pragma unroll
  for (int j = 0; j < 4; ++j) {
    const int d0 = j * 256 + lane * 4;
    float4 g = *(const float4*)(gamma + d0);
    float4 bb = *(const float4*)(beta + d0);
    ushort4 o;
    o.x = f2bf((v[j].x - mean) * rstd * g.x + bb.x);
    o.y = f2bf((v[j].y - mean) * rstd * g.y + bb.y);
    o.z = f2bf((v[j].z - mean) * rstd * g.z + bb.z);
    o.w = f2bf((v[j].w - mean) * rstd * g.w + bb.w);
    *(ushort4*)(y1 + (size_t)row * DIM + d0) = o;
  }
}

__global__ __launch_bounds__(256) void head4(const ushort* __restrict__ h0,
    const float* __restrict__ gamma, const float* __restrict__ beta,
    const float* __restrict__ W2, const float* __restrict__ b2,
    float* __restrict__ out)
{
  const int row  = blockIdx.x * 4 + (threadIdx.x >> 6);
  const int lane = threadIdx.x & 63;
  const int b = row >> 12, s = row & 4095;
  const ushort* r = h0 + (size_t)row * DIM;
  float v[16];
  float sum = 0.0f;
  #pragma unroll
  for (int j = 0; j < 4; ++j) {
    ushort4 u = *(const ushort4*)(r + j * 256 + lane * 4);
    v[j * 4 + 0] = bf2f(u.x); v[j * 4 + 1] = bf2f(u.y);
    v[j * 4 + 2] = bf2f(u.z); v[j * 4 + 3] = bf2f(u.w);
    sum += v[j * 4] + v[j * 4 + 1] + v[j * 4 + 2] + v[j * 4 + 3];
  }
  const float mean = wave_sum(sum) * (1.0f / DIM);
  float q2 = 0.0f;
  #pragma unroll
  for (int t = 0; t < 16; ++t) { float d = v[t] - mean; q2 += d * d; }
  const float rstd = rsqrtf(wave_sum(q2) * (1.0f / DIM) + 1e-6f);
  float part = 0.0f;
  #pragma unroll
  for (int j = 0; j < 4; ++j) {
    const int d0 = j * 256 + lane * 4;
    float4 g = *(const float4*)(gamma + d0);
    float4 bb = *(const float4*)(beta + d0);
    float4 w2 = *(const float4*)(W2 + d0);
    part += ((v[j * 4 + 0] - mean) * rstd * g.x + bb.x) * w2.x
          + ((v[j * 4 + 1] - mean) * rstd * g.y + bb.y) * w2.y
          + ((v[j * 4 + 2] - mean) * rstd * g.z + bb.z) * w2.z
          + ((v[j * 4 + 3] - mean) * rstd * g.w + bb.w) * w2.w;
  }
  const float logit = wave_sum(part) + b2[0];
  if (lane == 0) out[(size_t)s * BATCH + b] = 1.0f / (1.0f + expf(-logit));
}

// ---------------- launch ----------------
extern "C" void kernel_launch(void* const* d_in, const int* in_sizes, int n_in,
                              void* d_out, int out_size, void* d_ws, size_t ws_size,
                              hipStream_t stream) {
  const float* x     = (const float*)d_in[0];
  const float* Wk    = (const float*)d_in[1];
  const float* Wq    = (const float*)d_in[2];
  const float* Wv    = (const float*)d_in[3];
  const float* Wp    = (const float*)d_in[4];
  const float* W1    = (const float*)d_in[5];
  const float* b1    = (const float*)d_in[6];
  const float* W2    = (const float*)d_in[7];
  const float* b2    = (const float*)d_in[8];
  const float* gamma = (const float*)d_in[9];
  const float* beta  = (const float*)d_in[10];
  float* out = (float*)d_out;

  char* w = (char*)d_ws;
  ushort* xb   = (ushort*)(w + 0);            // 33,554,432 B
  ushort* wqkv = (ushort*)(w + 33554432);     //  6,291,456 B
  ushort* wpb  = (ushort*)(w + 39845888);     //  2,097,152 B
  ushort* w1b  = (ushort*)(w + 41943040);     //  2,097,152 B
  ushort* Qp   = (ushort*)(w + 44040192);     // 33,554,432 B
  ushort* Kp   = (ushort*)(w + 77594624);     // 33,554,432 B
  ushort* Vp   = (ushort*)(w + 111149056);    // 33,554,432 B
  ushort* VT   = (ushort*)(w + 144703488);    // 33,554,432 B
  float*  big  = (float*)(w + 178257920);     // 67,108,864 B
  // reuse (sequentially dead regions):
  ushort* eband = (ushort*)big;   // 16384*768*2 = 25.2 MB (fp16)
  ushort* aband = Qp;             // 25.2 MB bf16; Q dead after scores
  ushort* cbuf  = Kp;             // K dead after scores
  ushort* y1    = Vp;             // V dead after transpose
  ushort* h0    = xb;             // xb dead after qkv
  float* y0     = big;            // eband dead after softmax

  prep_x<<<16384, 256, 0, stream>>>(x, xb);
  f2bf_all<<<5120, 256, 0, stream>>>(Wk, Wq, Wv, Wp, W1, wqkv, wpb, w1b);

  qkv_gemm256<<<768, 512, 0, stream>>>(xb, wqkv, Kp, Qp, Vp);
  transpose_v<<<dim3(64, 16, 4), 256, 0, stream>>>(Vp, VT);
  scores_gemm256<<<192, 512, 0, stream>>>(Qp, Kp, eband);
  softmax768<<<4096, 256, 0, stream>>>(eband, aband);
  av_gemm256<<<256, 512, 0, stream>>>(aband, VT, cbuf);
  wp_gemm256<<<256, 512, 0, stream>>>(cbuf, wpb, x, y0);
  ln4<<<4096, 256, 0, stream>>>(y0, y1, gamma, beta);
  ffn1_gemm256<<<256, 512, 0, stream>>>(y1, w1b, b1, h0);
  head4<<<4096, 256, 0, stream>>>(h0, gamma, beta, W2, b2, out);
}

// Round 11
// 336.854 us; speedup vs baseline: 5.7140x; 1.0789x over previous
//
#include <hip/hip_runtime.h>
#include <stdint.h>
#include <math.h>

// ---------------- problem constants ----------------
#define S_LEN 4096
#define BATCH 4
#define DIM   1024
#define AP    256
#define BANDC 768           // 3*256 band columns for 256-row blocks
#define SCALE 0.03125f      // 1/sqrt(1024)

typedef __attribute__((ext_vector_type(4))) float f32x4;
typedef __attribute__((ext_vector_type(8))) short bf16x8;

// ---------------- helpers ----------------
__device__ __forceinline__ ushort f2bf(float f) {
  union { float f; uint32_t u; } v; v.f = f;
  uint32_t r = v.u + 0x7FFFu + ((v.u >> 16) & 1u);
  return (ushort)(r >> 16);
}
__device__ __forceinline__ float bf2f(ushort u) {
  union { uint32_t u; float f; } v; v.u = ((uint32_t)u) << 16; return v.f;
}
__device__ __forceinline__ ushort f2h(float f) {
  union { _Float16 h; ushort u; } v; v.h = (_Float16)f; return v.u;
}
__device__ __forceinline__ float h2f(ushort u) {
  union { ushort u; _Float16 h; } v; v.u = u; return (float)v.h;
}

__device__ __forceinline__ void gload16(const void* g, void* l) {
  __builtin_amdgcn_global_load_lds((const __attribute__((address_space(1))) void*)g,
                                   (__attribute__((address_space(3))) void*)l,
                                   16, 0, 0);
}

__device__ __forceinline__ float wave_sum(float v) {
  #pragma unroll
  for (int o = 32; o > 0; o >>= 1) v += __shfl_xor(v, o, 64);
  return v;
}
__device__ __forceinline__ float wave_max(float v) {
  #pragma unroll
  for (int o = 32; o > 0; o >>= 1) v = fmaxf(v, __shfl_xor(v, o, 64));
  return v;
}

// =====================================================================
// 256x256 GEMM core (best-measured variant, ~900 GF):
//  512 thr = 8 waves (2M x 4N), per-wave C = 128x64, acc[8][4] f32x4.
//  BK=64 as two [256][32] slabs/operand; 2 LDS buffers = 128 KiB.
//  Read-one-phase-ahead; vmcnt certify-before-barrier discipline.
//  Quarter-wave conflict-free swizzle (verified conflicts=0).
//  A,B row-major [256 x K] (B = B^T). Requires K % 64 == 0, K >= 128.
// =====================================================================
#define STAGE2(dstbase, g0, g1, kcol) \
  gload16((g0) + (kcol), lds + (dstbase) + stOff); \
  gload16((g1) + (kcol), lds + (dstbase) + 4096 + stOff);

#define MFMA16(arow, av, bv) \
  __builtin_amdgcn_s_setprio(1); \
  _Pragma("unroll") for (int m = 0; m < 4; ++m) \
  _Pragma("unroll") for (int n = 0; n < 4; ++n) \
    acc[(arow) + m][n] = __builtin_amdgcn_mfma_f32_16x16x32_bf16(av[m], bv[n], acc[(arow) + m][n], 0, 0, 0); \
  __builtin_amdgcn_s_setprio(0);

#define PHASE_CUT() \
  __builtin_amdgcn_sched_barrier(0); \
  asm volatile("s_barrier" ::: "memory");

__device__ __forceinline__ void gemm256_core(
    const ushort* __restrict__ Ablk, int lda,
    const ushort* __restrict__ Bblk, int ldb,
    int K, ushort* __restrict__ lds,
    f32x4 acc[8][4])
{
  const int tid  = threadIdx.x;
  const int lane = tid & 63;
  const int wave = tid >> 6;
  const int wr = wave >> 2;       // 0..1
  const int wn = wave & 3;        // 0..3

  const int srow = tid >> 2;                       // 0..127
  const int gseg = (tid & 3) ^ ((tid >> 3) & 3);   // slot ^ ((srow>>1)&3)
  const ushort* gA0 = Ablk + (size_t)srow * lda + gseg * 8;
  const ushort* gA1 = Ablk + (size_t)(srow + 128) * lda + gseg * 8;
  const ushort* gB0 = Bblk + (size_t)srow * ldb + gseg * 8;
  const ushort* gB1 = Bblk + (size_t)(srow + 128) * ldb + gseg * 8;
  const int stOff = wave * 512;                    // wave-uniform LDS base (ushorts)

  const int l15 = lane & 15;
  const int seg = (lane >> 4) ^ ((lane >> 1) & 3); // kseg ^ ((row>>1)&3)
  const int raBase = (wr * 128 + l15) * 32 + seg * 8;   // + m*512
  const int rbBase = (wn * 64  + l15) * 32 + seg * 8;   // + n*512

  const int NT = K >> 6;   // BK = 64

  // buffer layout (ushorts): A-slab0 @0, A-slab1 @8192, B-slab0 @16384, B-slab1 @24576
  STAGE2(0,     gA0, gA1, 0)      // u0
  STAGE2(16384, gB0, gB1, 0)      // u1
  STAGE2(8192,  gA0, gA1, 32)     // u2
  STAGE2(24576, gB0, gB1, 32)     // u3
  asm volatile("s_waitcnt vmcnt(4)" ::: "memory");   // u0,u1 landed (own loads)
  asm volatile("s_barrier" ::: "memory");            // ...all waves'

  bf16x8 aE[4], aO[4], bE[4], bO[4];
  #pragma unroll
  for (int m = 0; m < 4; ++m) aE[m] = *(const bf16x8*)(lds + raBase + m * 512);
  #pragma unroll
  for (int n = 0; n < 4; ++n) bE[n] = *(const bf16x8*)(lds + 16384 + rbBase + n * 512);

  for (int t = 0; t < NT; ++t) {
    const int rb = (t & 1) * 32768;
    const int sb = rb ^ 32768;
    const int k1 = (t + 1) << 6;
    const bool more = (t + 1 < NT);

    // ---- phase 0 ----
    #pragma unroll
    for (int m = 0; m < 4; ++m) aO[m] = *(const bf16x8*)(lds + rb + raBase + (m + 4) * 512);
    if (more) {
      STAGE2(sb,         gA0, gA1, k1)
      STAGE2(sb + 16384, gB0, gB1, k1)
    }
    MFMA16(0, aE, bE)
    if (more) asm volatile("s_waitcnt vmcnt(4)" ::: "memory");  // u2,u3(t) landed
    else      asm volatile("s_waitcnt vmcnt(0)" ::: "memory");
    PHASE_CUT()

    // ---- phase 1 ----
    #pragma unroll
    for (int m = 0; m < 4; ++m) aE[m] = *(const bf16x8*)(lds + rb + 8192 + raBase + m * 512);
    #pragma unroll
    for (int n = 0; n < 4; ++n) bO[n] = *(const bf16x8*)(lds + rb + 24576 + rbBase + n * 512);
    if (more) {
      STAGE2(sb + 8192,  gA0, gA1, k1 + 32)
      STAGE2(sb + 24576, gB0, gB1, k1 + 32)
    }
    MFMA16(4, aO, bE)
    PHASE_CUT()

    // ---- phase 2 ----
    #pragma unroll
    for (int m = 0; m < 4; ++m) aO[m] = *(const bf16x8*)(lds + rb + 8192 + raBase + (m + 4) * 512);
    MFMA16(0, aE, bO)
    if (more) asm volatile("s_waitcnt vmcnt(4)" ::: "memory");  // u0,u1(t+1) landed
    PHASE_CUT()

    // ---- phase 3 ----
    if (more) {
      #pragma unroll
      for (int m = 0; m < 4; ++m) aE[m] = *(const bf16x8*)(lds + sb + raBase + m * 512);
      #pragma unroll
      for (int n = 0; n < 4; ++n) bE[n] = *(const bf16x8*)(lds + sb + 16384 + rbBase + n * 512);
    }
    MFMA16(4, aO, bO)
    PHASE_CUT()
  }
}

#define ACC256_ZERO(acc) \
  _Pragma("unroll") for (int m_ = 0; m_ < 8; m_++) \
  _Pragma("unroll") for (int n_ = 0; n_ < 4; n_++) \
  _Pragma("unroll") for (int r_ = 0; r_ < 4; r_++) acc[m_][n_][r_] = 0.0f;

// coalesced bf16 epilogue: acc -> LDS (col-XOR, conflict-free) -> 16B/lane stores
__device__ __forceinline__ void epi256_store_bf16(
    f32x4 acc[8][4], ushort* __restrict__ lds,
    ushort* __restrict__ dst, int rowbase, int colb)
{
  __syncthreads();
  const int lane_ = threadIdx.x & 63;
  const int wave_ = threadIdx.x >> 6;
  const int wrb_ = (wave_ >> 2) * 128;
  const int wnb_ = (wave_ & 3) * 64;
  const int rb_ = (lane_ >> 4) << 2;
  const int cb_ = lane_ & 15;
  #pragma unroll
  for (int m = 0; m < 8; m++)
    #pragma unroll
    for (int n = 0; n < 4; n++)
      #pragma unroll
      for (int r = 0; r < 4; r++) {
        const int rl = wrb_ + m * 16 + rb_ + r;
        const int cl = wnb_ + n * 16 + cb_;
        const int cs = cl ^ (((rl >> 2) & 3) << 4);
        lds[rl * 256 + cs] = f2bf(acc[m][n][r]);
      }
  __syncthreads();
  #pragma unroll
  for (int it = 0; it < 16; ++it) {
    const int chunk = it * 512 + threadIdx.x;
    const int rl = chunk >> 5;
    const int c16 = chunk & 31;
    const int csw = (c16 * 16) ^ (((rl >> 2) & 3) << 5);
    bf16x8 v = *(const bf16x8*)((const char*)lds + rl * 512 + csw);
    *(bf16x8*)(dst + (size_t)(rowbase + rl) * DIM + colb + c16 * 8) = v;
  }
}

// transposed epilogue: scatter C^T into LDS, copy out rows of V^T.
// VTb = VT + b*DIM*S_LEN; rows become d = dbase+R, cols s = sbase + ...
__device__ __forceinline__ void epi256_store_vt(
    f32x4 acc[8][4], ushort* __restrict__ lds,
    ushort* __restrict__ VTb, int dbase, int sbase)
{
  __syncthreads();
  const int lane_ = threadIdx.x & 63;
  const int wave_ = threadIdx.x >> 6;
  const int wrb_ = (wave_ >> 2) * 128;
  const int wnb_ = (wave_ & 3) * 64;
  const int rb_ = (lane_ >> 4) << 2;
  const int cb_ = lane_ & 15;
  #pragma unroll
  for (int m = 0; m < 8; m++)
    #pragma unroll
    for (int n = 0; n < 4; n++)
      #pragma unroll
      for (int r = 0; r < 4; r++) {
        const int rl = wrb_ + m * 16 + rb_ + r;     // s-local
        const int cl = wnb_ + n * 16 + cb_;         // d-local
        const int inner = rl ^ (((cl >> 2) & 3) << 4);
        lds[cl * 256 + inner] = f2bf(acc[m][n][r]); // transposed (4-way scatter)
      }
  __syncthreads();
  #pragma unroll
  for (int it = 0; it < 16; ++it) {
    const int chunk = it * 512 + threadIdx.x;
    const int R = chunk >> 5;                       // d-local row
    const int c16 = chunk & 31;
    const int csw = (c16 * 16) ^ (((R >> 2) & 3) << 5);
    bf16x8 v = *(const bf16x8*)((const char*)lds + R * 512 + csw);
    *(bf16x8*)(VTb + (size_t)(dbase + R) * S_LEN + sbase + c16 * 8) = v;
  }
}

// residual + bf16 epilogue (wp -> y0 bf16)
__device__ __forceinline__ void epi256_store_res_bf16(
    f32x4 acc[8][4], ushort* __restrict__ lds,
    ushort* __restrict__ dst, int rowbase, int colb,
    const float* __restrict__ x)
{
  __syncthreads();
  const int lane_ = threadIdx.x & 63;
  const int wave_ = threadIdx.x >> 6;
  const int wrb_ = (wave_ >> 2) * 128;
  const int wnb_ = (wave_ & 3) * 64;
  const int rb_ = (lane_ >> 4) << 2;
  const int cb_ = lane_ & 15;
  #pragma unroll
  for (int m = 0; m < 8; m++)
    #pragma unroll
    for (int n = 0; n < 4; n++)
      #pragma unroll
      for (int r = 0; r < 4; r++) {
        const int rl = wrb_ + m * 16 + rb_ + r;
        const int cl = wnb_ + n * 16 + cb_;
        const int row = rowbase + rl;
        const int s = row & 4095, b = row >> 12;
        const float xv = x[((size_t)s * BATCH + b) * DIM + colb + cl];
        const int cs = cl ^ (((rl >> 2) & 3) << 4);
        lds[rl * 256 + cs] = f2bf(acc[m][n][r] + xv);
      }
  __syncthreads();
  #pragma unroll
  for (int it = 0; it < 16; ++it) {
    const int chunk = it * 512 + threadIdx.x;
    const int rl = chunk >> 5;
    const int c16 = chunk & 31;
    const int csw = (c16 * 16) ^ (((rl >> 2) & 3) << 5);
    bf16x8 v = *(const bf16x8*)((const char*)lds + rl * 512 + csw);
    *(bf16x8*)(dst + (size_t)(rowbase + rl) * DIM + colb + c16 * 8) = v;
  }
}

// bias + ReLU variant (ffn1 -> bf16 h0)
__device__ __forceinline__ void epi256_store_relu_bf16(
    f32x4 acc[8][4], ushort* __restrict__ lds,
    ushort* __restrict__ dst, int rowbase, int colb,
    const float* __restrict__ bias)
{
  __syncthreads();
  const int lane_ = threadIdx.x & 63;
  const int wave_ = threadIdx.x >> 6;
  const int wrb_ = (wave_ >> 2) * 128;
  const int wnb_ = (wave_ & 3) * 64;
  const int rb_ = (lane_ >> 4) << 2;
  const int cb_ = lane_ & 15;
  #pragma unroll
  for (int m = 0; m < 8; m++)
    #pragma unroll
    for (int n = 0; n < 4; n++) {
      const int cl = wnb_ + n * 16 + cb_;
      const float bv = bias[colb + cl];
      #pragma unroll
      for (int r = 0; r < 4; r++) {
        const int rl = wrb_ + m * 16 + rb_ + r;
        const int cs = cl ^ (((rl >> 2) & 3) << 4);
        lds[rl * 256 + cs] = f2bf(fmaxf(acc[m][n][r] + bv, 0.0f));
      }
    }
  __syncthreads();
  #pragma unroll
  for (int it = 0; it < 16; ++it) {
    const int chunk = it * 512 + threadIdx.x;
    const int rl = chunk >> 5;
    const int c16 = chunk & 31;
    const int csw = (c16 * 16) ^ (((rl >> 2) & 3) << 5);
    bf16x8 v = *(const bf16x8*)((const char*)lds + rl * 512 + csw);
    *(bf16x8*)(dst + (size_t)(rowbase + rl) * DIM + colb + c16 * 8) = v;
  }
}

#define EPI256_BEGIN(acc) { \
  const int lane_ = threadIdx.x & 63; \
  const int wave_ = threadIdx.x >> 6; \
  const int wrb_ = (wave_ >> 2) * 128; \
  const int wnb_ = (wave_ & 3) * 64; \
  const int rb_ = (lane_ >> 4) << 2; \
  const int cb_ = lane_ & 15; \
  _Pragma("unroll") for (int m_ = 0; m_ < 8; m_++) \
  _Pragma("unroll") for (int n_ = 0; n_ < 4; n_++) \
  _Pragma("unroll") for (int r_ = 0; r_ < 4; r_++) { \
    const int rloc = wrb_ + m_ * 16 + rb_ + r_; \
    const int cloc = wnb_ + n_ * 16 + cb_; \
    const float aval = acc[m_][n_][r_];
#define EPI256_END() } }

// ---------------- merged prep: x transpose-cast + all weight casts ----------------
__global__ __launch_bounds__(256) void prep_all(
    const float* __restrict__ x,
    const float* __restrict__ Wk, const float* __restrict__ Wq, const float* __restrict__ Wv,
    const float* __restrict__ Wp, const float* __restrict__ W1,
    ushort* __restrict__ xb, ushort* __restrict__ wqkv,
    ushort* __restrict__ wpb, ushort* __restrict__ w1b)
{
  const int g = blockIdx.x;
  if (g < 16384) {
    size_t idx = ((size_t)g * 256 + threadIdx.x) * 4;   // dest flat (b,s,d)
    int d = (int)(idx & 1023);
    int s = (int)((idx >> 10) & 4095);
    int b = (int)(idx >> 22);
    float4 v = *(const float4*)(x + ((size_t)s * BATCH + b) * DIM + d);
    ushort4 o;
    o.x = f2bf(v.x); o.y = f2bf(v.y); o.z = f2bf(v.z); o.w = f2bf(v.w);
    *(ushort4*)(xb + idx) = o;
  } else {
    const int gg = g - 16384;
    const int which = gg >> 10;
    const int idx = ((gg & 1023) * 256 + threadIdx.x) * 4;
    const float* src = (which == 0) ? Wk : (which == 1) ? Wq : (which == 2) ? Wv
                     : (which == 3) ? Wp : W1;
    ushort* dst = (which == 0) ? wqkv : (which == 1) ? wqkv + 1048576
                : (which == 2) ? wqkv + 2097152 : (which == 3) ? wpb : w1b;
    float4 v = *(const float4*)(src + idx);
    ushort4 o;
    o.x = f2bf(v.x); o.y = f2bf(v.y); o.z = f2bf(v.z); o.w = f2bf(v.w);
    *(ushort4*)(dst + idx) = o;
  }
}

// ---------------- GEMMs on the 256 core ----------------
__global__ __launch_bounds__(512, 2) void qkv_gemm256(
    const ushort* __restrict__ xb, const ushort* __restrict__ wqkv,
    ushort* __restrict__ Kp, ushort* __restrict__ Qp, ushort* __restrict__ VT)
{
  __shared__ ushort lds[65536];
  const int nid = (blockIdx.x & 7) * 96 + (blockIdx.x >> 3);  // XCD-chunked
  const int by = nid / 12;     // 0..63 (b*16 + s-block)
  const int bx = nid % 12;     // 0..11
  f32x4 acc[8][4];
  ACC256_ZERO(acc)
  gemm256_core(xb + (size_t)by * 256 * DIM, DIM,
               wqkv + (size_t)bx * 256 * DIM, DIM, DIM, lds, acc);
  if (bx < 8) {
    ushort* dst = (bx < 4) ? Kp : Qp;
    epi256_store_bf16(acc, lds, dst, by * 256, (bx & 3) * 256);
  } else {
    // V block: write V^T directly (transposed scatter)
    const int b = by >> 4, s0 = (by & 15) * 256;
    epi256_store_vt(acc, lds, VT + (size_t)b * DIM * S_LEN, (bx & 3) * 256, s0);
  }
}

__global__ __launch_bounds__(512, 2) void scores_gemm256(
    const ushort* __restrict__ Qp, const ushort* __restrict__ Kp,
    ushort* __restrict__ eb)
{
  const int bid = blockIdx.x;          // 192
  const int b   = bid / 48;
  const int rem = bid % 48;
  const int i   = rem / 3;             // 0..15 (256-row block)
  const int jj  = rem % 3;             // 0..2  (256-col band block)
  const int jblk = i + jj - 1;
  if (jblk < 0 || jblk >= 16) return;
  __shared__ ushort lds[65536];
  f32x4 acc[8][4];
  ACC256_ZERO(acc)
  gemm256_core(Qp + ((size_t)b * S_LEN + i * 256) * DIM, DIM,
               Kp + ((size_t)b * S_LEN + jblk * 256) * DIM, DIM, DIM, lds, acc);
  EPI256_BEGIN(acc)
    int q = i * 256 + rloc;
    int k = jblk * 256 + cloc;
    float v = aval * SCALE;
    int d = q - k;
    if (d == 0 || d > AP || d < -AP) v = -INFINITY;
    eb[((size_t)(b * S_LEN + q)) * BANDC + jj * 256 + cloc] = f2h(v);
  EPI256_END()
}

__global__ __launch_bounds__(512, 2) void av_gemm256(
    const ushort* __restrict__ aband, const ushort* __restrict__ VT,
    ushort* __restrict__ cbuf)
{
  __shared__ ushort lds[65536];
  const int bid  = blockIdx.x;     // 256
  const int b    = bid >> 6;
  const int i    = (bid >> 2) & 15;
  const int dblk = bid & 3;
  const int klo = (i == 0) ? 256 : 0;
  const int khi = (i == 15) ? 512 : BANDC;
  f32x4 acc[8][4];
  ACC256_ZERO(acc)
  const ushort* Ablk = aband + ((size_t)(b * S_LEN + i * 256)) * BANDC + klo;
  const ushort* Bblk = VT + (size_t)b * DIM * S_LEN + (size_t)dblk * 256 * S_LEN
                     + ((i - 1) * 256 + klo);
  gemm256_core(Ablk, BANDC, Bblk, S_LEN, khi - klo, lds, acc);
  epi256_store_bf16(acc, lds, cbuf, b * S_LEN + i * 256, dblk * 256);
}

__global__ __launch_bounds__(512, 2) void wp_gemm256(
    const ushort* __restrict__ cbuf, const ushort* __restrict__ wpb,
    const float* __restrict__ x, ushort* __restrict__ y0)
{
  __shared__ ushort lds[65536];
  const int nid = (blockIdx.x & 7) * 32 + (blockIdx.x >> 3);   // 256 blocks
  const int by = nid >> 2;     // 0..63
  const int bx = nid & 3;      // 0..3
  f32x4 acc[8][4];
  ACC256_ZERO(acc)
  gemm256_core(cbuf + (size_t)by * 256 * DIM, DIM,
               wpb + (size_t)bx * 256 * DIM, DIM, DIM, lds, acc);
  epi256_store_res_bf16(acc, lds, y0, by * 256, bx * 256, x);
}

__global__ __launch_bounds__(512, 2) void ffn1_gemm256(
    const ushort* __restrict__ y1, const ushort* __restrict__ w1b,
    const float* __restrict__ b1, ushort* __restrict__ h0)
{
  __shared__ ushort lds[65536];
  const int nid = (blockIdx.x & 7) * 32 + (blockIdx.x >> 3);
  const int by = nid >> 2;
  const int bx = nid & 3;
  f32x4 acc[8][4];
  ACC256_ZERO(acc)
  gemm256_core(y1 + (size_t)by * 256 * DIM, DIM,
               w1b + (size_t)bx * 256 * DIM, DIM, DIM, lds, acc);
  epi256_store_relu_bf16(acc, lds, h0, by * 256, bx * 256, b1);
}

// ---------------- softmax over the 768-band (wave-per-row) ----------------
__global__ __launch_bounds__(256) void softmax768(const ushort* __restrict__ eb,
                                                  ushort* __restrict__ aband)
{
  const int row  = blockIdx.x * 4 + (threadIdx.x >> 6);   // 0..16383
  const int lane = threadIdx.x & 63;
  const int s    = row & 4095;
  const int i256 = s >> 8;
  const ushort* e = eb + (size_t)row * BANDC;
  ushort* ab = aband + (size_t)row * BANDC;

  float vals[12];
  bool  ok[12];
  float mx = -INFINITY;
  #pragma unroll
  for (int j = 0; j < 6; ++j) {
    const int c0 = (j * 64 + lane) * 2;
    ushort2 u = *(const ushort2*)(e + c0);
    #pragma unroll
    for (int t = 0; t < 2; ++t) {
      const int c = c0 + t;
      const int jblk = i256 + (c >> 8) - 1;
      const int k = jblk * 256 + (c & 255);
      const int d = s - k;
      const bool valid = (jblk >= 0) && (jblk < 16) && (d != 0) && (d <= AP) && (d >= -AP);
      ok[j * 2 + t] = valid;
      float v = valid ? h2f(t ? u.y : u.x) : -INFINITY;
      vals[j * 2 + t] = v;
      mx = fmaxf(mx, v);
    }
  }
  mx = wave_max(mx);
  float ss = 0.0f;
  #pragma unroll
  for (int t = 0; t < 12; ++t) {
    float ev = ok[t] ? __expf(vals[t] - mx) : 0.0f;
    vals[t] = ev;
    ss += ev;
  }
  float inv = 1.0f / wave_sum(ss);
  #pragma unroll
  for (int j = 0; j < 6; ++j) {
    const int c0 = (j * 64 + lane) * 2;
    ushort2 o;
    o.x = f2bf(vals[j * 2 + 0] * inv);
    o.y = f2bf(vals[j * 2 + 1] * inv);
    *(ushort2*)(ab + c0) = o;
  }
}

// ---------------- norm / head (wave-per-row) ----------------
__global__ __launch_bounds__(256) void ln4(const ushort* __restrict__ y0, ushort* __restrict__ y1,
                                           const float* __restrict__ gamma, const float* __restrict__ beta)
{
  const int row  = blockIdx.x * 4 + (threadIdx.x >> 6);
  const int lane = threadIdx.x & 63;
  const ushort* r = y0 + (size_t)row * DIM;
  float v[16];
  float sum = 0.0f;
  #pragma unroll
  for (int j = 0; j < 2; ++j) {
    bf16x8 u = *(const bf16x8*)(r + j * 512 + lane * 8);
    #pragma unroll
    for (int t = 0; t < 8; ++t) { float f = bf2f((ushort)u[t]); v[j * 8 + t] = f; sum += f; }
  }
  const float mean = wave_sum(sum) * (1.0f / DIM);
  float q2 = 0.0f;
  #pragma unroll
  for (int t = 0; t < 16; ++t) { float d = v[t] - mean; q2 += d * d; }
  const float rstd = rsqrtf(wave_sum(q2) * (1.0f / DIM) + 1e-6f);
  #pragma unroll
  for (int j = 0; j < 2; ++j) {
    const int d0 = j * 512 + lane * 8;
    bf16x8 o;
    #pragma unroll
    for (int t = 0; t < 8; t += 4) {
      float4 g = *(const float4*)(gamma + d0 + t);
      float4 bb = *(const float4*)(beta + d0 + t);
      o[t + 0] = (short)f2bf((v[j * 8 + t + 0] - mean) * rstd * g.x + bb.x);
      o[t + 1] = (short)f2bf((v[j * 8 + t + 1] - mean) * rstd * g.y + bb.y);
      o[t + 2] = (short)f2bf((v[j * 8 + t + 2] - mean) * rstd * g.z + bb.z);
      o[t + 3] = (short)f2bf((v[j * 8 + t + 3] - mean) * rstd * g.w + bb.w);
    }
    *(bf16x8*)(y1 + (size_t)row * DIM + d0) = o;
  }
}

__global__ __launch_bounds__(256) void head4(const ushort* __restrict__ h0,
    const float* __restrict__ gamma, const float* __restrict__ beta,
    const float* __restrict__ W2, const float* __restrict__ b2,
    float* __restrict__ out)
{
  const int row  = blockIdx.x * 4 + (threadIdx.x >> 6);
  const int lane = threadIdx.x & 63;
  const int b = row >> 12, s = row & 4095;
  const ushort* r = h0 + (size_t)row * DIM;
  float v[16];
  float sum = 0.0f;
  #pragma unroll
  for (int j = 0; j < 2; ++j) {
    bf16x8 u = *(const bf16x8*)(r + j * 512 + lane * 8);
    #pragma unroll
    for (int t = 0; t < 8; ++t) { float f = bf2f((ushort)u[t]); v[j * 8 + t] = f; sum += f; }
  }
  const float mean = wave_sum(sum) * (1.0f / DIM);
  float q2 = 0.0f;
  #pragma unroll
  for (int t = 0; t < 16; ++t) { float d = v[t] - mean; q2 += d * d; }
  const float rstd = rsqrtf(wave_sum(q2) * (1.0f / DIM) + 1e-6f);
  float part = 0.0f;
  #pragma unroll
  for (int j = 0; j < 2; ++j) {
    const int d0 = j * 512 + lane * 8;
    #pragma unroll
    for (int t = 0; t < 8; t += 4) {
      float4 g = *(const float4*)(gamma + d0 + t);
      float4 bb = *(const float4*)(beta + d0 + t);
      float4 w2 = *(const float4*)(W2 + d0 + t);
      part += ((v[j * 8 + t + 0] - mean) * rstd * g.x + bb.x) * w2.x
            + ((v[j * 8 + t + 1] - mean) * rstd * g.y + bb.y) * w2.y
            + ((v[j * 8 + t + 2] - mean) * rstd * g.z + bb.z) * w2.z
            + ((v[j * 8 + t + 3] - mean) * rstd * g.w + bb.w) * w2.w;
    }
  }
  const float logit = wave_sum(part) + b2[0];
  if (lane == 0) out[(size_t)s * BATCH + b] = 1.0f / (1.0f + expf(-logit));
}

// ---------------- launch ----------------
extern "C" void kernel_launch(void* const* d_in, const int* in_sizes, int n_in,
                              void* d_out, int out_size, void* d_ws, size_t ws_size,
                              hipStream_t stream) {
  const float* x     = (const float*)d_in[0];
  const float* Wk    = (const float*)d_in[1];
  const float* Wq    = (const float*)d_in[2];
  const float* Wv    = (const float*)d_in[3];
  const float* Wp    = (const float*)d_in[4];
  const float* W1    = (const float*)d_in[5];
  const float* b1    = (const float*)d_in[6];
  const float* W2    = (const float*)d_in[7];
  const float* b2    = (const float*)d_in[8];
  const float* gamma = (const float*)d_in[9];
  const float* beta  = (const float*)d_in[10];
  float* out = (float*)d_out;

  char* w = (char*)d_ws;
  ushort* xb   = (ushort*)(w + 0);            // 33,554,432 B -> h0
  ushort* wqkv = (ushort*)(w + 33554432);     //  6,291,456 B
  ushort* wpb  = (ushort*)(w + 39845888);     //  2,097,152 B
  ushort* w1b  = (ushort*)(w + 41943040);     //  2,097,152 B
  ushort* Qp   = (ushort*)(w + 44040192);     // 33,554,432 B -> aband
  ushort* Kp   = (ushort*)(w + 77594624);     // 33,554,432 B -> cbuf
  ushort* y1   = (ushort*)(w + 111149056);    // 33,554,432 B (was Vp; V^T written directly)
  ushort* VT   = (ushort*)(w + 144703488);    // 33,554,432 B
  char*   big  = (w + 178257920);             // 67,108,864 B
  // reuse (sequentially dead regions):
  ushort* eband = (ushort*)big;   // 16384*768*2 = 25.2 MB (fp16)
  ushort* aband = Qp;             // Q dead after scores
  ushort* cbuf  = Kp;             // K dead after scores
  ushort* h0    = xb;             // xb dead after qkv
  ushort* y0    = (ushort*)big;   // bf16; eband dead after softmax

  prep_all<<<21504, 256, 0, stream>>>(x, Wk, Wq, Wv, Wp, W1, xb, wqkv, wpb, w1b);

  qkv_gemm256<<<768, 512, 0, stream>>>(xb, wqkv, Kp, Qp, VT);
  scores_gemm256<<<192, 512, 0, stream>>>(Qp, Kp, eband);
  softmax768<<<4096, 256, 0, stream>>>(eband, aband);
  av_gemm256<<<256, 512, 0, stream>>>(aband, VT, cbuf);
  wp_gemm256<<<256, 512, 0, stream>>>(cbuf, wpb, x, y0);
  ln4<<<4096, 256, 0, stream>>>(y0, y1, gamma, beta);
  ffn1_gemm256<<<256, 512, 0, stream>>>(y1, w1b, b1, h0);
  head4<<<4096, 256, 0, stream>>>(h0, gamma, beta, W2, b2, out);
}

// Round 14
// 334.739 us; speedup vs baseline: 5.7502x; 1.0063x over previous
//
#include <hip/hip_runtime.h>
#include <stdint.h>
#include <math.h>

// ---------------- problem constants ----------------
#define S_LEN 4096
#define BATCH 4
#define DIM   1024
#define AP    256
#define BANDC 768           // 3*256 band columns for 256-row blocks
#define SCALE 0.03125f      // 1/sqrt(1024)

typedef __attribute__((ext_vector_type(4))) float f32x4;
typedef __attribute__((ext_vector_type(8))) short bf16x8;

// ---------------- helpers ----------------
__device__ __forceinline__ ushort f2bf(float f) {
  union { float f; uint32_t u; } v; v.f = f;
  uint32_t r = v.u + 0x7FFFu + ((v.u >> 16) & 1u);
  return (ushort)(r >> 16);
}
__device__ __forceinline__ float bf2f(ushort u) {
  union { uint32_t u; float f; } v; v.u = ((uint32_t)u) << 16; return v.f;
}
__device__ __forceinline__ ushort f2h(float f) {
  union { _Float16 h; ushort u; } v; v.h = (_Float16)f; return v.u;
}
__device__ __forceinline__ float h2f(ushort u) {
  union { ushort u; _Float16 h; } v; v.u = u; return (float)v.h;
}

__device__ __forceinline__ void gload16(const void* g, void* l) {
  __builtin_amdgcn_global_load_lds((const __attribute__((address_space(1))) void*)g,
                                   (__attribute__((address_space(3))) void*)l,
                                   16, 0, 0);
}

__device__ __forceinline__ float wave_sum(float v) {
  #pragma unroll
  for (int o = 32; o > 0; o >>= 1) v += __shfl_xor(v, o, 64);
  return v;
}
__device__ __forceinline__ float wave_max(float v) {
  #pragma unroll
  for (int o = 32; o > 0; o >>= 1) v = fmaxf(v, __shfl_xor(v, o, 64));
  return v;
}

// =====================================================================
// 256x256 GEMM core (best-measured variant, ~900 GF — session ceiling
// for plain-HIP barrier-phased schedules; six variants all ~equal):
//  512 thr = 8 waves (2M x 4N), per-wave C = 128x64, acc[8][4] f32x4.
//  BK=64 as two [256][32] slabs/operand; 2 LDS buffers = 128 KiB.
//  Read-one-phase-ahead; vmcnt certify-before-barrier discipline.
//  Quarter-wave conflict-free swizzle (verified conflicts=0).
//  A,B row-major [256 x K] (B = B^T). Requires K % 64 == 0, K >= 128.
// =====================================================================
#define STAGE2(dstbase, g0, g1, kcol) \
  gload16((g0) + (kcol), lds + (dstbase) + stOff); \
  gload16((g1) + (kcol), lds + (dstbase) + 4096 + stOff);

#define MFMA16(arow, av, bv) \
  __builtin_amdgcn_s_setprio(1); \
  _Pragma("unroll") for (int m = 0; m < 4; ++m) \
  _Pragma("unroll") for (int n = 0; n < 4; ++n) \
    acc[(arow) + m][n] = __builtin_amdgcn_mfma_f32_16x16x32_bf16(av[m], bv[n], acc[(arow) + m][n], 0, 0, 0); \
  __builtin_amdgcn_s_setprio(0);

#define PHASE_CUT() \
  __builtin_amdgcn_sched_barrier(0); \
  asm volatile("s_barrier" ::: "memory");

__device__ __forceinline__ void gemm256_core(
    const ushort* __restrict__ Ablk, int lda,
    const ushort* __restrict__ Bblk, int ldb,
    int K, ushort* __restrict__ lds,
    f32x4 acc[8][4])
{
  const int tid  = threadIdx.x;
  const int lane = tid & 63;
  const int wave = tid >> 6;
  const int wr = wave >> 2;       // 0..1
  const int wn = wave & 3;        // 0..3

  const int srow = tid >> 2;                       // 0..127
  const int gseg = (tid & 3) ^ ((tid >> 3) & 3);   // slot ^ ((srow>>1)&3)
  const ushort* gA0 = Ablk + (size_t)srow * lda + gseg * 8;
  const ushort* gA1 = Ablk + (size_t)(srow + 128) * lda + gseg * 8;
  const ushort* gB0 = Bblk + (size_t)srow * ldb + gseg * 8;
  const ushort* gB1 = Bblk + (size_t)(srow + 128) * ldb + gseg * 8;
  const int stOff = wave * 512;                    // wave-uniform LDS base (ushorts)

  const int l15 = lane & 15;
  const int seg = (lane >> 4) ^ ((lane >> 1) & 3); // kseg ^ ((row>>1)&3)
  const int raBase = (wr * 128 + l15) * 32 + seg * 8;   // + m*512
  const int rbBase = (wn * 64  + l15) * 32 + seg * 8;   // + n*512

  const int NT = K >> 6;   // BK = 64

  // buffer layout (ushorts): A-slab0 @0, A-slab1 @8192, B-slab0 @16384, B-slab1 @24576
  STAGE2(0,     gA0, gA1, 0)      // u0
  STAGE2(16384, gB0, gB1, 0)      // u1
  STAGE2(8192,  gA0, gA1, 32)     // u2
  STAGE2(24576, gB0, gB1, 32)     // u3
  asm volatile("s_waitcnt vmcnt(4)" ::: "memory");   // u0,u1 landed (own loads)
  asm volatile("s_barrier" ::: "memory");            // ...all waves'

  bf16x8 aE[4], aO[4], bE[4], bO[4];
  #pragma unroll
  for (int m = 0; m < 4; ++m) aE[m] = *(const bf16x8*)(lds + raBase + m * 512);
  #pragma unroll
  for (int n = 0; n < 4; ++n) bE[n] = *(const bf16x8*)(lds + 16384 + rbBase + n * 512);

  for (int t = 0; t < NT; ++t) {
    const int rb = (t & 1) * 32768;
    const int sb = rb ^ 32768;
    const int k1 = (t + 1) << 6;
    const bool more = (t + 1 < NT);

    // ---- phase 0 ----
    #pragma unroll
    for (int m = 0; m < 4; ++m) aO[m] = *(const bf16x8*)(lds + rb + raBase + (m + 4) * 512);
    if (more) {
      STAGE2(sb,         gA0, gA1, k1)
      STAGE2(sb + 16384, gB0, gB1, k1)
    }
    MFMA16(0, aE, bE)
    if (more) asm volatile("s_waitcnt vmcnt(4)" ::: "memory");  // u2,u3(t) landed
    else      asm volatile("s_waitcnt vmcnt(0)" ::: "memory");
    PHASE_CUT()

    // ---- phase 1 ----
    #pragma unroll
    for (int m = 0; m < 4; ++m) aE[m] = *(const bf16x8*)(lds + rb + 8192 + raBase + m * 512);
    #pragma unroll
    for (int n = 0; n < 4; ++n) bO[n] = *(const bf16x8*)(lds + rb + 24576 + rbBase + n * 512);
    if (more) {
      STAGE2(sb + 8192,  gA0, gA1, k1 + 32)
      STAGE2(sb + 24576, gB0, gB1, k1 + 32)
    }
    MFMA16(4, aO, bE)
    PHASE_CUT()

    // ---- phase 2 ----
    #pragma unroll
    for (int m = 0; m < 4; ++m) aO[m] = *(const bf16x8*)(lds + rb + 8192 + raBase + (m + 4) * 512);
    MFMA16(0, aE, bO)
    if (more) asm volatile("s_waitcnt vmcnt(4)" ::: "memory");  // u0,u1(t+1) landed
    PHASE_CUT()

    // ---- phase 3 ----
    if (more) {
      #pragma unroll
      for (int m = 0; m < 4; ++m) aE[m] = *(const bf16x8*)(lds + sb + raBase + m * 512);
      #pragma unroll
      for (int n = 0; n < 4; ++n) bE[n] = *(const bf16x8*)(lds + sb + 16384 + rbBase + n * 512);
    }
    MFMA16(4, aO, bO)
    PHASE_CUT()
  }
}

#define ACC256_ZERO(acc) \
  _Pragma("unroll") for (int m_ = 0; m_ < 8; m_++) \
  _Pragma("unroll") for (int n_ = 0; n_ < 4; n_++) \
  _Pragma("unroll") for (int r_ = 0; r_ < 4; r_++) acc[m_][n_][r_] = 0.0f;

// coalesced bf16 epilogue: acc -> LDS (col-XOR, conflict-free) -> 16B/lane stores
__device__ __forceinline__ void epi256_store_bf16(
    f32x4 acc[8][4], ushort* __restrict__ lds,
    ushort* __restrict__ dst, int rowbase, int colb)
{
  __syncthreads();
  const int lane_ = threadIdx.x & 63;
  const int wave_ = threadIdx.x >> 6;
  const int wrb_ = (wave_ >> 2) * 128;
  const int wnb_ = (wave_ & 3) * 64;
  const int rb_ = (lane_ >> 4) << 2;
  const int cb_ = lane_ & 15;
  #pragma unroll
  for (int m = 0; m < 8; m++)
    #pragma unroll
    for (int n = 0; n < 4; n++)
      #pragma unroll
      for (int r = 0; r < 4; r++) {
        const int rl = wrb_ + m * 16 + rb_ + r;
        const int cl = wnb_ + n * 16 + cb_;
        const int cs = cl ^ (((rl >> 2) & 3) << 4);
        lds[rl * 256 + cs] = f2bf(acc[m][n][r]);
      }
  __syncthreads();
  #pragma unroll
  for (int it = 0; it < 16; ++it) {
    const int chunk = it * 512 + threadIdx.x;
    const int rl = chunk >> 5;
    const int c16 = chunk & 31;
    const int csw = (c16 * 16) ^ (((rl >> 2) & 3) << 5);
    bf16x8 v = *(const bf16x8*)((const char*)lds + rl * 512 + csw);
    *(bf16x8*)(dst + (size_t)(rowbase + rl) * DIM + colb + c16 * 8) = v;
  }
}

// transposed epilogue: scatter C^T into LDS, copy out rows of V^T.
__device__ __forceinline__ void epi256_store_vt(
    f32x4 acc[8][4], ushort* __restrict__ lds,
    ushort* __restrict__ VTb, int dbase, int sbase)
{
  __syncthreads();
  const int lane_ = threadIdx.x & 63;
  const int wave_ = threadIdx.x >> 6;
  const int wrb_ = (wave_ >> 2) * 128;
  const int wnb_ = (wave_ & 3) * 64;
  const int rb_ = (lane_ >> 4) << 2;
  const int cb_ = lane_ & 15;
  #pragma unroll
  for (int m = 0; m < 8; m++)
    #pragma unroll
    for (int n = 0; n < 4; n++)
      #pragma unroll
      for (int r = 0; r < 4; r++) {
        const int rl = wrb_ + m * 16 + rb_ + r;     // s-local
        const int cl = wnb_ + n * 16 + cb_;         // d-local
        const int inner = rl ^ (((cl >> 2) & 3) << 4);
        lds[cl * 256 + inner] = f2bf(acc[m][n][r]); // transposed (4-way scatter)
      }
  __syncthreads();
  #pragma unroll
  for (int it = 0; it < 16; ++it) {
    const int chunk = it * 512 + threadIdx.x;
    const int R = chunk >> 5;                       // d-local row
    const int c16 = chunk & 31;
    const int csw = (c16 * 16) ^ (((R >> 2) & 3) << 5);
    bf16x8 v = *(const bf16x8*)((const char*)lds + R * 512 + csw);
    *(bf16x8*)(VTb + (size_t)(dbase + R) * S_LEN + sbase + c16 * 8) = v;
  }
}

// residual + bf16 epilogue (wp -> y0 bf16)
__device__ __forceinline__ void epi256_store_res_bf16(
    f32x4 acc[8][4], ushort* __restrict__ lds,
    ushort* __restrict__ dst, int rowbase, int colb,
    const float* __restrict__ x)
{
  __syncthreads();
  const int lane_ = threadIdx.x & 63;
  const int wave_ = threadIdx.x >> 6;
  const int wrb_ = (wave_ >> 2) * 128;
  const int wnb_ = (wave_ & 3) * 64;
  const int rb_ = (lane_ >> 4) << 2;
  const int cb_ = lane_ & 15;
  #pragma unroll
  for (int m = 0; m < 8; m++)
    #pragma unroll
    for (int n = 0; n < 4; n++)
      #pragma unroll
      for (int r = 0; r < 4; r++) {
        const int rl = wrb_ + m * 16 + rb_ + r;
        const int cl = wnb_ + n * 16 + cb_;
        const int row = rowbase + rl;
        const int s = row & 4095, b = row >> 12;
        const float xv = x[((size_t)s * BATCH + b) * DIM + colb + cl];
        const int cs = cl ^ (((rl >> 2) & 3) << 4);
        lds[rl * 256 + cs] = f2bf(acc[m][n][r] + xv);
      }
  __syncthreads();
  #pragma unroll
  for (int it = 0; it < 16; ++it) {
    const int chunk = it * 512 + threadIdx.x;
    const int rl = chunk >> 5;
    const int c16 = chunk & 31;
    const int csw = (c16 * 16) ^ (((rl >> 2) & 3) << 5);
    bf16x8 v = *(const bf16x8*)((const char*)lds + rl * 512 + csw);
    *(bf16x8*)(dst + (size_t)(rowbase + rl) * DIM + colb + c16 * 8) = v;
  }
}

// bias + ReLU variant (ffn1 -> bf16 h0)
__device__ __forceinline__ void epi256_store_relu_bf16(
    f32x4 acc[8][4], ushort* __restrict__ lds,
    ushort* __restrict__ dst, int rowbase, int colb,
    const float* __restrict__ bias)
{
  __syncthreads();
  const int lane_ = threadIdx.x & 63;
  const int wave_ = threadIdx.x >> 6;
  const int wrb_ = (wave_ >> 2) * 128;
  const int wnb_ = (wave_ & 3) * 64;
  const int rb_ = (lane_ >> 4) << 2;
  const int cb_ = lane_ & 15;
  #pragma unroll
  for (int m = 0; m < 8; m++)
    #pragma unroll
    for (int n = 0; n < 4; n++) {
      const int cl = wnb_ + n * 16 + cb_;
      const float bv = bias[colb + cl];
      #pragma unroll
      for (int r = 0; r < 4; r++) {
        const int rl = wrb_ + m * 16 + rb_ + r;
        const int cs = cl ^ (((rl >> 2) & 3) << 4);
        lds[rl * 256 + cs] = f2bf(fmaxf(acc[m][n][r] + bv, 0.0f));
      }
    }
  __syncthreads();
  #pragma unroll
  for (int it = 0; it < 16; ++it) {
    const int chunk = it * 512 + threadIdx.x;
    const int rl = chunk >> 5;
    const int c16 = chunk & 31;
    const int csw = (c16 * 16) ^ (((rl >> 2) & 3) << 5);
    bf16x8 v = *(const bf16x8*)((const char*)lds + rl * 512 + csw);
    *(bf16x8*)(dst + (size_t)(rowbase + rl) * DIM + colb + c16 * 8) = v;
  }
}

#define EPI256_BEGIN(acc) { \
  const int lane_ = threadIdx.x & 63; \
  const int wave_ = threadIdx.x >> 6; \
  const int wrb_ = (wave_ >> 2) * 128; \
  const int wnb_ = (wave_ & 3) * 64; \
  const int rb_ = (lane_ >> 4) << 2; \
  const int cb_ = lane_ & 15; \
  _Pragma("unroll") for (int m_ = 0; m_ < 8; m_++) \
  _Pragma("unroll") for (int n_ = 0; n_ < 4; n_++) \
  _Pragma("unroll") for (int r_ = 0; r_ < 4; r_++) { \
    const int rloc = wrb_ + m_ * 16 + rb_ + r_; \
    const int cloc = wnb_ + n_ * 16 + cb_; \
    const float aval = acc[m_][n_][r_];
#define EPI256_END() } }

// ---------------- merged prep: x transpose-cast + all weight casts ----------------
__global__ __launch_bounds__(256) void prep_all(
    const float* __restrict__ x,
    const float* __restrict__ Wk, const float* __restrict__ Wq, const float* __restrict__ Wv,
    const float* __restrict__ Wp, const float* __restrict__ W1,
    ushort* __restrict__ xb, ushort* __restrict__ wqkv,
    ushort* __restrict__ wpb, ushort* __restrict__ w1b)
{
  const int g = blockIdx.x;
  if (g < 16384) {
    size_t idx = ((size_t)g * 256 + threadIdx.x) * 4;   // dest flat (b,s,d)
    int d = (int)(idx & 1023);
    int s = (int)((idx >> 10) & 4095);
    int b = (int)(idx >> 22);
    float4 v = *(const float4*)(x + ((size_t)s * BATCH + b) * DIM + d);
    ushort4 o;
    o.x = f2bf(v.x); o.y = f2bf(v.y); o.z = f2bf(v.z); o.w = f2bf(v.w);
    *(ushort4*)(xb + idx) = o;
  } else {
    const int gg = g - 16384;
    const int which = gg >> 10;
    const int idx = ((gg & 1023) * 256 + threadIdx.x) * 4;
    const float* src = (which == 0) ? Wk : (which == 1) ? Wq : (which == 2) ? Wv
                     : (which == 3) ? Wp : W1;
    ushort* dst = (which == 0) ? wqkv : (which == 1) ? wqkv + 1048576
                : (which == 2) ? wqkv + 2097152 : (which == 3) ? wpb : w1b;
    float4 v = *(const float4*)(src + idx);
    ushort4 o;
    o.x = f2bf(v.x); o.y = f2bf(v.y); o.z = f2bf(v.z); o.w = f2bf(v.w);
    *(ushort4*)(dst + idx) = o;
  }
}

// ---------------- GEMMs on the 256 core ----------------
__global__ __launch_bounds__(512, 2) void qkv_gemm256(
    const ushort* __restrict__ xb, const ushort* __restrict__ wqkv,
    ushort* __restrict__ Kp, ushort* __restrict__ Qp, ushort* __restrict__ VT)
{
  __shared__ ushort lds[65536];
  const int nid = (blockIdx.x & 7) * 96 + (blockIdx.x >> 3);  // XCD-chunked
  const int by = nid / 12;     // 0..63 (b*16 + s-block)
  const int bx = nid % 12;     // 0..11
  f32x4 acc[8][4];
  ACC256_ZERO(acc)
  gemm256_core(xb + (size_t)by * 256 * DIM, DIM,
               wqkv + (size_t)bx * 256 * DIM, DIM, DIM, lds, acc);
  if (bx < 8) {
    ushort* dst = (bx < 4) ? Kp : Qp;
    epi256_store_bf16(acc, lds, dst, by * 256, (bx & 3) * 256);
  } else {
    const int b = by >> 4, s0 = (by & 15) * 256;
    epi256_store_vt(acc, lds, VT + (size_t)b * DIM * S_LEN, (bx & 3) * 256, s0);
  }
}

__global__ __launch_bounds__(512, 2) void scores_gemm256(
    const ushort* __restrict__ Qp, const ushort* __restrict__ Kp,
    ushort* __restrict__ eb)
{
  const int bid = blockIdx.x;          // 192
  const int b   = bid / 48;
  const int rem = bid % 48;
  const int i   = rem / 3;             // 0..15 (256-row block)
  const int jj  = rem % 3;             // 0..2  (256-col band block)
  const int jblk = i + jj - 1;
  if (jblk < 0 || jblk >= 16) return;
  __shared__ ushort lds[65536];
  f32x4 acc[8][4];
  ACC256_ZERO(acc)
  gemm256_core(Qp + ((size_t)b * S_LEN + i * 256) * DIM, DIM,
               Kp + ((size_t)b * S_LEN + jblk * 256) * DIM, DIM, DIM, lds, acc);
  EPI256_BEGIN(acc)
    int q = i * 256 + rloc;
    int k = jblk * 256 + cloc;
    float v = aval * SCALE;
    int d = q - k;
    if (d == 0 || d > AP || d < -AP) v = -INFINITY;
    eb[((size_t)(b * S_LEN + q)) * BANDC + jj * 256 + cloc] = f2h(v);
  EPI256_END()
}

__global__ __launch_bounds__(512, 2) void av_gemm256(
    const ushort* __restrict__ aband, const ushort* __restrict__ VT,
    ushort* __restrict__ cbuf)
{
  __shared__ ushort lds[65536];
  const int bid  = blockIdx.x;     // 256
  const int b    = bid >> 6;
  const int i    = (bid >> 2) & 15;
  const int dblk = bid & 3;
  const int klo = (i == 0) ? 256 : 0;
  const int khi = (i == 15) ? 512 : BANDC;
  f32x4 acc[8][4];
  ACC256_ZERO(acc)
  const ushort* Ablk = aband + ((size_t)(b * S_LEN + i * 256)) * BANDC + klo;
  const ushort* Bblk = VT + (size_t)b * DIM * S_LEN + (size_t)dblk * 256 * S_LEN
                     + ((i - 1) * 256 + klo);
  gemm256_core(Ablk, BANDC, Bblk, S_LEN, khi - klo, lds, acc);
  epi256_store_bf16(acc, lds, cbuf, b * S_LEN + i * 256, dblk * 256);
}

__global__ __launch_bounds__(512, 2) void wp_gemm256(
    const ushort* __restrict__ cbuf, const ushort* __restrict__ wpb,
    const float* __restrict__ x, ushort* __restrict__ y0)
{
  __shared__ ushort lds[65536];
  const int nid = (blockIdx.x & 7) * 32 + (blockIdx.x >> 3);   // 256 blocks
  const int by = nid >> 2;     // 0..63
  const int bx = nid & 3;      // 0..3
  f32x4 acc[8][4];
  ACC256_ZERO(acc)
  gemm256_core(cbuf + (size_t)by * 256 * DIM, DIM,
               wpb + (size_t)bx * 256 * DIM, DIM, DIM, lds, acc);
  epi256_store_res_bf16(acc, lds, y0, by * 256, bx * 256, x);
}

__global__ __launch_bounds__(512, 2) void ffn1_gemm256(
    const ushort* __restrict__ y1, const ushort* __restrict__ w1b,
    const float* __restrict__ b1, ushort* __restrict__ h0)
{
  __shared__ ushort lds[65536];
  const int nid = (blockIdx.x & 7) * 32 + (blockIdx.x >> 3);
  const int by = nid >> 2;
  const int bx = nid & 3;
  f32x4 acc[8][4];
  ACC256_ZERO(acc)
  gemm256_core(y1 + (size_t)by * 256 * DIM, DIM,
               w1b + (size_t)bx * 256 * DIM, DIM, DIM, lds, acc);
  epi256_store_relu_bf16(acc, lds, h0, by * 256, bx * 256, b1);
}

// ---------------- softmax over the 768-band (wave-per-row) ----------------
__global__ __launch_bounds__(256) void softmax768(const ushort* __restrict__ eb,
                                                  ushort* __restrict__ aband)
{
  const int row  = blockIdx.x * 4 + (threadIdx.x >> 6);   // 0..16383
  const int lane = threadIdx.x & 63;
  const int s    = row & 4095;
  const int i256 = s >> 8;
  const ushort* e = eb + (size_t)row * BANDC;
  ushort* ab = aband + (size_t)row * BANDC;

  float vals[12];
  bool  ok[12];
  float mx = -INFINITY;
  #pragma unroll
  for (int j = 0; j < 6; ++j) {
    const int c0 = (j * 64 + lane) * 2;
    ushort2 u = *(const ushort2*)(e + c0);
    #pragma unroll
    for (int t = 0; t < 2; ++t) {
      const int c = c0 + t;
      const int jblk = i256 + (c >> 8) - 1;
      const int k = jblk * 256 + (c & 255);
      const int d = s - k;
      const bool valid = (jblk >= 0) && (jblk < 16) && (d != 0) && (d <= AP) && (d >= -AP);
      ok[j * 2 + t] = valid;
      float v = valid ? h2f(t ? u.y : u.x) : -INFINITY;
      vals[j * 2 + t] = v;
      mx = fmaxf(mx, v);
    }
  }
  mx = wave_max(mx);
  float ss = 0.0f;
  #pragma unroll
  for (int t = 0; t < 12; ++t) {
    float ev = ok[t] ? __expf(vals[t] - mx) : 0.0f;
    vals[t] = ev;
    ss += ev;
  }
  float inv = 1.0f / wave_sum(ss);
  #pragma unroll
  for (int j = 0; j < 6; ++j) {
    const int c0 = (j * 64 + lane) * 2;
    ushort2 o;
    o.x = f2bf(vals[j * 2 + 0] * inv);
    o.y = f2bf(vals[j * 2 + 1] * inv);
    *(ushort2*)(ab + c0) = o;
  }
}

// ---------------- norm / head (wave-per-row) ----------------
__global__ __launch_bounds__(256) void ln4(const ushort* __restrict__ y0, ushort* __restrict__ y1,
                                           const float* __restrict__ gamma, const float* __restrict__ beta)
{
  const int row  = blockIdx.x * 4 + (threadIdx.x >> 6);
  const int lane = threadIdx.x & 63;
  const ushort* r = y0 + (size_t)row * DIM;
  float v[16];
  float sum = 0.0f;
  #pragma unroll
  for (int j = 0; j < 2; ++j) {
    bf16x8 u = *(const bf16x8*)(r + j * 512 + lane * 8);
    #pragma unroll
    for (int t = 0; t < 8; ++t) { float f = bf2f((ushort)u[t]); v[j * 8 + t] = f; sum += f; }
  }
  const float mean = wave_sum(sum) * (1.0f / DIM);
  float q2 = 0.0f;
  #pragma unroll
  for (int t = 0; t < 16; ++t) { float d = v[t] - mean; q2 += d * d; }
  const float rstd = rsqrtf(wave_sum(q2) * (1.0f / DIM) + 1e-6f);
  #pragma unroll
  for (int j = 0; j < 2; ++j) {
    const int d0 = j * 512 + lane * 8;
    bf16x8 o;
    #pragma unroll
    for (int t = 0; t < 8; t += 4) {
      float4 g = *(const float4*)(gamma + d0 + t);
      float4 bb = *(const float4*)(beta + d0 + t);
      o[t + 0] = (short)f2bf((v[j * 8 + t + 0] - mean) * rstd * g.x + bb.x);
      o[t + 1] = (short)f2bf((v[j * 8 + t + 1] - mean) * rstd * g.y + bb.y);
      o[t + 2] = (short)f2bf((v[j * 8 + t + 2] - mean) * rstd * g.z + bb.z);
      o[t + 3] = (short)f2bf((v[j * 8 + t + 3] - mean) * rstd * g.w + bb.w);
    }
    *(bf16x8*)(y1 + (size_t)row * DIM + d0) = o;
  }
}

__global__ __launch_bounds__(256) void head4(const ushort* __restrict__ h0,
    const float* __restrict__ gamma, const float* __restrict__ beta,
    const float* __restrict__ W2, const float* __restrict__ b2,
    float* __restrict__ out)
{
  const int row  = blockIdx.x * 4 + (threadIdx.x >> 6);
  const int lane = threadIdx.x & 63;
  const int b = row >> 12, s = row & 4095;
  const ushort* r = h0 + (size_t)row * DIM;
  float v[16];
  float sum = 0.0f;
  #pragma unroll
  for (int j = 0; j < 2; ++j) {
    bf16x8 u = *(const bf16x8*)(r + j * 512 + lane * 8);
    #pragma unroll
    for (int t = 0; t < 8; ++t) { float f = bf2f((ushort)u[t]); v[j * 8 + t] = f; sum += f; }
  }
  const float mean = wave_sum(sum) * (1.0f / DIM);
  float q2 = 0.0f;
  #pragma unroll
  for (int t = 0; t < 16; ++t) { float d = v[t] - mean; q2 += d * d; }
  const float rstd = rsqrtf(wave_sum(q2) * (1.0f / DIM) + 1e-6f);
  float part = 0.0f;
  #pragma unroll
  for (int j = 0; j < 2; ++j) {
    const int d0 = j * 512 + lane * 8;
    #pragma unroll
    for (int t = 0; t < 8; t += 4) {
      float4 g = *(const float4*)(gamma + d0 + t);
      float4 bb = *(const float4*)(beta + d0 + t);
      float4 w2 = *(const float4*)(W2 + d0 + t);
      part += ((v[j * 8 + t + 0] - mean) * rstd * g.x + bb.x) * w2.x
            + ((v[j * 8 + t + 1] - mean) * rstd * g.y + bb.y) * w2.y
            + ((v[j * 8 + t + 2] - mean) * rstd * g.z + bb.z) * w2.z
            + ((v[j * 8 + t + 3] - mean) * rstd * g.w + bb.w) * w2.w;
    }
  }
  const float logit = wave_sum(part) + b2[0];
  if (lane == 0) out[(size_t)s * BATCH + b] = 1.0f / (1.0f + expf(-logit));
}

// ---------------- launch ----------------
extern "C" void kernel_launch(void* const* d_in, const int* in_sizes, int n_in,
                              void* d_out, int out_size, void* d_ws, size_t ws_size,
                              hipStream_t stream) {
  const float* x     = (const float*)d_in[0];
  const float* Wk    = (const float*)d_in[1];
  const float* Wq    = (const float*)d_in[2];
  const float* Wv    = (const float*)d_in[3];
  const float* Wp    = (const float*)d_in[4];
  const float* W1    = (const float*)d_in[5];
  const float* b1    = (const float*)d_in[6];
  const float* W2    = (const float*)d_in[7];
  const float* b2    = (const float*)d_in[8];
  const float* gamma = (const float*)d_in[9];
  const float* beta  = (const float*)d_in[10];
  float* out = (float*)d_out;

  char* w = (char*)d_ws;
  ushort* xb   = (ushort*)(w + 0);            // 33,554,432 B -> h0
  ushort* wqkv = (ushort*)(w + 33554432);     //  6,291,456 B
  ushort* wpb  = (ushort*)(w + 39845888);     //  2,097,152 B
  ushort* w1b  = (ushort*)(w + 41943040);     //  2,097,152 B
  ushort* Qp   = (ushort*)(w + 44040192);     // 33,554,432 B -> aband
  ushort* Kp   = (ushort*)(w + 77594624);     // 33,554,432 B -> cbuf
  ushort* y1   = (ushort*)(w + 111149056);    // 33,554,432 B
  ushort* VT   = (ushort*)(w + 144703488);    // 33,554,432 B (V^T written directly by qkv)
  char*   big  = (w + 178257920);             // 67,108,864 B
  // reuse (sequentially dead regions):
  ushort* eband = (ushort*)big;   // 16384*768*2 = 25.2 MB (fp16)
  ushort* aband = Qp;             // Q dead after scores
  ushort* cbuf  = Kp;             // K dead after scores
  ushort* h0    = xb;             // xb dead after qkv
  ushort* y0    = (ushort*)big;   // bf16; eband dead after softmax

  prep_all<<<21504, 256, 0, stream>>>(x, Wk, Wq, Wv, Wp, W1, xb, wqkv, wpb, w1b);

  qkv_gemm256<<<768, 512, 0, stream>>>(xb, wqkv, Kp, Qp, VT);
  scores_gemm256<<<192, 512, 0, stream>>>(Qp, Kp, eband);
  softmax768<<<4096, 256, 0, stream>>>(eband, aband);
  av_gemm256<<<256, 512, 0, stream>>>(aband, VT, cbuf);
  wp_gemm256<<<256, 512, 0, stream>>>(cbuf, wpb, x, y0);
  ln4<<<4096, 256, 0, stream>>>(y0, y1, gamma, beta);
  ffn1_gemm256<<<256, 512, 0, stream>>>(y1, w1b, b1, h0);
  head4<<<4096, 256, 0, stream>>>(h0, gamma, beta, W2, b2, out);
}